// Round 12
// baseline (1805.690 us; speedup 1.0000x reference)
//
#include <hip/hip_runtime.h>
#include <math.h>

typedef unsigned short u16;
typedef unsigned int u32;
typedef short bf16x8 __attribute__((ext_vector_type(8)));
typedef float f32x4 __attribute__((ext_vector_type(4)));

__device__ __forceinline__ u16 f2bf(float f) {
  u32 u = __float_as_uint(f);
  u32 r = (u + 0x7fffu + ((u >> 16) & 1u)) >> 16;
  return (u16)r;
}
__device__ __forceinline__ float bf2f(u16 h) {
  return __uint_as_float(((u32)h) << 16);
}
// async global->LDS, 16B per lane; LDS dest = wave-uniform base + lane*16
__device__ __forceinline__ void gload_lds16(const u16* g, u16* l) {
  __builtin_amdgcn_global_load_lds(
      (const __attribute__((address_space(1))) void*)g,
      (__attribute__((address_space(3))) void*)l, 16, 0, 0);
}
__device__ __forceinline__ float blockReduceSum(float v, float* red) {
  #pragma unroll
  for (int off = 32; off > 0; off >>= 1) v += __shfl_down(v, off, 64);
  const int lane = threadIdx.x & 63;
  const int wid = threadIdx.x >> 6;
  __syncthreads();
  if (lane == 0) red[wid] = v;
  __syncthreads();
  const int nw = (blockDim.x + 63) >> 6;
  float s = red[0];
  for (int i = 1; i < nw; ++i) s += red[i];
  return s;
}

// ---------------- positional encoding ----------------
__global__ void pe_kernel(float* __restrict__ pe) {
  int l = blockIdx.x;
  int i = threadIdx.x;
  double e = exp2(-(double)(2 * (i / 2)) / 256.0 * 13.287712379549449);
  double ang = (double)l * e;
  pe[l * 256 + i] = (float)((i & 1) ? cos(ang) : sin(ang));
}

// ---------------- embedding gather -> bf16 (wave per row) ----------------
__global__ __launch_bounds__(256) void gather_kernel(
    const int* __restrict__ txts, const float* __restrict__ emb,
    u16* __restrict__ tx) {
  int row = blockIdx.x * 4 + (threadIdx.x >> 6);
  int lane = threadIdx.x & 63;
  int tok = txts[row];
  float4 e = *(const float4*)(emb + (size_t)tok * 256 + lane * 4);
  u16 o[4] = {f2bf(e.x), f2bf(e.y), f2bf(e.z), f2bf(e.w)};
  *(uint2*)(tx + (size_t)row * 256 + lane * 4) = *(const uint2*)o;
}

// ------- weight transpose fp32[K][N] -> bf16[N][K], custom group stride ----
__global__ __launch_bounds__(256) void transpose_bf16(
    const float* __restrict__ W, u16* __restrict__ Wt, int K, int N,
    int dstStride) {
  __shared__ float tile[32][33];
  int g = blockIdx.z;
  const float* Wg = W + (size_t)g * K * N;
  u16* Wtg = Wt + (size_t)g * dstStride;
  int n0 = blockIdx.x * 32, k0 = blockIdx.y * 32;
  int tx = threadIdx.x & 31, ty = threadIdx.x >> 5;
  #pragma unroll
  for (int i = 0; i < 32; i += 8)
    tile[ty + i][tx] = Wg[(size_t)(k0 + ty + i) * N + n0 + tx];
  __syncthreads();
  #pragma unroll
  for (int i = 0; i < 32; i += 8)
    Wtg[(size_t)(n0 + ty + i) * K + k0 + tx] = f2bf(tile[tx][ty + i]);
}

// ------- merged transpose for Wq/Wk/Wv/Wo (all [4][256][256]) -------------
__global__ __launch_bounds__(256) void transpose_qkvo(
    const float* __restrict__ Wq, const float* __restrict__ Wk,
    const float* __restrict__ Wv, const float* __restrict__ Wo,
    u16* __restrict__ WqkvT, u16* __restrict__ WoT) {
  __shared__ float tile[32][33];
  int z = blockIdx.z, l = z >> 2, which = z & 3;
  const float* src = (which == 0) ? Wq : (which == 1) ? Wk
                     : (which == 2) ? Wv : Wo;
  src += (size_t)l * 65536;
  u16* dst = (which < 3) ? (WqkvT + (size_t)l * 196608 + which * 65536)
                         : (WoT + (size_t)l * 65536);
  int n0 = blockIdx.x * 32, k0 = blockIdx.y * 32;
  int tx = threadIdx.x & 31, ty = threadIdx.x >> 5;
  #pragma unroll
  for (int i = 0; i < 32; i += 8)
    tile[ty + i][tx] = src[(size_t)(k0 + ty + i) * 256 + n0 + tx];
  __syncthreads();
  #pragma unroll
  for (int i = 0; i < 32; i += 8)
    dst[(size_t)(n0 + ty + i) * 256 + k0 + tx] = f2bf(tile[tx][ty + i]);
}

// ---------------- concat qkv bias ----------------
__global__ void bias_concat_kernel(const float* __restrict__ bq,
                                   const float* __restrict__ bk,
                                   const float* __restrict__ bv,
                                   float* __restrict__ bqkv) {
  int l = blockIdx.x, i = threadIdx.x;
  float v;
  if (i < 256) v = bq[l * 256 + i];
  else if (i < 512) v = bk[l * 256 + i - 256];
  else v = bv[l * 256 + i - 512];
  bqkv[l * 768 + i] = v;
}

// ---------------- bf16 MFMA GEMM, 128x128 tile (m97 shape) ----------------
// grid (N/128, M/128), block 256 (4 waves: 2x2). act: 0 none, 1 relu.
__global__ __launch_bounds__(256) void gemm_bf16(
    const u16* __restrict__ A, const u16* __restrict__ Bt,
    const float* __restrict__ bias, u16* __restrict__ Cb, int M, int N, int K,
    int act) {
  __shared__ u16 As[128][32];
  __shared__ u16 Bs[128][32];
  const int tid = threadIdx.x;
  const int wave = tid >> 6, lane = tid & 63;
  const int wr = wave >> 1, wc = wave & 1;
  const int rowblk = blockIdx.y * 128, colblk = blockIdx.x * 128;
  const int l16 = lane & 15, lq = lane >> 4;
  const int lr = lane >> 2, lc = lane & 3;
  const int r0 = wave * 32;
  f32x4 acc[4][4];
  #pragma unroll
  for (int i = 0; i < 4; ++i)
    #pragma unroll
    for (int j = 0; j < 4; ++j) acc[i][j] = (f32x4)(0.f);

  for (int kt = 0; kt < K; kt += 32) {
    __syncthreads();
    gload_lds16(A + (size_t)(rowblk + r0 + lr) * K + kt + lc * 8, &As[r0][0]);
    gload_lds16(A + (size_t)(rowblk + r0 + 16 + lr) * K + kt + lc * 8,
                &As[r0 + 16][0]);
    gload_lds16(Bt + (size_t)(colblk + r0 + lr) * K + kt + lc * 8, &Bs[r0][0]);
    gload_lds16(Bt + (size_t)(colblk + r0 + 16 + lr) * K + kt + lc * 8,
                &Bs[r0 + 16][0]);
    __syncthreads();
    bf16x8 af[4], bfr[4];
    #pragma unroll
    for (int t = 0; t < 4; ++t) {
      af[t] = *(const bf16x8*)&As[wr * 64 + t * 16 + l16][lq * 8];
      bfr[t] = *(const bf16x8*)&Bs[wc * 64 + t * 16 + l16][lq * 8];
    }
    #pragma unroll
    for (int i = 0; i < 4; ++i)
      #pragma unroll
      for (int j = 0; j < 4; ++j)
        acc[i][j] = __builtin_amdgcn_mfma_f32_16x16x32_bf16(af[i], bfr[j],
                                                            acc[i][j], 0, 0, 0);
  }
  const int rbase = rowblk + wr * 64, cbase = colblk + wc * 64;
  #pragma unroll
  for (int j = 0; j < 4; ++j) {
    int col = cbase + j * 16 + l16;
    float bv = bias[col];
    #pragma unroll
    for (int i = 0; i < 4; ++i) {
      int row0 = rbase + i * 16 + lq * 4;
      #pragma unroll
      for (int r = 0; r < 4; ++r) {
        float vv = acc[i][j][r] + bv;
        if (act == 1) vv = fmaxf(vv, 0.f);
        Cb[(size_t)(row0 + r) * N + col] = f2bf(vv);
      }
    }
  }
}

// ------- fused GEMM (N=256) + bf16 residual/PE + LayerNorm -----------------
// 64-row blocks, 256 threads (4 col-waves). grid = M/64.
__global__ __launch_bounds__(256) void gemm_ln(
    const u16* __restrict__ A, const u16* __restrict__ Bt,
    const float* __restrict__ bias, const float* __restrict__ g,
    const float* __restrict__ bvec, const float* __restrict__ pe,
    u16* __restrict__ hddbf, int M, int K, int mode) {
  __shared__ u16 As[64][32];
  __shared__ u16 Bs[256][32];
  __shared__ float redS[4][64];
  __shared__ float redQ[4][64];
  __shared__ float rowstat[64][2];
  const int tid = threadIdx.x;
  const int wave = tid >> 6, lane = tid & 63;
  const int wc = wave;
  const int rowblk = blockIdx.x * 64;
  const int l16 = lane & 15, lq = lane >> 4;
  const int lr = lane >> 2, lc = lane & 3;
  f32x4 acc[4][4];
  #pragma unroll
  for (int i = 0; i < 4; ++i)
    #pragma unroll
    for (int j = 0; j < 4; ++j) acc[i][j] = (f32x4)(0.f);

  for (int kt = 0; kt < K; kt += 32) {
    __syncthreads();
    gload_lds16(A + (size_t)(rowblk + wave * 16 + lr) * K + kt + lc * 8,
                &As[wave * 16][0]);
    #pragma unroll
    for (int p = 0; p < 4; ++p)
      gload_lds16(Bt + (size_t)(wave * 64 + p * 16 + lr) * K + kt + lc * 8,
                  &Bs[wave * 64 + p * 16][0]);
    __syncthreads();
    bf16x8 af[4], bfr[4];
    #pragma unroll
    for (int t = 0; t < 4; ++t) {
      af[t] = *(const bf16x8*)&As[t * 16 + l16][lq * 8];
      bfr[t] = *(const bf16x8*)&Bs[wc * 64 + t * 16 + l16][lq * 8];
    }
    #pragma unroll
    for (int i = 0; i < 4; ++i)
      #pragma unroll
      for (int j = 0; j < 4; ++j)
        acc[i][j] = __builtin_amdgcn_mfma_f32_16x16x32_bf16(af[i], bfr[j],
                                                            acc[i][j], 0, 0, 0);
  }
  const int cbase = wc * 64;
  #pragma unroll
  for (int j = 0; j < 4; ++j) {
    int col = cbase + j * 16 + l16;
    float bv = bias[col];
    #pragma unroll
    for (int i = 0; i < 4; ++i) {
      int row0 = rowblk + i * 16 + lq * 4;
      #pragma unroll
      for (int r = 0; r < 4; ++r) {
        float v = acc[i][j][r] + bv;
        if (mode == 0) v += bf2f(hddbf[(size_t)(row0 + r) * 256 + col]);
        acc[i][j][r] = v;
      }
    }
  }
  #pragma unroll
  for (int i = 0; i < 4; ++i) {
    #pragma unroll
    for (int r = 0; r < 4; ++r) {
      float s = 0.f, q = 0.f;
      #pragma unroll
      for (int j = 0; j < 4; ++j) {
        float v = acc[i][j][r];
        s += v;
        q += v * v;
      }
      #pragma unroll
      for (int m = 1; m < 16; m <<= 1) {
        s += __shfl_xor(s, m, 64);
        q += __shfl_xor(q, m, 64);
      }
      if (l16 == 0) {
        int lrr = i * 16 + lq * 4 + r;
        redS[wc][lrr] = s;
        redQ[wc][lrr] = q;
      }
    }
  }
  __syncthreads();
  if (tid < 64) {
    float s = redS[0][tid] + redS[1][tid] + redS[2][tid] + redS[3][tid];
    float q = redQ[0][tid] + redQ[1][tid] + redQ[2][tid] + redQ[3][tid];
    float mean = s * (1.f / 256.f);
    float var = q * (1.f / 256.f) - mean * mean;
    rowstat[tid][0] = mean;
    rowstat[tid][1] = rsqrtf(var + 1e-5f);
  }
  __syncthreads();
  float gg[4], bb2[4];
  #pragma unroll
  for (int j = 0; j < 4; ++j) {
    int col = cbase + j * 16 + l16;
    gg[j] = g[col];
    bb2[j] = bvec[col];
  }
  #pragma unroll
  for (int i = 0; i < 4; ++i) {
    #pragma unroll
    for (int r = 0; r < 4; ++r) {
      int lrr = i * 16 + lq * 4 + r;
      int row = rowblk + lrr;
      float mean = rowstat[lrr][0], rstd = rowstat[lrr][1];
      #pragma unroll
      for (int j = 0; j < 4; ++j) {
        int col = cbase + j * 16 + l16;
        float o = (acc[i][j][r] - mean) * rstd * gg[j] + bb2[j];
        if (mode == 1) o += pe[(size_t)(row & 127) * 256 + col];
        hddbf[(size_t)row * 256 + col] = f2bf(o);
      }
    }
  }
}

// ------- fused FFN: relu(A@W1+b1)@W2+b2 + residual + LN --------------------
__global__ __launch_bounds__(512) void ffn_ln(
    const u16* __restrict__ A, const u16* __restrict__ W1t,
    const float* __restrict__ b1, const u16* __restrict__ W2t,
    const float* __restrict__ b2, const float* __restrict__ g,
    const float* __restrict__ bvec, u16* __restrict__ hddbf, int M) {
  __shared__ u16 As[64][264];
  __shared__ u16 Fs[64][520];
  __shared__ float redS[4][64];
  __shared__ float redQ[4][64];
  __shared__ float rowstat[64][2];
  const int tid = threadIdx.x;
  const int wave = tid >> 6, lane = tid & 63;
  const int l16 = lane & 15, lq = lane >> 4;
  const int rowblk = blockIdx.x * 64;
  for (int i = tid; i < 2048; i += 512) {
    int row = i >> 5, ch = i & 31;
    *(uint4*)&As[row][ch * 8] =
        *(const uint4*)(A + (size_t)(rowblk + row) * 256 + ch * 8);
  }
  __syncthreads();
  {
    f32x4 acc1[4][4];
    #pragma unroll
    for (int i = 0; i < 4; ++i)
      #pragma unroll
      for (int j = 0; j < 4; ++j) acc1[i][j] = (f32x4)(0.f);
    #pragma unroll
    for (int kt = 0; kt < 8; ++kt) {
      bf16x8 af[4], bfr[4];
      #pragma unroll
      for (int t = 0; t < 4; ++t) {
        af[t] = *(const bf16x8*)&As[t * 16 + l16][kt * 32 + lq * 8];
        bfr[t] = *(const bf16x8*)(W1t +
                                  (size_t)(wave * 64 + t * 16 + l16) * 256 +
                                  kt * 32 + lq * 8);
      }
      #pragma unroll
      for (int i = 0; i < 4; ++i)
        #pragma unroll
        for (int j = 0; j < 4; ++j)
          acc1[i][j] = __builtin_amdgcn_mfma_f32_16x16x32_bf16(
              af[i], bfr[j], acc1[i][j], 0, 0, 0);
    }
    #pragma unroll
    for (int j = 0; j < 4; ++j) {
      int col = wave * 64 + j * 16 + l16;
      float bias1 = b1[col];
      #pragma unroll
      for (int i = 0; i < 4; ++i) {
        int row0 = i * 16 + lq * 4;
        #pragma unroll
        for (int r = 0; r < 4; ++r)
          Fs[row0 + r][col] = f2bf(fmaxf(acc1[i][j][r] + bias1, 0.f));
      }
    }
  }
  __syncthreads();
  const int wr = wave >> 2, wc = wave & 3;
  f32x4 acc2[2][4];
  #pragma unroll
  for (int i = 0; i < 2; ++i)
    #pragma unroll
    for (int j = 0; j < 4; ++j) acc2[i][j] = (f32x4)(0.f);
  #pragma unroll
  for (int kt = 0; kt < 16; ++kt) {
    bf16x8 af[2], bfr[4];
    #pragma unroll
    for (int i = 0; i < 2; ++i)
      af[i] = *(const bf16x8*)&Fs[wr * 32 + i * 16 + l16][kt * 32 + lq * 8];
    #pragma unroll
    for (int j = 0; j < 4; ++j)
      bfr[j] = *(const bf16x8*)(W2t + (size_t)(wc * 64 + j * 16 + l16) * 512 +
                                kt * 32 + lq * 8);
    #pragma unroll
    for (int i = 0; i < 2; ++i)
      #pragma unroll
      for (int j = 0; j < 4; ++j)
        acc2[i][j] = __builtin_amdgcn_mfma_f32_16x16x32_bf16(af[i], bfr[j],
                                                             acc2[i][j], 0, 0,
                                                             0);
  }
  #pragma unroll
  for (int j = 0; j < 4; ++j) {
    int col = wc * 64 + j * 16 + l16;
    float bias2 = b2[col];
    #pragma unroll
    for (int i = 0; i < 2; ++i) {
      int row0 = rowblk + wr * 32 + i * 16 + lq * 4;
      #pragma unroll
      for (int r = 0; r < 4; ++r)
        acc2[i][j][r] += bias2 + bf2f(hddbf[(size_t)(row0 + r) * 256 + col]);
    }
  }
  #pragma unroll
  for (int i = 0; i < 2; ++i) {
    #pragma unroll
    for (int r = 0; r < 4; ++r) {
      float s = 0.f, q = 0.f;
      #pragma unroll
      for (int j = 0; j < 4; ++j) {
        float v = acc2[i][j][r];
        s += v;
        q += v * v;
      }
      #pragma unroll
      for (int m = 1; m < 16; m <<= 1) {
        s += __shfl_xor(s, m, 64);
        q += __shfl_xor(q, m, 64);
      }
      if (l16 == 0) {
        int lrr = wr * 32 + i * 16 + lq * 4 + r;
        redS[wc][lrr] = s;
        redQ[wc][lrr] = q;
      }
    }
  }
  __syncthreads();
  if (tid < 64) {
    float s = redS[0][tid] + redS[1][tid] + redS[2][tid] + redS[3][tid];
    float q = redQ[0][tid] + redQ[1][tid] + redQ[2][tid] + redQ[3][tid];
    float mean = s * (1.f / 256.f);
    float var = q * (1.f / 256.f) - mean * mean;
    rowstat[tid][0] = mean;
    rowstat[tid][1] = rsqrtf(var + 1e-5f);
  }
  __syncthreads();
  #pragma unroll
  for (int j = 0; j < 4; ++j) {
    int col = wc * 64 + j * 16 + l16;
    float gg = g[col], bb2v = bvec[col];
    #pragma unroll
    for (int i = 0; i < 2; ++i) {
      #pragma unroll
      for (int r = 0; r < 4; ++r) {
        int lrr = wr * 32 + i * 16 + lq * 4 + r;
        int row = rowblk + lrr;
        float o = (acc2[i][j][r] - rowstat[lrr][0]) * rowstat[lrr][1] * gg +
                  bb2v;
        hddbf[(size_t)row * 256 + col] = f2bf(o);
      }
    }
  }
}

// ---------------- generic fp32 GEMM (small GRU matmuls) ----------------
__global__ __launch_bounds__(256) void gemm_f32(
    const float* __restrict__ A, const float* __restrict__ B,
    const float* __restrict__ bias, float* __restrict__ C,
    int M, int N, int K, int act) {
  __shared__ float As[16][68];
  __shared__ float Bs[16][64];
  const int id = threadIdx.x;
  const int tx = id & 15;
  const int ty = id >> 4;
  const int colblk = blockIdx.x * 64;
  const int rowblk = blockIdx.y * 64;
  const int lin = id * 4;
  const int ar = lin >> 4;
  const int ac = lin & 15;
  const int bc = lin >> 6;
  const int bcol = lin & 63;
  float acc[4][4] = {};
  for (int kt = 0; kt < K; kt += 16) {
    float4 a4 = *(const float4*)(A + (size_t)(rowblk + ar) * K + kt + ac);
    float4 b4 = *(const float4*)(B + (size_t)(kt + bc) * N + colblk + bcol);
    As[ac + 0][ar] = a4.x; As[ac + 1][ar] = a4.y;
    As[ac + 2][ar] = a4.z; As[ac + 3][ar] = a4.w;
    *(float4*)&Bs[bc][bcol] = b4;
    __syncthreads();
    #pragma unroll
    for (int kk = 0; kk < 16; ++kk) {
      float4 av = *(const float4*)&As[kk][ty * 4];
      float4 bv = *(const float4*)&Bs[kk][tx * 4];
      float a[4] = {av.x, av.y, av.z, av.w};
      float b[4] = {bv.x, bv.y, bv.z, bv.w};
      #pragma unroll
      for (int i = 0; i < 4; ++i)
        #pragma unroll
        for (int j = 0; j < 4; ++j) acc[i][j] += a[i] * b[j];
    }
    __syncthreads();
  }
  const int col = colblk + tx * 4;
  float4 bi = *(const float4*)(bias + col);
  #pragma unroll
  for (int i = 0; i < 4; ++i) {
    float r[4] = {acc[i][0] + bi.x, acc[i][1] + bi.y,
                  acc[i][2] + bi.z, acc[i][3] + bi.w};
    if (act == 2) {
      #pragma unroll
      for (int j = 0; j < 4; ++j) r[j] = expf(-fmaxf(r[j], 0.f));
    }
    *(float4*)(C + (size_t)(rowblk + ty * 4 + i) * N + col) =
        make_float4(r[0], r[1], r[2], r[3]);
  }
}

// ---------------- attention, single-pass (scores bounded => no max) -------
__global__ __launch_bounds__(128) void attn_kernel(
    const u16* __restrict__ qkv, const int* __restrict__ txt_lengths,
    u16* __restrict__ o) {
  __shared__ float Ks[128][32];
  __shared__ float Vs[128][32];
  __shared__ float Qs[128][36];
  int bh = blockIdx.x;
  int b = bh >> 3, h = bh & 7;
  int t = threadIdx.x;
  int len = txt_lengths[b] + 2;
  const size_t base = ((size_t)b * 128) * 768 + h * 32;
  #pragma unroll
  for (int p = 0; p < 4; ++p) {
    int idx = p * 128 + t;
    int row = idx >> 2, ch = idx & 3;
    size_t gofs = base + (size_t)row * 768 + ch * 8;
    uint4 qv4 = *(const uint4*)(qkv + gofs);
    uint4 kv4 = *(const uint4*)(qkv + gofs + 256);
    uint4 vv4 = *(const uint4*)(qkv + gofs + 512);
    const u16* ks = (const u16*)&kv4;
    const u16* vs = (const u16*)&vv4;
    const u16* qs = (const u16*)&qv4;
    #pragma unroll
    for (int e = 0; e < 8; ++e) {
      Ks[row][ch * 8 + e] = bf2f(ks[e]);
      Vs[row][ch * 8 + e] = bf2f(vs[e]);
      Qs[row][ch * 8 + e] = bf2f(qs[e]);
    }
  }
  __syncthreads();
  float4 qv[8];
  #pragma unroll
  for (int i = 0; i < 8; ++i) {
    qv[i] = *(const float4*)&Qs[t][i * 4];
    qv[i].x *= 0.17677669529663687f; qv[i].y *= 0.17677669529663687f;
    qv[i].z *= 0.17677669529663687f; qv[i].w *= 0.17677669529663687f;
  }
  float l = 0.f;
  float ov[32];
  #pragma unroll
  for (int d = 0; d < 32; ++d) ov[d] = 0.f;
  for (int j = 0; j < len; ++j) {
    const float4* kr = (const float4*)&Ks[j][0];
    float s = 0.f;
    #pragma unroll
    for (int i = 0; i < 8; ++i) {
      float4 kk = kr[i];
      s += qv[i].x * kk.x + qv[i].y * kk.y + qv[i].z * kk.z + qv[i].w * kk.w;
    }
    float p = __expf(s);
    l += p;
    const float4* vr = (const float4*)&Vs[j][0];
    #pragma unroll
    for (int i = 0; i < 8; ++i) {
      float4 vvv = vr[i];
      ov[i * 4 + 0] += p * vvv.x; ov[i * 4 + 1] += p * vvv.y;
      ov[i * 4 + 2] += p * vvv.z; ov[i * 4 + 3] += p * vvv.w;
    }
  }
  float inv = 1.f / l;
  u16 ob[32];
  #pragma unroll
  for (int d = 0; d < 32; ++d) ob[d] = f2bf(ov[d] * inv);
  u16* orow = o + ((size_t)(b * 128 + t)) * 256 + h * 32;
  #pragma unroll
  for (int c = 0; c < 4; ++c)
    *(uint4*)(orow + c * 8) = *(const uint4*)&ob[c * 8];
}

// ---------------- GRU-D input imputation + concat ----------------
__global__ void impute_kernel(
    const float* __restrict__ x1, const float* __restrict__ m1,
    const float* __restrict__ d1, const float* __restrict__ dec_w,
    const float* __restrict__ dec_b, const float* __restrict__ x_m,
    float* __restrict__ xprep, float* __restrict__ dprep) {
  int idx = blockIdx.x * 256 + threadIdx.x;
  if (idx >= 256 * 24 * 16) return;
  int f = idx & 15;
  int t = (idx >> 4) % 24;
  int b = idx / (24 * 16);
  int src = (b * 36 + t) * 16 + f;
  float x = x1[src], m = m1[src], d = d1[src];
  float xd = expf(-fmaxf(d * dec_w[f] + dec_b[f], 0.f));
  float xv = m * x + (1.f - m) * xd * x + (1.f - m) * (1.f - xd) * x_m[f];
  int dst = b * 24 + t;
  xprep[dst * 32 + f] = xv;
  xprep[dst * 32 + 16 + f] = m;
  dprep[dst * 16 + f] = d;
}

// ------- GRU scan v7 (MFMA): 128 blocks x 2 batches, low-VGPR -------------
// WhhT: bf16 [768][256] = W_hh^T. A rows 0,1 = batches; lanes l16>=2 use 0.
__global__ __launch_bounds__(256, 4) void gru_scan_mfma(
    const float* __restrict__ gx, const float* __restrict__ hdcyb,
    const u16* __restrict__ WhhT, const float* __restrict__ b_hh,
    const float* __restrict__ h0, float* __restrict__ ys) {
  __shared__ float hf[2][256];
  __shared__ u16 hbf[2][264];
  __shared__ float gls[2][768];
  const int b0 = blockIdx.x * 2;
  const int tid = threadIdx.x;
  const int wave = tid >> 6, lane = tid & 63;
  const int l16 = lane & 15, lq = lane >> 4;
  for (int i = tid; i < 512; i += 256) {
    int bb = i >> 8, col = i & 255;
    float v = h0[(size_t)(b0 + bb) * 256 + col] *
              hdcyb[(size_t)((b0 + bb) * 24) * 256 + col];
    hf[bb][col] = v;
    hbf[bb][col] = f2bf(v);
  }
  const float bh0 = b_hh[tid], bh1 = b_hh[256 + tid], bh2 = b_hh[512 + tid];
  __syncthreads();
  for (int t = 0; t < 24; ++t) {
    // matvec via MFMA: wave covers cols [wave*192,+192) in 2 halves of 6 tiles
    #pragma unroll
    for (int half = 0; half < 2; ++half) {
      f32x4 acc[6];
      #pragma unroll
      for (int n = 0; n < 6; ++n) acc[n] = (f32x4)(0.f);
      #pragma unroll
      for (int kt = 0; kt < 8; ++kt) {
        bf16x8 af = (bf16x8)(short)0;
        if (l16 < 2) af = *(const bf16x8*)&hbf[l16][kt * 32 + lq * 8];
        #pragma unroll
        for (int n = 0; n < 6; ++n) {
          int col0 = wave * 192 + half * 96 + n * 16;
          bf16x8 bf = *(const bf16x8*)(WhhT + (size_t)(col0 + l16) * 256 +
                                       kt * 32 + lq * 8);
          acc[n] =
              __builtin_amdgcn_mfma_f32_16x16x32_bf16(af, bf, acc[n], 0, 0, 0);
        }
      }
      // D: col=lane&15, row=(lane>>4)*4+reg -> rows 0,1 in lq==0, reg 0,1
      if (lq == 0) {
        #pragma unroll
        for (int n = 0; n < 6; ++n) {
          int col = wave * 192 + half * 96 + n * 16 + l16;
          gls[0][col] = acc[n][0];
          gls[1][col] = acc[n][1];
        }
      }
    }
    __syncthreads();
    // gate update: thread handles col=tid for both batches
    #pragma unroll
    for (int bb = 0; bb < 2; ++bb) {
      const float* gxr = gx + (size_t)((b0 + bb) * 24 + t) * 768;
      int col = tid;
      float r = 1.f / (1.f + __expf(-(gxr[col] + gls[bb][col] + bh0)));
      float z =
          1.f / (1.f + __expf(-(gxr[256 + col] + gls[bb][256 + col] + bh1)));
      float n = tanhf(gxr[512 + col] + r * (gls[bb][512 + col] + bh2));
      float h1d = hf[bb][col];
      float hn = (1.f - z) * n + z * h1d;
      ys[(size_t)(t * 256 + b0 + bb) * 256 + col] = hn;
      float nxt = (t < 23)
                      ? hdcyb[(size_t)((b0 + bb) * 24 + t + 1) * 256 + col]
                      : 1.f;
      float hd = hn * nxt;  // pre-decayed for next step
      hf[bb][col] = hd;
      hbf[bb][col] = f2bf(hd);
    }
    __syncthreads();
  }
}

// ------- c_t = LN(concat(...)) + pred + masked-MSE (merged) ---------------
__global__ __launch_bounds__(256) void ct_pred_kernel(
    const float* __restrict__ ys, const u16* __restrict__ hddbf,
    const int* __restrict__ input_lengths, const float* __restrict__ age,
    const float* __restrict__ gen, const float* __restrict__ g,
    const float* __restrict__ bb, float* __restrict__ c_t,
    const float* __restrict__ ct_w, const float* __restrict__ x1,
    const float* __restrict__ f_ind, float* __restrict__ accum) {
  __shared__ float buf[514];
  __shared__ float ctl[514];
  __shared__ float red[8];
  __shared__ float sq[192];
  int b = blockIdx.x, tid = threadIdx.x;
  int il = input_lengths[b] - 1;
  buf[tid] = ys[(size_t)(il * 256 + b) * 256 + tid];
  buf[256 + tid] = bf2f(hddbf[(size_t)(b * 128) * 256 + tid]);
  if (tid < 2) buf[512 + tid] = (tid == 0) ? age[b] : gen[b];
  __syncthreads();
  float p = buf[tid] + buf[256 + tid] + (tid < 2 ? buf[512 + tid] : 0.f);
  float mean = blockReduceSum(p, red) / 514.f;
  float d0 = buf[tid] - mean;
  float d1 = buf[256 + tid] - mean;
  float dq = (tid < 2) ? (buf[512 + tid] - mean) : 0.f;
  float var = blockReduceSum(d0 * d0 + d1 * d1 + dq * dq, red) / 514.f;
  float rs = rsqrtf(var + 1e-5f);
  float c0 = d0 * rs * g[tid] + bb[tid];
  float c1 = d1 * rs * g[256 + tid] + bb[256 + tid];
  ctl[tid] = c0;
  ctl[256 + tid] = c1;
  c_t[(size_t)b * 514 + tid] = c0;
  c_t[(size_t)b * 514 + 256 + tid] = c1;
  if (tid < 2) {
    float c2 = dq * rs * g[512 + tid] + bb[512 + tid];
    ctl[512 + tid] = c2;
    c_t[(size_t)b * 514 + 512 + tid] = c2;
  }
  __syncthreads();
  if (tid < 192) {
    int t = tid >> 4, f = tid & 15;
    float acc = 0.f;
    for (int c = 0; c < 514; ++c)
      acc += ctl[c] * ct_w[(size_t)(t * 514 + c) * 16 + f];
    float diff = acc - x1[(size_t)(b * 36 + 24 + t) * 16 + f];
    sq[tid] = diff * diff;
  }
  __syncthreads();
  if (tid < 12) {
    float s = 0.f;
    #pragma unroll
    for (int f = 0; f < 16; ++f) s += sq[tid * 16 + f];
    float w = f_ind[b * 12 + tid];
    atomicAdd(&accum[0], (s * (1.f / 16.f)) * w);
    atomicAdd(&accum[1], w);
  }
}

// ---------------- z1 = c_t @ fc_W1 + fc_b1 ----------------
__global__ __launch_bounds__(64) void fc1_kernel(
    const float* __restrict__ c_t, const float* __restrict__ fc_W1,
    const float* __restrict__ fc_b1, float* __restrict__ z1) {
  int t = blockIdx.x, b = blockIdx.y, dd = threadIdx.x;
  __shared__ float ct[514];
  for (int i = dd; i < 514; i += 64) ct[i] = c_t[(size_t)b * 514 + i];
  __syncthreads();
  float acc = fc_b1[t * 64 + dd];
  for (int c = 0; c < 514; ++c)
    acc += ct[c] * fc_W1[(size_t)(t * 514 + c) * 64 + dd];
  z1[(size_t)(t * 256 + b) * 64 + dd] = acc;
}

// ---------------- batchnorm stats over B per (t, dd) ----------------
__global__ __launch_bounds__(256) void bn_stats_kernel(
    const float* __restrict__ z1, float* __restrict__ mu,
    float* __restrict__ rstd) {
  __shared__ float red[8];
  int t = blockIdx.x >> 6;
  int dd = blockIdx.x & 63;
  int b = threadIdx.x;
  float v = z1[(size_t)(t * 256 + b) * 64 + dd];
  float mean = blockReduceSum(v, red) * (1.f / 256.f);
  float d = v - mean;
  float var = blockReduceSum(d * d, red) * (1.f / 256.f);
  if (b == 0) {
    mu[t * 64 + dd] = mean;
    rstd[t * 64 + dd] = rsqrtf(var + 1e-5f);
  }
}

// ---------------- out = relu(bn(z1)) @ fc_W2 + fc_b2 ----------------
__global__ __launch_bounds__(64) void out_kernel(
    const float* __restrict__ z1, const float* __restrict__ mu,
    const float* __restrict__ rstd, const float* __restrict__ bn_g,
    const float* __restrict__ bn_b, const float* __restrict__ fc_W2,
    const float* __restrict__ fc_b2, float* __restrict__ out) {
  int t = blockIdx.x, b = blockIdx.y, dd = threadIdx.x;
  float v = z1[(size_t)(t * 256 + b) * 64 + dd];
  float zn = (v - mu[t * 64 + dd]) * rstd[t * 64 + dd] * bn_g[t * 64 + dd] +
             bn_b[t * 64 + dd];
  float val = fmaxf(zn, 0.f) * fc_W2[t * 64 + dd];
  #pragma unroll
  for (int off = 32; off > 0; off >>= 1) val += __shfl_down(val, off, 64);
  if (dd == 0) out[t * 256 + b] = val + fc_b2[t];
}

__global__ void loss_final_kernel(const float* __restrict__ accum,
                                  float* __restrict__ out) {
  out[0] = accum[0] / accum[1];
}

// =======================================================================
extern "C" void kernel_launch(void* const* d_in, const int* in_sizes, int n_in,
                              void* d_out, int out_size, void* d_ws,
                              size_t ws_size, hipStream_t stream) {
  const float* x1 = (const float*)d_in[0];
  const float* h0 = (const float*)d_in[1];
  const float* m1 = (const float*)d_in[2];
  const float* d1 = (const float*)d_in[3];
  const float* x_m = (const float*)d_in[4];
  const float* age = (const float*)d_in[5];
  const float* gen = (const float*)d_in[6];
  const int* input_lengths = (const int*)d_in[7];
  const int* txts = (const int*)d_in[8];
  const int* txt_lengths = (const int*)d_in[9];
  const float* f_ind = (const float*)d_in[10];
  const float* emb = (const float*)d_in[11];
  const float* Win = (const float*)d_in[12];
  const float* bin_ = (const float*)d_in[13];
  const float* ln_in_g = (const float*)d_in[14];
  const float* ln_in_b = (const float*)d_in[15];
  const float* Wq = (const float*)d_in[16];
  const float* bq = (const float*)d_in[17];
  const float* Wk = (const float*)d_in[18];
  const float* bk = (const float*)d_in[19];
  const float* Wv = (const float*)d_in[20];
  const float* bv = (const float*)d_in[21];
  const float* Wo = (const float*)d_in[22];
  const float* bo = (const float*)d_in[23];
  const float* ln1_g = (const float*)d_in[24];
  const float* ln1_b = (const float*)d_in[25];
  const float* Wf1 = (const float*)d_in[26];
  const float* bf1 = (const float*)d_in[27];
  const float* Wf2 = (const float*)d_in[28];
  const float* bf2 = (const float*)d_in[29];
  const float* ln2_g = (const float*)d_in[30];
  const float* ln2_b = (const float*)d_in[31];
  const float* dec_w = (const float*)d_in[32];
  const float* dec_b = (const float*)d_in[33];
  const float* hd_W = (const float*)d_in[34];
  const float* hd_b = (const float*)d_in[35];
  const float* W_ih = (const float*)d_in[36];
  const float* b_ih = (const float*)d_in[37];
  const float* W_hh = (const float*)d_in[38];
  const float* b_hh = (const float*)d_in[39];
  const float* ln_c_g = (const float*)d_in[40];
  const float* ln_c_b = (const float*)d_in[41];
  const float* ct_w = (const float*)d_in[42];
  const float* fc_W1 = (const float*)d_in[43];
  const float* fc_b1 = (const float*)d_in[44];
  const float* bn_g = (const float*)d_in[45];
  const float* bn_b = (const float*)d_in[46];
  const float* fc_W2 = (const float*)d_in[47];
  const float* fc_b2 = (const float*)d_in[48];
  float* out = (float*)d_out;

  // ---- workspace layout (bytes) ----
  char* base = (char*)d_ws;
  u16* hdd_bf = (u16*)(base + 0);             // 16.8 MB (residual stream)
  u16* qkvb = (u16*)(base + 16777216);        // 50.3 MB
  u16* ob = (u16*)(base + 67108864);          // 16.8 MB (also tx_bf)
  u16* WinT = (u16*)(base + 83886080);        // 65536 el
  u16* WqkvT = WinT + 65536;                  // 4 x 196608 el
  u16* WoT = WqkvT + 786432;                  // 4 x 65536 el
  u16* Wf1T = WoT + 262144;                   // 4 x 131072 el
  u16* Wf2T = Wf1T + 524288;                  // 4 x 131072 el
  float* bqkv = (float*)(base + 88211456);    // 3072 f32
  float* pe = (float*)(base + 88223744);      // 128 KB
  u16* WhhT = (u16*)(base + 88354816);        // 384 KB bf16 [768][256]
  // GRU/head overlay over qkvb/ob (dead post-transformer); hdd_bf stays live
  char* gru = base + 16777216;
  float* xprep = (float*)gru;                 // 786432 B
  float* dprep = (float*)(gru + 786432);      // 393216 B
  float* gx = (float*)(gru + 1179648);        // 18874368 B
  float* hdcyb = (float*)(gru + 20054016);    // 6291456 B
  float* ys = (float*)(gru + 26345472);       // 6291456 B
  float* c_t = (float*)(gru + 32636928);      // 526336 B
  float* z1 = (float*)(gru + 33163264);       // 786432 B
  float* muv = (float*)(gru + 33949696);
  float* rstdv = (float*)(gru + 33952768);
  float* accum = (float*)(gru + 33955840);

  hipMemsetAsync(accum, 0, 2 * sizeof(float), stream);

  // ---- weight conversion ----
  transpose_bf16<<<dim3(8, 8, 1), 256, 0, stream>>>(Win, WinT, 256, 256, 65536);
  transpose_qkvo<<<dim3(8, 8, 16), 256, 0, stream>>>(Wq, Wk, Wv, Wo, WqkvT,
                                                     WoT);
  transpose_bf16<<<dim3(16, 8, 4), 256, 0, stream>>>(Wf1, Wf1T, 256, 512,
                                                     131072);
  transpose_bf16<<<dim3(8, 16, 4), 256, 0, stream>>>(Wf2, Wf2T, 512, 256,
                                                     131072);
  transpose_bf16<<<dim3(24, 8, 1), 256, 0, stream>>>(W_hh, WhhT, 256, 768,
                                                     196608);
  bias_concat_kernel<<<4, 768, 0, stream>>>(bq, bk, bv, bqkv);

  // ---- text transformer ----
  pe_kernel<<<128, 256, 0, stream>>>(pe);
  gather_kernel<<<8192, 256, 0, stream>>>(txts, emb, ob);  // tx in ob
  gemm_ln<<<512, 256, 0, stream>>>(ob, WinT, bin_, ln_in_g, ln_in_b, pe,
                                   hdd_bf, 32768, 256, 1);
  for (int l = 0; l < 4; ++l) {
    gemm_bf16<<<dim3(6, 256), 256, 0, stream>>>(hdd_bf, WqkvT + l * 196608,
                                                bqkv + l * 768, qkvb, 32768,
                                                768, 256, 0);
    attn_kernel<<<2048, 128, 0, stream>>>(qkvb, txt_lengths, ob);
    gemm_ln<<<512, 256, 0, stream>>>(ob, WoT + l * 65536, bo + l * 256,
                                     ln1_g + l * 256, ln1_b + l * 256, pe,
                                     hdd_bf, 32768, 256, 0);
    ffn_ln<<<512, 512, 0, stream>>>(hdd_bf, Wf1T + l * 131072, bf1 + l * 512,
                                    Wf2T + l * 131072, bf2 + l * 256,
                                    ln2_g + l * 256, ln2_b + l * 256, hdd_bf,
                                    32768);
  }

  // ---- GRU-D branch ----
  impute_kernel<<<384, 256, 0, stream>>>(x1, m1, d1, dec_w, dec_b, x_m, xprep,
                                         dprep);
  gemm_f32<<<dim3(12, 96), 256, 0, stream>>>(xprep, W_ih, b_ih, gx, 6144, 768,
                                             32, 0);
  gemm_f32<<<dim3(4, 96), 256, 0, stream>>>(dprep, hd_W, hd_b, hdcyb, 6144,
                                            256, 16, 2);
  gru_scan_mfma<<<128, 256, 0, stream>>>(gx, hdcyb, WhhT, b_hh, h0, ys);

  // ---- head ----
  ct_pred_kernel<<<256, 256, 0, stream>>>(ys, hdd_bf, input_lengths, age, gen,
                                          ln_c_g, ln_c_b, c_t, ct_w, x1, f_ind,
                                          accum);
  fc1_kernel<<<dim3(12, 256), 64, 0, stream>>>(c_t, fc_W1, fc_b1, z1);
  bn_stats_kernel<<<768, 256, 0, stream>>>(z1, muv, rstdv);
  out_kernel<<<dim3(12, 256), 64, 0, stream>>>(z1, muv, rstdv, bn_g, bn_b,
                                               fc_W2, fc_b2, out);
  loss_final_kernel<<<1, 1, 0, stream>>>(accum, out + 3072);
}

// Round 13
// 1469.345 us; speedup vs baseline: 1.2289x; 1.2289x over previous
//
#include <hip/hip_runtime.h>
#include <math.h>

typedef unsigned short u16;
typedef unsigned int u32;
typedef short bf16x8 __attribute__((ext_vector_type(8)));
typedef float f32x4 __attribute__((ext_vector_type(4)));

__device__ __forceinline__ u16 f2bf(float f) {
  u32 u = __float_as_uint(f);
  u32 r = (u + 0x7fffu + ((u >> 16) & 1u)) >> 16;
  return (u16)r;
}
__device__ __forceinline__ float bf2f(u16 h) {
  return __uint_as_float(((u32)h) << 16);
}
// async global->LDS, 16B per lane; LDS dest = wave-uniform base + lane*16
__device__ __forceinline__ void gload_lds16(const u16* g, u16* l) {
  __builtin_amdgcn_global_load_lds(
      (const __attribute__((address_space(1))) void*)g,
      (__attribute__((address_space(3))) void*)l, 16, 0, 0);
}
__device__ __forceinline__ float blockReduceSum(float v, float* red) {
  #pragma unroll
  for (int off = 32; off > 0; off >>= 1) v += __shfl_down(v, off, 64);
  const int lane = threadIdx.x & 63;
  const int wid = threadIdx.x >> 6;
  __syncthreads();
  if (lane == 0) red[wid] = v;
  __syncthreads();
  const int nw = (blockDim.x + 63) >> 6;
  float s = red[0];
  for (int i = 1; i < nw; ++i) s += red[i];
  return s;
}

// ---------------- positional encoding ----------------
__global__ void pe_kernel(float* __restrict__ pe) {
  int l = blockIdx.x;
  int i = threadIdx.x;
  double e = exp2(-(double)(2 * (i / 2)) / 256.0 * 13.287712379549449);
  double ang = (double)l * e;
  pe[l * 256 + i] = (float)((i & 1) ? cos(ang) : sin(ang));
}

// ---------------- embedding gather -> bf16 (wave per row) ----------------
__global__ __launch_bounds__(256) void gather_kernel(
    const int* __restrict__ txts, const float* __restrict__ emb,
    u16* __restrict__ tx) {
  int row = blockIdx.x * 4 + (threadIdx.x >> 6);
  int lane = threadIdx.x & 63;
  int tok = txts[row];
  float4 e = *(const float4*)(emb + (size_t)tok * 256 + lane * 4);
  u16 o[4] = {f2bf(e.x), f2bf(e.y), f2bf(e.z), f2bf(e.w)};
  *(uint2*)(tx + (size_t)row * 256 + lane * 4) = *(const uint2*)o;
}

// ------- weight transpose fp32[K][N] -> bf16[N][K], custom group stride ----
__global__ __launch_bounds__(256) void transpose_bf16(
    const float* __restrict__ W, u16* __restrict__ Wt, int K, int N,
    int dstStride) {
  __shared__ float tile[32][33];
  int g = blockIdx.z;
  const float* Wg = W + (size_t)g * K * N;
  u16* Wtg = Wt + (size_t)g * dstStride;
  int n0 = blockIdx.x * 32, k0 = blockIdx.y * 32;
  int tx = threadIdx.x & 31, ty = threadIdx.x >> 5;
  #pragma unroll
  for (int i = 0; i < 32; i += 8)
    tile[ty + i][tx] = Wg[(size_t)(k0 + ty + i) * N + n0 + tx];
  __syncthreads();
  #pragma unroll
  for (int i = 0; i < 32; i += 8)
    Wtg[(size_t)(n0 + ty + i) * K + k0 + tx] = f2bf(tile[tx][ty + i]);
}

// ------- merged transpose for Wq/Wk/Wv/Wo (all [4][256][256]) -------------
__global__ __launch_bounds__(256) void transpose_qkvo(
    const float* __restrict__ Wq, const float* __restrict__ Wk,
    const float* __restrict__ Wv, const float* __restrict__ Wo,
    u16* __restrict__ WqkvT, u16* __restrict__ WoT) {
  __shared__ float tile[32][33];
  int z = blockIdx.z, l = z >> 2, which = z & 3;
  const float* src = (which == 0) ? Wq : (which == 1) ? Wk
                     : (which == 2) ? Wv : Wo;
  src += (size_t)l * 65536;
  u16* dst = (which < 3) ? (WqkvT + (size_t)l * 196608 + which * 65536)
                         : (WoT + (size_t)l * 65536);
  int n0 = blockIdx.x * 32, k0 = blockIdx.y * 32;
  int tx = threadIdx.x & 31, ty = threadIdx.x >> 5;
  #pragma unroll
  for (int i = 0; i < 32; i += 8)
    tile[ty + i][tx] = src[(size_t)(k0 + ty + i) * 256 + n0 + tx];
  __syncthreads();
  #pragma unroll
  for (int i = 0; i < 32; i += 8)
    dst[(size_t)(n0 + ty + i) * 256 + k0 + tx] = f2bf(tile[tx][ty + i]);
}

// ---------------- concat qkv bias ----------------
__global__ void bias_concat_kernel(const float* __restrict__ bq,
                                   const float* __restrict__ bk,
                                   const float* __restrict__ bv,
                                   float* __restrict__ bqkv) {
  int l = blockIdx.x, i = threadIdx.x;
  float v;
  if (i < 256) v = bq[l * 256 + i];
  else if (i < 512) v = bk[l * 256 + i - 256];
  else v = bv[l * 256 + i - 512];
  bqkv[l * 768 + i] = v;
}

// ---------------- bf16 MFMA GEMM, 128x128 tile (m97 shape) ----------------
// grid (N/128, M/128), block 256 (4 waves: 2x2). act: 0 none, 1 relu.
__global__ __launch_bounds__(256) void gemm_bf16(
    const u16* __restrict__ A, const u16* __restrict__ Bt,
    const float* __restrict__ bias, u16* __restrict__ Cb, int M, int N, int K,
    int act) {
  __shared__ u16 As[128][32];
  __shared__ u16 Bs[128][32];
  const int tid = threadIdx.x;
  const int wave = tid >> 6, lane = tid & 63;
  const int wr = wave >> 1, wc = wave & 1;
  const int rowblk = blockIdx.y * 128, colblk = blockIdx.x * 128;
  const int l16 = lane & 15, lq = lane >> 4;
  const int lr = lane >> 2, lc = lane & 3;
  const int r0 = wave * 32;
  f32x4 acc[4][4];
  #pragma unroll
  for (int i = 0; i < 4; ++i)
    #pragma unroll
    for (int j = 0; j < 4; ++j) acc[i][j] = (f32x4)(0.f);

  for (int kt = 0; kt < K; kt += 32) {
    __syncthreads();
    gload_lds16(A + (size_t)(rowblk + r0 + lr) * K + kt + lc * 8, &As[r0][0]);
    gload_lds16(A + (size_t)(rowblk + r0 + 16 + lr) * K + kt + lc * 8,
                &As[r0 + 16][0]);
    gload_lds16(Bt + (size_t)(colblk + r0 + lr) * K + kt + lc * 8, &Bs[r0][0]);
    gload_lds16(Bt + (size_t)(colblk + r0 + 16 + lr) * K + kt + lc * 8,
                &Bs[r0 + 16][0]);
    __syncthreads();
    bf16x8 af[4], bfr[4];
    #pragma unroll
    for (int t = 0; t < 4; ++t) {
      af[t] = *(const bf16x8*)&As[wr * 64 + t * 16 + l16][lq * 8];
      bfr[t] = *(const bf16x8*)&Bs[wc * 64 + t * 16 + l16][lq * 8];
    }
    #pragma unroll
    for (int i = 0; i < 4; ++i)
      #pragma unroll
      for (int j = 0; j < 4; ++j)
        acc[i][j] = __builtin_amdgcn_mfma_f32_16x16x32_bf16(af[i], bfr[j],
                                                            acc[i][j], 0, 0, 0);
  }
  const int rbase = rowblk + wr * 64, cbase = colblk + wc * 64;
  #pragma unroll
  for (int j = 0; j < 4; ++j) {
    int col = cbase + j * 16 + l16;
    float bv = bias[col];
    #pragma unroll
    for (int i = 0; i < 4; ++i) {
      int row0 = rbase + i * 16 + lq * 4;
      #pragma unroll
      for (int r = 0; r < 4; ++r) {
        float vv = acc[i][j][r] + bv;
        if (act == 1) vv = fmaxf(vv, 0.f);
        Cb[(size_t)(row0 + r) * N + col] = f2bf(vv);
      }
    }
  }
}

// ------- fused GEMM (N=256) + bf16 residual/PE + LayerNorm -----------------
// 64-row blocks, 256 threads (4 col-waves). grid = M/64.
__global__ __launch_bounds__(256) void gemm_ln(
    const u16* __restrict__ A, const u16* __restrict__ Bt,
    const float* __restrict__ bias, const float* __restrict__ g,
    const float* __restrict__ bvec, const float* __restrict__ pe,
    u16* __restrict__ hddbf, int M, int K, int mode) {
  __shared__ u16 As[64][32];
  __shared__ u16 Bs[256][32];
  __shared__ float redS[4][64];
  __shared__ float redQ[4][64];
  __shared__ float rowstat[64][2];
  const int tid = threadIdx.x;
  const int wave = tid >> 6, lane = tid & 63;
  const int wc = wave;
  const int rowblk = blockIdx.x * 64;
  const int l16 = lane & 15, lq = lane >> 4;
  const int lr = lane >> 2, lc = lane & 3;
  f32x4 acc[4][4];
  #pragma unroll
  for (int i = 0; i < 4; ++i)
    #pragma unroll
    for (int j = 0; j < 4; ++j) acc[i][j] = (f32x4)(0.f);

  for (int kt = 0; kt < K; kt += 32) {
    __syncthreads();
    gload_lds16(A + (size_t)(rowblk + wave * 16 + lr) * K + kt + lc * 8,
                &As[wave * 16][0]);
    #pragma unroll
    for (int p = 0; p < 4; ++p)
      gload_lds16(Bt + (size_t)(wave * 64 + p * 16 + lr) * K + kt + lc * 8,
                  &Bs[wave * 64 + p * 16][0]);
    __syncthreads();
    bf16x8 af[4], bfr[4];
    #pragma unroll
    for (int t = 0; t < 4; ++t) {
      af[t] = *(const bf16x8*)&As[t * 16 + l16][lq * 8];
      bfr[t] = *(const bf16x8*)&Bs[wc * 64 + t * 16 + l16][lq * 8];
    }
    #pragma unroll
    for (int i = 0; i < 4; ++i)
      #pragma unroll
      for (int j = 0; j < 4; ++j)
        acc[i][j] = __builtin_amdgcn_mfma_f32_16x16x32_bf16(af[i], bfr[j],
                                                            acc[i][j], 0, 0, 0);
  }
  const int cbase = wc * 64;
  #pragma unroll
  for (int j = 0; j < 4; ++j) {
    int col = cbase + j * 16 + l16;
    float bv = bias[col];
    #pragma unroll
    for (int i = 0; i < 4; ++i) {
      int row0 = rowblk + i * 16 + lq * 4;
      #pragma unroll
      for (int r = 0; r < 4; ++r) {
        float v = acc[i][j][r] + bv;
        if (mode == 0) v += bf2f(hddbf[(size_t)(row0 + r) * 256 + col]);
        acc[i][j][r] = v;
      }
    }
  }
  #pragma unroll
  for (int i = 0; i < 4; ++i) {
    #pragma unroll
    for (int r = 0; r < 4; ++r) {
      float s = 0.f, q = 0.f;
      #pragma unroll
      for (int j = 0; j < 4; ++j) {
        float v = acc[i][j][r];
        s += v;
        q += v * v;
      }
      #pragma unroll
      for (int m = 1; m < 16; m <<= 1) {
        s += __shfl_xor(s, m, 64);
        q += __shfl_xor(q, m, 64);
      }
      if (l16 == 0) {
        int lrr = i * 16 + lq * 4 + r;
        redS[wc][lrr] = s;
        redQ[wc][lrr] = q;
      }
    }
  }
  __syncthreads();
  if (tid < 64) {
    float s = redS[0][tid] + redS[1][tid] + redS[2][tid] + redS[3][tid];
    float q = redQ[0][tid] + redQ[1][tid] + redQ[2][tid] + redQ[3][tid];
    float mean = s * (1.f / 256.f);
    float var = q * (1.f / 256.f) - mean * mean;
    rowstat[tid][0] = mean;
    rowstat[tid][1] = rsqrtf(var + 1e-5f);
  }
  __syncthreads();
  float gg[4], bb2[4];
  #pragma unroll
  for (int j = 0; j < 4; ++j) {
    int col = cbase + j * 16 + l16;
    gg[j] = g[col];
    bb2[j] = bvec[col];
  }
  #pragma unroll
  for (int i = 0; i < 4; ++i) {
    #pragma unroll
    for (int r = 0; r < 4; ++r) {
      int lrr = i * 16 + lq * 4 + r;
      int row = rowblk + lrr;
      float mean = rowstat[lrr][0], rstd = rowstat[lrr][1];
      #pragma unroll
      for (int j = 0; j < 4; ++j) {
        int col = cbase + j * 16 + l16;
        float o = (acc[i][j][r] - mean) * rstd * gg[j] + bb2[j];
        if (mode == 1) o += pe[(size_t)(row & 127) * 256 + col];
        hddbf[(size_t)row * 256 + col] = f2bf(o);
      }
    }
  }
}

// ------- fused FFN: relu(A@W1+b1)@W2+b2 + residual + LN --------------------
__global__ __launch_bounds__(512) void ffn_ln(
    const u16* __restrict__ A, const u16* __restrict__ W1t,
    const float* __restrict__ b1, const u16* __restrict__ W2t,
    const float* __restrict__ b2, const float* __restrict__ g,
    const float* __restrict__ bvec, u16* __restrict__ hddbf, int M) {
  __shared__ u16 As[64][264];
  __shared__ u16 Fs[64][520];
  __shared__ float redS[4][64];
  __shared__ float redQ[4][64];
  __shared__ float rowstat[64][2];
  const int tid = threadIdx.x;
  const int wave = tid >> 6, lane = tid & 63;
  const int l16 = lane & 15, lq = lane >> 4;
  const int rowblk = blockIdx.x * 64;
  for (int i = tid; i < 2048; i += 512) {
    int row = i >> 5, ch = i & 31;
    *(uint4*)&As[row][ch * 8] =
        *(const uint4*)(A + (size_t)(rowblk + row) * 256 + ch * 8);
  }
  __syncthreads();
  {
    f32x4 acc1[4][4];
    #pragma unroll
    for (int i = 0; i < 4; ++i)
      #pragma unroll
      for (int j = 0; j < 4; ++j) acc1[i][j] = (f32x4)(0.f);
    #pragma unroll
    for (int kt = 0; kt < 8; ++kt) {
      bf16x8 af[4], bfr[4];
      #pragma unroll
      for (int t = 0; t < 4; ++t) {
        af[t] = *(const bf16x8*)&As[t * 16 + l16][kt * 32 + lq * 8];
        bfr[t] = *(const bf16x8*)(W1t +
                                  (size_t)(wave * 64 + t * 16 + l16) * 256 +
                                  kt * 32 + lq * 8);
      }
      #pragma unroll
      for (int i = 0; i < 4; ++i)
        #pragma unroll
        for (int j = 0; j < 4; ++j)
          acc1[i][j] = __builtin_amdgcn_mfma_f32_16x16x32_bf16(
              af[i], bfr[j], acc1[i][j], 0, 0, 0);
    }
    #pragma unroll
    for (int j = 0; j < 4; ++j) {
      int col = wave * 64 + j * 16 + l16;
      float bias1 = b1[col];
      #pragma unroll
      for (int i = 0; i < 4; ++i) {
        int row0 = i * 16 + lq * 4;
        #pragma unroll
        for (int r = 0; r < 4; ++r)
          Fs[row0 + r][col] = f2bf(fmaxf(acc1[i][j][r] + bias1, 0.f));
      }
    }
  }
  __syncthreads();
  const int wr = wave >> 2, wc = wave & 3;
  f32x4 acc2[2][4];
  #pragma unroll
  for (int i = 0; i < 2; ++i)
    #pragma unroll
    for (int j = 0; j < 4; ++j) acc2[i][j] = (f32x4)(0.f);
  #pragma unroll
  for (int kt = 0; kt < 16; ++kt) {
    bf16x8 af[2], bfr[4];
    #pragma unroll
    for (int i = 0; i < 2; ++i)
      af[i] = *(const bf16x8*)&Fs[wr * 32 + i * 16 + l16][kt * 32 + lq * 8];
    #pragma unroll
    for (int j = 0; j < 4; ++j)
      bfr[j] = *(const bf16x8*)(W2t + (size_t)(wc * 64 + j * 16 + l16) * 512 +
                                kt * 32 + lq * 8);
    #pragma unroll
    for (int i = 0; i < 2; ++i)
      #pragma unroll
      for (int j = 0; j < 4; ++j)
        acc2[i][j] = __builtin_amdgcn_mfma_f32_16x16x32_bf16(af[i], bfr[j],
                                                             acc2[i][j], 0, 0,
                                                             0);
  }
  #pragma unroll
  for (int j = 0; j < 4; ++j) {
    int col = wc * 64 + j * 16 + l16;
    float bias2 = b2[col];
    #pragma unroll
    for (int i = 0; i < 2; ++i) {
      int row0 = rowblk + wr * 32 + i * 16 + lq * 4;
      #pragma unroll
      for (int r = 0; r < 4; ++r)
        acc2[i][j][r] += bias2 + bf2f(hddbf[(size_t)(row0 + r) * 256 + col]);
    }
  }
  #pragma unroll
  for (int i = 0; i < 2; ++i) {
    #pragma unroll
    for (int r = 0; r < 4; ++r) {
      float s = 0.f, q = 0.f;
      #pragma unroll
      for (int j = 0; j < 4; ++j) {
        float v = acc2[i][j][r];
        s += v;
        q += v * v;
      }
      #pragma unroll
      for (int m = 1; m < 16; m <<= 1) {
        s += __shfl_xor(s, m, 64);
        q += __shfl_xor(q, m, 64);
      }
      if (l16 == 0) {
        int lrr = wr * 32 + i * 16 + lq * 4 + r;
        redS[wc][lrr] = s;
        redQ[wc][lrr] = q;
      }
    }
  }
  __syncthreads();
  if (tid < 64) {
    float s = redS[0][tid] + redS[1][tid] + redS[2][tid] + redS[3][tid];
    float q = redQ[0][tid] + redQ[1][tid] + redQ[2][tid] + redQ[3][tid];
    float mean = s * (1.f / 256.f);
    float var = q * (1.f / 256.f) - mean * mean;
    rowstat[tid][0] = mean;
    rowstat[tid][1] = rsqrtf(var + 1e-5f);
  }
  __syncthreads();
  #pragma unroll
  for (int j = 0; j < 4; ++j) {
    int col = wc * 64 + j * 16 + l16;
    float gg = g[col], bb2v = bvec[col];
    #pragma unroll
    for (int i = 0; i < 2; ++i) {
      #pragma unroll
      for (int r = 0; r < 4; ++r) {
        int lrr = wr * 32 + i * 16 + lq * 4 + r;
        int row = rowblk + lrr;
        float o = (acc2[i][j][r] - rowstat[lrr][0]) * rowstat[lrr][1] * gg +
                  bb2v;
        hddbf[(size_t)row * 256 + col] = f2bf(o);
      }
    }
  }
}

// ---------------- generic fp32 GEMM (small GRU matmuls) ----------------
__global__ __launch_bounds__(256) void gemm_f32(
    const float* __restrict__ A, const float* __restrict__ B,
    const float* __restrict__ bias, float* __restrict__ C,
    int M, int N, int K, int act) {
  __shared__ float As[16][68];
  __shared__ float Bs[16][64];
  const int id = threadIdx.x;
  const int tx = id & 15;
  const int ty = id >> 4;
  const int colblk = blockIdx.x * 64;
  const int rowblk = blockIdx.y * 64;
  const int lin = id * 4;
  const int ar = lin >> 4;
  const int ac = lin & 15;
  const int bc = lin >> 6;
  const int bcol = lin & 63;
  float acc[4][4] = {};
  for (int kt = 0; kt < K; kt += 16) {
    float4 a4 = *(const float4*)(A + (size_t)(rowblk + ar) * K + kt + ac);
    float4 b4 = *(const float4*)(B + (size_t)(kt + bc) * N + colblk + bcol);
    As[ac + 0][ar] = a4.x; As[ac + 1][ar] = a4.y;
    As[ac + 2][ar] = a4.z; As[ac + 3][ar] = a4.w;
    *(float4*)&Bs[bc][bcol] = b4;
    __syncthreads();
    #pragma unroll
    for (int kk = 0; kk < 16; ++kk) {
      float4 av = *(const float4*)&As[kk][ty * 4];
      float4 bv = *(const float4*)&Bs[kk][tx * 4];
      float a[4] = {av.x, av.y, av.z, av.w};
      float b[4] = {bv.x, bv.y, bv.z, bv.w};
      #pragma unroll
      for (int i = 0; i < 4; ++i)
        #pragma unroll
        for (int j = 0; j < 4; ++j) acc[i][j] += a[i] * b[j];
    }
    __syncthreads();
  }
  const int col = colblk + tx * 4;
  float4 bi = *(const float4*)(bias + col);
  #pragma unroll
  for (int i = 0; i < 4; ++i) {
    float r[4] = {acc[i][0] + bi.x, acc[i][1] + bi.y,
                  acc[i][2] + bi.z, acc[i][3] + bi.w};
    if (act == 2) {
      #pragma unroll
      for (int j = 0; j < 4; ++j) r[j] = expf(-fmaxf(r[j], 0.f));
    }
    *(float4*)(C + (size_t)(rowblk + ty * 4 + i) * N + col) =
        make_float4(r[0], r[1], r[2], r[3]);
  }
}

// ---------------- attention, single-pass, Q in registers ------------------
__global__ __launch_bounds__(128) void attn_kernel(
    const u16* __restrict__ qkv, const int* __restrict__ txt_lengths,
    u16* __restrict__ o) {
  __shared__ float Ks[128][32];
  __shared__ float Vs[128][32];
  int bh = blockIdx.x;
  int b = bh >> 3, h = bh & 7;
  int t = threadIdx.x;
  int len = txt_lengths[b] + 2;
  const size_t base = ((size_t)b * 128) * 768 + h * 32;
  // Q for this thread's own row -> registers (coalesced within groups)
  float4 qv[8];
  {
    const u16* qr = qkv + base + (size_t)t * 768;
    #pragma unroll
    for (int c = 0; c < 4; ++c) {
      uint4 q4 = *(const uint4*)(qr + c * 8);
      const u16* qs = (const u16*)&q4;
      qv[c * 2 + 0] = make_float4(bf2f(qs[0]), bf2f(qs[1]), bf2f(qs[2]),
                                  bf2f(qs[3]));
      qv[c * 2 + 1] = make_float4(bf2f(qs[4]), bf2f(qs[5]), bf2f(qs[6]),
                                  bf2f(qs[7]));
    }
    #pragma unroll
    for (int i = 0; i < 8; ++i) {
      qv[i].x *= 0.17677669529663687f; qv[i].y *= 0.17677669529663687f;
      qv[i].z *= 0.17677669529663687f; qv[i].w *= 0.17677669529663687f;
    }
  }
  // stage K/V into LDS
  #pragma unroll
  for (int p = 0; p < 4; ++p) {
    int idx = p * 128 + t;
    int row = idx >> 2, ch = idx & 3;
    size_t gofs = base + (size_t)row * 768 + ch * 8;
    uint4 kv4 = *(const uint4*)(qkv + gofs + 256);
    uint4 vv4 = *(const uint4*)(qkv + gofs + 512);
    const u16* ks = (const u16*)&kv4;
    const u16* vs = (const u16*)&vv4;
    #pragma unroll
    for (int e = 0; e < 8; ++e) {
      Ks[row][ch * 8 + e] = bf2f(ks[e]);
      Vs[row][ch * 8 + e] = bf2f(vs[e]);
    }
  }
  __syncthreads();
  float l = 0.f;
  float ov[32];
  #pragma unroll
  for (int d = 0; d < 32; ++d) ov[d] = 0.f;
  for (int j = 0; j < len; ++j) {
    const float4* kr = (const float4*)&Ks[j][0];
    float s = 0.f;
    #pragma unroll
    for (int i = 0; i < 8; ++i) {
      float4 kk = kr[i];
      s += qv[i].x * kk.x + qv[i].y * kk.y + qv[i].z * kk.z + qv[i].w * kk.w;
    }
    float p = __expf(s);
    l += p;
    const float4* vr = (const float4*)&Vs[j][0];
    #pragma unroll
    for (int i = 0; i < 8; ++i) {
      float4 vvv = vr[i];
      ov[i * 4 + 0] += p * vvv.x; ov[i * 4 + 1] += p * vvv.y;
      ov[i * 4 + 2] += p * vvv.z; ov[i * 4 + 3] += p * vvv.w;
    }
  }
  float inv = 1.f / l;
  u16 ob[32];
  #pragma unroll
  for (int d = 0; d < 32; ++d) ob[d] = f2bf(ov[d] * inv);
  u16* orow = o + ((size_t)(b * 128 + t)) * 256 + h * 32;
  #pragma unroll
  for (int c = 0; c < 4; ++c)
    *(uint4*)(orow + c * 8) = *(const uint4*)&ob[c * 8];
}

// ---------------- GRU-D input imputation + concat ----------------
__global__ void impute_kernel(
    const float* __restrict__ x1, const float* __restrict__ m1,
    const float* __restrict__ d1, const float* __restrict__ dec_w,
    const float* __restrict__ dec_b, const float* __restrict__ x_m,
    float* __restrict__ xprep, float* __restrict__ dprep) {
  int idx = blockIdx.x * 256 + threadIdx.x;
  if (idx >= 256 * 24 * 16) return;
  int f = idx & 15;
  int t = (idx >> 4) % 24;
  int b = idx / (24 * 16);
  int src = (b * 36 + t) * 16 + f;
  float x = x1[src], m = m1[src], d = d1[src];
  float xd = expf(-fmaxf(d * dec_w[f] + dec_b[f], 0.f));
  float xv = m * x + (1.f - m) * xd * x + (1.f - m) * (1.f - xd) * x_m[f];
  int dst = b * 24 + t;
  xprep[dst * 32 + f] = xv;
  xprep[dst * 32 + 16 + f] = m;
  dprep[dst * 16 + f] = d;
}

// ------- GRU scan (R11 MFMA): 128 blocks x 2 batches, 256 threads ---------
// WhhT: bf16 [768][256] = W_hh^T. A = 16x256 (rows 0,1 = batches, rest 0).
__global__ __launch_bounds__(256) void gru_scan_mfma(
    const float* __restrict__ gx, const float* __restrict__ hdcyb,
    const u16* __restrict__ WhhT, const float* __restrict__ b_hh,
    const float* __restrict__ h0, float* __restrict__ ys) {
  __shared__ float hf[2][256];
  __shared__ u16 hbf[16][264];   // rows 2..15 zero
  __shared__ float gls[2][768];
  const int b0 = blockIdx.x * 2;
  const int tid = threadIdx.x;
  const int wave = tid >> 6, lane = tid & 63;
  const int l16 = lane & 15, lq = lane >> 4;
  #pragma unroll
  for (int r = 2; r < 16; ++r) hbf[r][tid] = 0;
  for (int i = tid; i < 512; i += 256) {
    int bb = i >> 8, col = i & 255;
    float v = h0[(size_t)(b0 + bb) * 256 + col] *
              hdcyb[(size_t)((b0 + bb) * 24) * 256 + col];
    hf[bb][col] = v;
    hbf[bb][col] = f2bf(v);
  }
  const float bh0 = b_hh[tid], bh1 = b_hh[256 + tid], bh2 = b_hh[512 + tid];
  __syncthreads();
  for (int t = 0; t < 24; ++t) {
    // matvec via MFMA: wave covers cols [wave*192, +192) in 12 tiles of 16
    f32x4 acc[12];
    #pragma unroll
    for (int n = 0; n < 12; ++n) acc[n] = (f32x4)(0.f);
    #pragma unroll
    for (int kt = 0; kt < 8; ++kt) {
      bf16x8 af = *(const bf16x8*)&hbf[l16][kt * 32 + lq * 8];
      #pragma unroll
      for (int n = 0; n < 12; ++n) {
        int col0 = wave * 192 + n * 16;
        bf16x8 bf = *(const bf16x8*)(WhhT + (size_t)(col0 + l16) * 256 +
                                     kt * 32 + lq * 8);
        acc[n] =
            __builtin_amdgcn_mfma_f32_16x16x32_bf16(af, bf, acc[n], 0, 0, 0);
      }
    }
    if (lq == 0) {
      #pragma unroll
      for (int n = 0; n < 12; ++n) {
        int col = wave * 192 + n * 16 + l16;
        gls[0][col] = acc[n][0];
        gls[1][col] = acc[n][1];
      }
    }
    __syncthreads();
    #pragma unroll
    for (int bb = 0; bb < 2; ++bb) {
      const float* gxr = gx + (size_t)((b0 + bb) * 24 + t) * 768;
      int col = tid;
      float r = 1.f / (1.f + __expf(-(gxr[col] + gls[bb][col] + bh0)));
      float z =
          1.f / (1.f + __expf(-(gxr[256 + col] + gls[bb][256 + col] + bh1)));
      float n = tanhf(gxr[512 + col] + r * (gls[bb][512 + col] + bh2));
      float h1d = hf[bb][col];
      float hn = (1.f - z) * n + z * h1d;
      ys[(size_t)(t * 256 + b0 + bb) * 256 + col] = hn;
      float nxt = (t < 23)
                      ? hdcyb[(size_t)((b0 + bb) * 24 + t + 1) * 256 + col]
                      : 1.f;
      float hd = hn * nxt;
      hf[bb][col] = hd;
      hbf[bb][col] = f2bf(hd);
    }
    __syncthreads();
  }
}

// ------- c_t = LN(concat(...)) + pred + masked-MSE (merged) ---------------
__global__ __launch_bounds__(256) void ct_pred_kernel(
    const float* __restrict__ ys, const u16* __restrict__ hddbf,
    const int* __restrict__ input_lengths, const float* __restrict__ age,
    const float* __restrict__ gen, const float* __restrict__ g,
    const float* __restrict__ bb, float* __restrict__ c_t,
    const float* __restrict__ ct_w, const float* __restrict__ x1,
    const float* __restrict__ f_ind, float* __restrict__ accum) {
  __shared__ float buf[514];
  __shared__ float ctl[514];
  __shared__ float red[8];
  __shared__ float sq[192];
  int b = blockIdx.x, tid = threadIdx.x;
  int il = input_lengths[b] - 1;
  buf[tid] = ys[(size_t)(il * 256 + b) * 256 + tid];
  buf[256 + tid] = bf2f(hddbf[(size_t)(b * 128) * 256 + tid]);
  if (tid < 2) buf[512 + tid] = (tid == 0) ? age[b] : gen[b];
  __syncthreads();
  float p = buf[tid] + buf[256 + tid] + (tid < 2 ? buf[512 + tid] : 0.f);
  float mean = blockReduceSum(p, red) / 514.f;
  float d0 = buf[tid] - mean;
  float d1 = buf[256 + tid] - mean;
  float dq = (tid < 2) ? (buf[512 + tid] - mean) : 0.f;
  float var = blockReduceSum(d0 * d0 + d1 * d1 + dq * dq, red) / 514.f;
  float rs = rsqrtf(var + 1e-5f);
  float c0 = d0 * rs * g[tid] + bb[tid];
  float c1 = d1 * rs * g[256 + tid] + bb[256 + tid];
  ctl[tid] = c0;
  ctl[256 + tid] = c1;
  c_t[(size_t)b * 514 + tid] = c0;
  c_t[(size_t)b * 514 + 256 + tid] = c1;
  if (tid < 2) {
    float c2 = dq * rs * g[512 + tid] + bb[512 + tid];
    ctl[512 + tid] = c2;
    c_t[(size_t)b * 514 + 512 + tid] = c2;
  }
  __syncthreads();
  if (tid < 192) {
    int t = tid >> 4, f = tid & 15;
    float acc = 0.f;
    for (int c = 0; c < 514; ++c)
      acc += ctl[c] * ct_w[(size_t)(t * 514 + c) * 16 + f];
    float diff = acc - x1[(size_t)(b * 36 + 24 + t) * 16 + f];
    sq[tid] = diff * diff;
  }
  __syncthreads();
  if (tid < 12) {
    float s = 0.f;
    #pragma unroll
    for (int f = 0; f < 16; ++f) s += sq[tid * 16 + f];
    float w = f_ind[b * 12 + tid];
    atomicAdd(&accum[0], (s * (1.f / 16.f)) * w);
    atomicAdd(&accum[1], w);
  }
}

// ---------------- z1 = c_t @ fc_W1 + fc_b1 ----------------
__global__ __launch_bounds__(64) void fc1_kernel(
    const float* __restrict__ c_t, const float* __restrict__ fc_W1,
    const float* __restrict__ fc_b1, float* __restrict__ z1) {
  int t = blockIdx.x, b = blockIdx.y, dd = threadIdx.x;
  __shared__ float ct[514];
  for (int i = dd; i < 514; i += 64) ct[i] = c_t[(size_t)b * 514 + i];
  __syncthreads();
  float acc = fc_b1[t * 64 + dd];
  for (int c = 0; c < 514; ++c)
    acc += ct[c] * fc_W1[(size_t)(t * 514 + c) * 64 + dd];
  z1[(size_t)(t * 256 + b) * 64 + dd] = acc;
}

// ---------------- batchnorm stats over B per (t, dd) ----------------
__global__ __launch_bounds__(256) void bn_stats_kernel(
    const float* __restrict__ z1, float* __restrict__ mu,
    float* __restrict__ rstd) {
  __shared__ float red[8];
  int t = blockIdx.x >> 6;
  int dd = blockIdx.x & 63;
  int b = threadIdx.x;
  float v = z1[(size_t)(t * 256 + b) * 64 + dd];
  float mean = blockReduceSum(v, red) * (1.f / 256.f);
  float d = v - mean;
  float var = blockReduceSum(d * d, red) * (1.f / 256.f);
  if (b == 0) {
    mu[t * 64 + dd] = mean;
    rstd[t * 64 + dd] = rsqrtf(var + 1e-5f);
  }
}

// ---------------- out = relu(bn(z1)) @ fc_W2 + fc_b2 ----------------
__global__ __launch_bounds__(64) void out_kernel(
    const float* __restrict__ z1, const float* __restrict__ mu,
    const float* __restrict__ rstd, const float* __restrict__ bn_g,
    const float* __restrict__ bn_b, const float* __restrict__ fc_W2,
    const float* __restrict__ fc_b2, float* __restrict__ out) {
  int t = blockIdx.x, b = blockIdx.y, dd = threadIdx.x;
  float v = z1[(size_t)(t * 256 + b) * 64 + dd];
  float zn = (v - mu[t * 64 + dd]) * rstd[t * 64 + dd] * bn_g[t * 64 + dd] +
             bn_b[t * 64 + dd];
  float val = fmaxf(zn, 0.f) * fc_W2[t * 64 + dd];
  #pragma unroll
  for (int off = 32; off > 0; off >>= 1) val += __shfl_down(val, off, 64);
  if (dd == 0) out[t * 256 + b] = val + fc_b2[t];
}

__global__ void loss_final_kernel(const float* __restrict__ accum,
                                  float* __restrict__ out) {
  out[0] = accum[0] / accum[1];
}

// =======================================================================
extern "C" void kernel_launch(void* const* d_in, const int* in_sizes, int n_in,
                              void* d_out, int out_size, void* d_ws,
                              size_t ws_size, hipStream_t stream) {
  const float* x1 = (const float*)d_in[0];
  const float* h0 = (const float*)d_in[1];
  const float* m1 = (const float*)d_in[2];
  const float* d1 = (const float*)d_in[3];
  const float* x_m = (const float*)d_in[4];
  const float* age = (const float*)d_in[5];
  const float* gen = (const float*)d_in[6];
  const int* input_lengths = (const int*)d_in[7];
  const int* txts = (const int*)d_in[8];
  const int* txt_lengths = (const int*)d_in[9];
  const float* f_ind = (const float*)d_in[10];
  const float* emb = (const float*)d_in[11];
  const float* Win = (const float*)d_in[12];
  const float* bin_ = (const float*)d_in[13];
  const float* ln_in_g = (const float*)d_in[14];
  const float* ln_in_b = (const float*)d_in[15];
  const float* Wq = (const float*)d_in[16];
  const float* bq = (const float*)d_in[17];
  const float* Wk = (const float*)d_in[18];
  const float* bk = (const float*)d_in[19];
  const float* Wv = (const float*)d_in[20];
  const float* bv = (const float*)d_in[21];
  const float* Wo = (const float*)d_in[22];
  const float* bo = (const float*)d_in[23];
  const float* ln1_g = (const float*)d_in[24];
  const float* ln1_b = (const float*)d_in[25];
  const float* Wf1 = (const float*)d_in[26];
  const float* bf1 = (const float*)d_in[27];
  const float* Wf2 = (const float*)d_in[28];
  const float* bf2 = (const float*)d_in[29];
  const float* ln2_g = (const float*)d_in[30];
  const float* ln2_b = (const float*)d_in[31];
  const float* dec_w = (const float*)d_in[32];
  const float* dec_b = (const float*)d_in[33];
  const float* hd_W = (const float*)d_in[34];
  const float* hd_b = (const float*)d_in[35];
  const float* W_ih = (const float*)d_in[36];
  const float* b_ih = (const float*)d_in[37];
  const float* W_hh = (const float*)d_in[38];
  const float* b_hh = (const float*)d_in[39];
  const float* ln_c_g = (const float*)d_in[40];
  const float* ln_c_b = (const float*)d_in[41];
  const float* ct_w = (const float*)d_in[42];
  const float* fc_W1 = (const float*)d_in[43];
  const float* fc_b1 = (const float*)d_in[44];
  const float* bn_g = (const float*)d_in[45];
  const float* bn_b = (const float*)d_in[46];
  const float* fc_W2 = (const float*)d_in[47];
  const float* fc_b2 = (const float*)d_in[48];
  float* out = (float*)d_out;

  // ---- workspace layout (bytes) ----
  char* base = (char*)d_ws;
  u16* hdd_bf = (u16*)(base + 0);             // 16.8 MB (residual stream)
  u16* qkvb = (u16*)(base + 16777216);        // 50.3 MB
  u16* ob = (u16*)(base + 67108864);          // 16.8 MB (also tx_bf)
  u16* WinT = (u16*)(base + 83886080);        // 65536 el
  u16* WqkvT = WinT + 65536;                  // 4 x 196608 el
  u16* WoT = WqkvT + 786432;                  // 4 x 65536 el
  u16* Wf1T = WoT + 262144;                   // 4 x 131072 el
  u16* Wf2T = Wf1T + 524288;                  // 4 x 131072 el
  float* bqkv = (float*)(base + 88211456);    // 3072 f32
  float* pe = (float*)(base + 88223744);      // 128 KB
  u16* WhhT = (u16*)(base + 88354816);        // 384 KB bf16 [768][256]
  // GRU/head overlay over qkvb/ob (dead post-transformer); hdd_bf stays live
  char* gru = base + 16777216;
  float* xprep = (float*)gru;                 // 786432 B
  float* dprep = (float*)(gru + 786432);      // 393216 B
  float* gx = (float*)(gru + 1179648);        // 18874368 B
  float* hdcyb = (float*)(gru + 20054016);    // 6291456 B
  float* ys = (float*)(gru + 26345472);       // 6291456 B
  float* c_t = (float*)(gru + 32636928);      // 526336 B
  float* z1 = (float*)(gru + 33163264);       // 786432 B
  float* muv = (float*)(gru + 33949696);
  float* rstdv = (float*)(gru + 33952768);
  float* accum = (float*)(gru + 33955840);

  hipMemsetAsync(accum, 0, 2 * sizeof(float), stream);

  // ---- weight conversion ----
  transpose_bf16<<<dim3(8, 8, 1), 256, 0, stream>>>(Win, WinT, 256, 256, 65536);
  transpose_qkvo<<<dim3(8, 8, 16), 256, 0, stream>>>(Wq, Wk, Wv, Wo, WqkvT,
                                                     WoT);
  transpose_bf16<<<dim3(16, 8, 4), 256, 0, stream>>>(Wf1, Wf1T, 256, 512,
                                                     131072);
  transpose_bf16<<<dim3(8, 16, 4), 256, 0, stream>>>(Wf2, Wf2T, 512, 256,
                                                     131072);
  transpose_bf16<<<dim3(24, 8, 1), 256, 0, stream>>>(W_hh, WhhT, 256, 768,
                                                     196608);
  bias_concat_kernel<<<4, 768, 0, stream>>>(bq, bk, bv, bqkv);

  // ---- text transformer ----
  pe_kernel<<<128, 256, 0, stream>>>(pe);
  gather_kernel<<<8192, 256, 0, stream>>>(txts, emb, ob);  // tx in ob
  gemm_ln<<<512, 256, 0, stream>>>(ob, WinT, bin_, ln_in_g, ln_in_b, pe,
                                   hdd_bf, 32768, 256, 1);
  for (int l = 0; l < 4; ++l) {
    gemm_bf16<<<dim3(6, 256), 256, 0, stream>>>(hdd_bf, WqkvT + l * 196608,
                                                bqkv + l * 768, qkvb, 32768,
                                                768, 256, 0);
    attn_kernel<<<2048, 128, 0, stream>>>(qkvb, txt_lengths, ob);
    gemm_ln<<<512, 256, 0, stream>>>(ob, WoT + l * 65536, bo + l * 256,
                                     ln1_g + l * 256, ln1_b + l * 256, pe,
                                     hdd_bf, 32768, 256, 0);
    ffn_ln<<<512, 512, 0, stream>>>(hdd_bf, Wf1T + l * 131072, bf1 + l * 512,
                                    Wf2T + l * 131072, bf2 + l * 256,
                                    ln2_g + l * 256, ln2_b + l * 256, hdd_bf,
                                    32768);
  }

  // ---- GRU-D branch ----
  impute_kernel<<<384, 256, 0, stream>>>(x1, m1, d1, dec_w, dec_b, x_m, xprep,
                                         dprep);
  gemm_f32<<<dim3(12, 96), 256, 0, stream>>>(xprep, W_ih, b_ih, gx, 6144, 768,
                                             32, 0);
  gemm_f32<<<dim3(4, 96), 256, 0, stream>>>(dprep, hd_W, hd_b, hdcyb, 6144,
                                            256, 16, 2);
  gru_scan_mfma<<<128, 256, 0, stream>>>(gx, hdcyb, WhhT, b_hh, h0, ys);

  // ---- head ----
  ct_pred_kernel<<<256, 256, 0, stream>>>(ys, hdd_bf, input_lengths, age, gen,
                                          ln_c_g, ln_c_b, c_t, ct_w, x1, f_ind,
                                          accum);
  fc1_kernel<<<dim3(12, 256), 64, 0, stream>>>(c_t, fc_W1, fc_b1, z1);
  bn_stats_kernel<<<768, 256, 0, stream>>>(z1, muv, rstdv);
  out_kernel<<<dim3(12, 256), 64, 0, stream>>>(z1, muv, rstdv, bn_g, bn_b,
                                               fc_W2, fc_b2, out);
  loss_final_kernel<<<1, 1, 0, stream>>>(accum, out + 3072);
}

// Round 14
// 1145.368 us; speedup vs baseline: 1.5765x; 1.2829x over previous
//
#include <hip/hip_runtime.h>
#include <math.h>

typedef unsigned short u16;
typedef unsigned int u32;
typedef short bf16x8 __attribute__((ext_vector_type(8)));
typedef float f32x4 __attribute__((ext_vector_type(4)));

__device__ __forceinline__ u16 f2bf(float f) {
  u32 u = __float_as_uint(f);
  u32 r = (u + 0x7fffu + ((u >> 16) & 1u)) >> 16;
  return (u16)r;
}
__device__ __forceinline__ float bf2f(u16 h) {
  return __uint_as_float(((u32)h) << 16);
}
// async global->LDS, 16B per lane; LDS dest = wave-uniform base + lane*16
__device__ __forceinline__ void gload_lds16(const u16* g, u16* l) {
  __builtin_amdgcn_global_load_lds(
      (const __attribute__((address_space(1))) void*)g,
      (__attribute__((address_space(3))) void*)l, 16, 0, 0);
}
__device__ __forceinline__ float blockReduceSum(float v, float* red) {
  #pragma unroll
  for (int off = 32; off > 0; off >>= 1) v += __shfl_down(v, off, 64);
  const int lane = threadIdx.x & 63;
  const int wid = threadIdx.x >> 6;
  __syncthreads();
  if (lane == 0) red[wid] = v;
  __syncthreads();
  const int nw = (blockDim.x + 63) >> 6;
  float s = red[0];
  for (int i = 1; i < nw; ++i) s += red[i];
  return s;
}

// ---------------- positional encoding ----------------
__global__ void pe_kernel(float* __restrict__ pe) {
  int l = blockIdx.x;
  int i = threadIdx.x;
  double e = exp2(-(double)(2 * (i / 2)) / 256.0 * 13.287712379549449);
  double ang = (double)l * e;
  pe[l * 256 + i] = (float)((i & 1) ? cos(ang) : sin(ang));
}

// ---------------- embedding gather -> bf16 (wave per row) ----------------
__global__ __launch_bounds__(256) void gather_kernel(
    const int* __restrict__ txts, const float* __restrict__ emb,
    u16* __restrict__ tx) {
  int row = blockIdx.x * 4 + (threadIdx.x >> 6);
  int lane = threadIdx.x & 63;
  int tok = txts[row];
  float4 e = *(const float4*)(emb + (size_t)tok * 256 + lane * 4);
  u16 o[4] = {f2bf(e.x), f2bf(e.y), f2bf(e.z), f2bf(e.w)};
  *(uint2*)(tx + (size_t)row * 256 + lane * 4) = *(const uint2*)o;
}

// ------- weight transpose fp32[K][N] -> bf16[N][K], custom group stride ----
__global__ __launch_bounds__(256) void transpose_bf16(
    const float* __restrict__ W, u16* __restrict__ Wt, int K, int N,
    int dstStride) {
  __shared__ float tile[32][33];
  int g = blockIdx.z;
  const float* Wg = W + (size_t)g * K * N;
  u16* Wtg = Wt + (size_t)g * dstStride;
  int n0 = blockIdx.x * 32, k0 = blockIdx.y * 32;
  int tx = threadIdx.x & 31, ty = threadIdx.x >> 5;
  #pragma unroll
  for (int i = 0; i < 32; i += 8)
    tile[ty + i][tx] = Wg[(size_t)(k0 + ty + i) * N + n0 + tx];
  __syncthreads();
  #pragma unroll
  for (int i = 0; i < 32; i += 8)
    Wtg[(size_t)(n0 + ty + i) * K + k0 + tx] = f2bf(tile[tx][ty + i]);
}

// ------- merged transpose for Wq/Wk/Wv/Wo (all [4][256][256]) -------------
__global__ __launch_bounds__(256) void transpose_qkvo(
    const float* __restrict__ Wq, const float* __restrict__ Wk,
    const float* __restrict__ Wv, const float* __restrict__ Wo,
    u16* __restrict__ WqkvT, u16* __restrict__ WoT) {
  __shared__ float tile[32][33];
  int z = blockIdx.z, l = z >> 2, which = z & 3;
  const float* src = (which == 0) ? Wq : (which == 1) ? Wk
                     : (which == 2) ? Wv : Wo;
  src += (size_t)l * 65536;
  u16* dst = (which < 3) ? (WqkvT + (size_t)l * 196608 + which * 65536)
                         : (WoT + (size_t)l * 65536);
  int n0 = blockIdx.x * 32, k0 = blockIdx.y * 32;
  int tx = threadIdx.x & 31, ty = threadIdx.x >> 5;
  #pragma unroll
  for (int i = 0; i < 32; i += 8)
    tile[ty + i][tx] = src[(size_t)(k0 + ty + i) * 256 + n0 + tx];
  __syncthreads();
  #pragma unroll
  for (int i = 0; i < 32; i += 8)
    dst[(size_t)(n0 + ty + i) * 256 + k0 + tx] = f2bf(tile[tx][ty + i]);
}

// ---------------- concat qkv bias ----------------
__global__ void bias_concat_kernel(const float* __restrict__ bq,
                                   const float* __restrict__ bk,
                                   const float* __restrict__ bv,
                                   float* __restrict__ bqkv) {
  int l = blockIdx.x, i = threadIdx.x;
  float v;
  if (i < 256) v = bq[l * 256 + i];
  else if (i < 512) v = bk[l * 256 + i - 256];
  else v = bv[l * 256 + i - 512];
  bqkv[l * 768 + i] = v;
}

// ---------------- bf16 MFMA GEMM, 128x128 tile (m97 shape) ----------------
// grid (N/128, M/128), block 256 (4 waves: 2x2). act: 0 none, 1 relu.
__global__ __launch_bounds__(256) void gemm_bf16(
    const u16* __restrict__ A, const u16* __restrict__ Bt,
    const float* __restrict__ bias, u16* __restrict__ Cb, int M, int N, int K,
    int act) {
  __shared__ u16 As[128][32];
  __shared__ u16 Bs[128][32];
  const int tid = threadIdx.x;
  const int wave = tid >> 6, lane = tid & 63;
  const int wr = wave >> 1, wc = wave & 1;
  const int rowblk = blockIdx.y * 128, colblk = blockIdx.x * 128;
  const int l16 = lane & 15, lq = lane >> 4;
  const int lr = lane >> 2, lc = lane & 3;
  const int r0 = wave * 32;
  f32x4 acc[4][4];
  #pragma unroll
  for (int i = 0; i < 4; ++i)
    #pragma unroll
    for (int j = 0; j < 4; ++j) acc[i][j] = (f32x4)(0.f);

  for (int kt = 0; kt < K; kt += 32) {
    __syncthreads();
    gload_lds16(A + (size_t)(rowblk + r0 + lr) * K + kt + lc * 8, &As[r0][0]);
    gload_lds16(A + (size_t)(rowblk + r0 + 16 + lr) * K + kt + lc * 8,
                &As[r0 + 16][0]);
    gload_lds16(Bt + (size_t)(colblk + r0 + lr) * K + kt + lc * 8, &Bs[r0][0]);
    gload_lds16(Bt + (size_t)(colblk + r0 + 16 + lr) * K + kt + lc * 8,
                &Bs[r0 + 16][0]);
    __syncthreads();
    bf16x8 af[4], bfr[4];
    #pragma unroll
    for (int t = 0; t < 4; ++t) {
      af[t] = *(const bf16x8*)&As[wr * 64 + t * 16 + l16][lq * 8];
      bfr[t] = *(const bf16x8*)&Bs[wc * 64 + t * 16 + l16][lq * 8];
    }
    #pragma unroll
    for (int i = 0; i < 4; ++i)
      #pragma unroll
      for (int j = 0; j < 4; ++j)
        acc[i][j] = __builtin_amdgcn_mfma_f32_16x16x32_bf16(af[i], bfr[j],
                                                            acc[i][j], 0, 0, 0);
  }
  const int rbase = rowblk + wr * 64, cbase = colblk + wc * 64;
  #pragma unroll
  for (int j = 0; j < 4; ++j) {
    int col = cbase + j * 16 + l16;
    float bv = bias[col];
    #pragma unroll
    for (int i = 0; i < 4; ++i) {
      int row0 = rbase + i * 16 + lq * 4;
      #pragma unroll
      for (int r = 0; r < 4; ++r) {
        float vv = acc[i][j][r] + bv;
        if (act == 1) vv = fmaxf(vv, 0.f);
        Cb[(size_t)(row0 + r) * N + col] = f2bf(vv);
      }
    }
  }
}

// ------- fused GEMM (N=256) + bf16 residual/PE + LayerNorm -----------------
// 64-row blocks, 256 threads (4 col-waves). grid = M/64.
__global__ __launch_bounds__(256) void gemm_ln(
    const u16* __restrict__ A, const u16* __restrict__ Bt,
    const float* __restrict__ bias, const float* __restrict__ g,
    const float* __restrict__ bvec, const float* __restrict__ pe,
    u16* __restrict__ hddbf, int M, int K, int mode) {
  __shared__ u16 As[64][32];
  __shared__ u16 Bs[256][32];
  __shared__ float redS[4][64];
  __shared__ float redQ[4][64];
  __shared__ float rowstat[64][2];
  const int tid = threadIdx.x;
  const int wave = tid >> 6, lane = tid & 63;
  const int wc = wave;
  const int rowblk = blockIdx.x * 64;
  const int l16 = lane & 15, lq = lane >> 4;
  const int lr = lane >> 2, lc = lane & 3;
  f32x4 acc[4][4];
  #pragma unroll
  for (int i = 0; i < 4; ++i)
    #pragma unroll
    for (int j = 0; j < 4; ++j) acc[i][j] = (f32x4)(0.f);

  for (int kt = 0; kt < K; kt += 32) {
    __syncthreads();
    gload_lds16(A + (size_t)(rowblk + wave * 16 + lr) * K + kt + lc * 8,
                &As[wave * 16][0]);
    #pragma unroll
    for (int p = 0; p < 4; ++p)
      gload_lds16(Bt + (size_t)(wave * 64 + p * 16 + lr) * K + kt + lc * 8,
                  &Bs[wave * 64 + p * 16][0]);
    __syncthreads();
    bf16x8 af[4], bfr[4];
    #pragma unroll
    for (int t = 0; t < 4; ++t) {
      af[t] = *(const bf16x8*)&As[t * 16 + l16][lq * 8];
      bfr[t] = *(const bf16x8*)&Bs[wc * 64 + t * 16 + l16][lq * 8];
    }
    #pragma unroll
    for (int i = 0; i < 4; ++i)
      #pragma unroll
      for (int j = 0; j < 4; ++j)
        acc[i][j] = __builtin_amdgcn_mfma_f32_16x16x32_bf16(af[i], bfr[j],
                                                            acc[i][j], 0, 0, 0);
  }
  const int cbase = wc * 64;
  #pragma unroll
  for (int j = 0; j < 4; ++j) {
    int col = cbase + j * 16 + l16;
    float bv = bias[col];
    #pragma unroll
    for (int i = 0; i < 4; ++i) {
      int row0 = rowblk + i * 16 + lq * 4;
      #pragma unroll
      for (int r = 0; r < 4; ++r) {
        float v = acc[i][j][r] + bv;
        if (mode == 0) v += bf2f(hddbf[(size_t)(row0 + r) * 256 + col]);
        acc[i][j][r] = v;
      }
    }
  }
  #pragma unroll
  for (int i = 0; i < 4; ++i) {
    #pragma unroll
    for (int r = 0; r < 4; ++r) {
      float s = 0.f, q = 0.f;
      #pragma unroll
      for (int j = 0; j < 4; ++j) {
        float v = acc[i][j][r];
        s += v;
        q += v * v;
      }
      #pragma unroll
      for (int m = 1; m < 16; m <<= 1) {
        s += __shfl_xor(s, m, 64);
        q += __shfl_xor(q, m, 64);
      }
      if (l16 == 0) {
        int lrr = i * 16 + lq * 4 + r;
        redS[wc][lrr] = s;
        redQ[wc][lrr] = q;
      }
    }
  }
  __syncthreads();
  if (tid < 64) {
    float s = redS[0][tid] + redS[1][tid] + redS[2][tid] + redS[3][tid];
    float q = redQ[0][tid] + redQ[1][tid] + redQ[2][tid] + redQ[3][tid];
    float mean = s * (1.f / 256.f);
    float var = q * (1.f / 256.f) - mean * mean;
    rowstat[tid][0] = mean;
    rowstat[tid][1] = rsqrtf(var + 1e-5f);
  }
  __syncthreads();
  float gg[4], bb2[4];
  #pragma unroll
  for (int j = 0; j < 4; ++j) {
    int col = cbase + j * 16 + l16;
    gg[j] = g[col];
    bb2[j] = bvec[col];
  }
  #pragma unroll
  for (int i = 0; i < 4; ++i) {
    #pragma unroll
    for (int r = 0; r < 4; ++r) {
      int lrr = i * 16 + lq * 4 + r;
      int row = rowblk + lrr;
      float mean = rowstat[lrr][0], rstd = rowstat[lrr][1];
      #pragma unroll
      for (int j = 0; j < 4; ++j) {
        int col = cbase + j * 16 + l16;
        float o = (acc[i][j][r] - mean) * rstd * gg[j] + bb2[j];
        if (mode == 1) o += pe[(size_t)(row & 127) * 256 + col];
        hddbf[(size_t)row * 256 + col] = f2bf(o);
      }
    }
  }
}

// ------- fused FFN: relu(A@W1+b1)@W2+b2 + residual + LN --------------------
__global__ __launch_bounds__(512) void ffn_ln(
    const u16* __restrict__ A, const u16* __restrict__ W1t,
    const float* __restrict__ b1, const u16* __restrict__ W2t,
    const float* __restrict__ b2, const float* __restrict__ g,
    const float* __restrict__ bvec, u16* __restrict__ hddbf, int M) {
  __shared__ u16 As[64][264];
  __shared__ u16 Fs[64][520];
  __shared__ float redS[4][64];
  __shared__ float redQ[4][64];
  __shared__ float rowstat[64][2];
  const int tid = threadIdx.x;
  const int wave = tid >> 6, lane = tid & 63;
  const int l16 = lane & 15, lq = lane >> 4;
  const int rowblk = blockIdx.x * 64;
  for (int i = tid; i < 2048; i += 512) {
    int row = i >> 5, ch = i & 31;
    *(uint4*)&As[row][ch * 8] =
        *(const uint4*)(A + (size_t)(rowblk + row) * 256 + ch * 8);
  }
  __syncthreads();
  {
    f32x4 acc1[4][4];
    #pragma unroll
    for (int i = 0; i < 4; ++i)
      #pragma unroll
      for (int j = 0; j < 4; ++j) acc1[i][j] = (f32x4)(0.f);
    #pragma unroll
    for (int kt = 0; kt < 8; ++kt) {
      bf16x8 af[4], bfr[4];
      #pragma unroll
      for (int t = 0; t < 4; ++t) {
        af[t] = *(const bf16x8*)&As[t * 16 + l16][kt * 32 + lq * 8];
        bfr[t] = *(const bf16x8*)(W1t +
                                  (size_t)(wave * 64 + t * 16 + l16) * 256 +
                                  kt * 32 + lq * 8);
      }
      #pragma unroll
      for (int i = 0; i < 4; ++i)
        #pragma unroll
        for (int j = 0; j < 4; ++j)
          acc1[i][j] = __builtin_amdgcn_mfma_f32_16x16x32_bf16(
              af[i], bfr[j], acc1[i][j], 0, 0, 0);
    }
    #pragma unroll
    for (int j = 0; j < 4; ++j) {
      int col = wave * 64 + j * 16 + l16;
      float bias1 = b1[col];
      #pragma unroll
      for (int i = 0; i < 4; ++i) {
        int row0 = i * 16 + lq * 4;
        #pragma unroll
        for (int r = 0; r < 4; ++r)
          Fs[row0 + r][col] = f2bf(fmaxf(acc1[i][j][r] + bias1, 0.f));
      }
    }
  }
  __syncthreads();
  const int wr = wave >> 2, wc = wave & 3;
  f32x4 acc2[2][4];
  #pragma unroll
  for (int i = 0; i < 2; ++i)
    #pragma unroll
    for (int j = 0; j < 4; ++j) acc2[i][j] = (f32x4)(0.f);
  #pragma unroll
  for (int kt = 0; kt < 16; ++kt) {
    bf16x8 af[2], bfr[4];
    #pragma unroll
    for (int i = 0; i < 2; ++i)
      af[i] = *(const bf16x8*)&Fs[wr * 32 + i * 16 + l16][kt * 32 + lq * 8];
    #pragma unroll
    for (int j = 0; j < 4; ++j)
      bfr[j] = *(const bf16x8*)(W2t + (size_t)(wc * 64 + j * 16 + l16) * 512 +
                                kt * 32 + lq * 8);
    #pragma unroll
    for (int i = 0; i < 2; ++i)
      #pragma unroll
      for (int j = 0; j < 4; ++j)
        acc2[i][j] = __builtin_amdgcn_mfma_f32_16x16x32_bf16(af[i], bfr[j],
                                                             acc2[i][j], 0, 0,
                                                             0);
  }
  #pragma unroll
  for (int j = 0; j < 4; ++j) {
    int col = wc * 64 + j * 16 + l16;
    float bias2 = b2[col];
    #pragma unroll
    for (int i = 0; i < 2; ++i) {
      int row0 = rowblk + wr * 32 + i * 16 + lq * 4;
      #pragma unroll
      for (int r = 0; r < 4; ++r)
        acc2[i][j][r] += bias2 + bf2f(hddbf[(size_t)(row0 + r) * 256 + col]);
    }
  }
  #pragma unroll
  for (int i = 0; i < 2; ++i) {
    #pragma unroll
    for (int r = 0; r < 4; ++r) {
      float s = 0.f, q = 0.f;
      #pragma unroll
      for (int j = 0; j < 4; ++j) {
        float v = acc2[i][j][r];
        s += v;
        q += v * v;
      }
      #pragma unroll
      for (int m = 1; m < 16; m <<= 1) {
        s += __shfl_xor(s, m, 64);
        q += __shfl_xor(q, m, 64);
      }
      if (l16 == 0) {
        int lrr = wr * 32 + i * 16 + lq * 4 + r;
        redS[wc][lrr] = s;
        redQ[wc][lrr] = q;
      }
    }
  }
  __syncthreads();
  if (tid < 64) {
    float s = redS[0][tid] + redS[1][tid] + redS[2][tid] + redS[3][tid];
    float q = redQ[0][tid] + redQ[1][tid] + redQ[2][tid] + redQ[3][tid];
    float mean = s * (1.f / 256.f);
    float var = q * (1.f / 256.f) - mean * mean;
    rowstat[tid][0] = mean;
    rowstat[tid][1] = rsqrtf(var + 1e-5f);
  }
  __syncthreads();
  #pragma unroll
  for (int j = 0; j < 4; ++j) {
    int col = wc * 64 + j * 16 + l16;
    float gg = g[col], bb2v = bvec[col];
    #pragma unroll
    for (int i = 0; i < 2; ++i) {
      #pragma unroll
      for (int r = 0; r < 4; ++r) {
        int lrr = wr * 32 + i * 16 + lq * 4 + r;
        int row = rowblk + lrr;
        float o = (acc2[i][j][r] - rowstat[lrr][0]) * rowstat[lrr][1] * gg +
                  bb2v;
        hddbf[(size_t)row * 256 + col] = f2bf(o);
      }
    }
  }
}

// ---------------- generic fp32 GEMM (small GRU matmuls) ----------------
__global__ __launch_bounds__(256) void gemm_f32(
    const float* __restrict__ A, const float* __restrict__ B,
    const float* __restrict__ bias, float* __restrict__ C,
    int M, int N, int K, int act) {
  __shared__ float As[16][68];
  __shared__ float Bs[16][64];
  const int id = threadIdx.x;
  const int tx = id & 15;
  const int ty = id >> 4;
  const int colblk = blockIdx.x * 64;
  const int rowblk = blockIdx.y * 64;
  const int lin = id * 4;
  const int ar = lin >> 4;
  const int ac = lin & 15;
  const int bc = lin >> 6;
  const int bcol = lin & 63;
  float acc[4][4] = {};
  for (int kt = 0; kt < K; kt += 16) {
    float4 a4 = *(const float4*)(A + (size_t)(rowblk + ar) * K + kt + ac);
    float4 b4 = *(const float4*)(B + (size_t)(kt + bc) * N + colblk + bcol);
    As[ac + 0][ar] = a4.x; As[ac + 1][ar] = a4.y;
    As[ac + 2][ar] = a4.z; As[ac + 3][ar] = a4.w;
    *(float4*)&Bs[bc][bcol] = b4;
    __syncthreads();
    #pragma unroll
    for (int kk = 0; kk < 16; ++kk) {
      float4 av = *(const float4*)&As[kk][ty * 4];
      float4 bv = *(const float4*)&Bs[kk][tx * 4];
      float a[4] = {av.x, av.y, av.z, av.w};
      float b[4] = {bv.x, bv.y, bv.z, bv.w};
      #pragma unroll
      for (int i = 0; i < 4; ++i)
        #pragma unroll
        for (int j = 0; j < 4; ++j) acc[i][j] += a[i] * b[j];
    }
    __syncthreads();
  }
  const int col = colblk + tx * 4;
  float4 bi = *(const float4*)(bias + col);
  #pragma unroll
  for (int i = 0; i < 4; ++i) {
    float r[4] = {acc[i][0] + bi.x, acc[i][1] + bi.y,
                  acc[i][2] + bi.z, acc[i][3] + bi.w};
    if (act == 2) {
      #pragma unroll
      for (int j = 0; j < 4; ++j) r[j] = expf(-fmaxf(r[j], 0.f));
    }
    *(float4*)(C + (size_t)(rowblk + ty * 4 + i) * N + col) =
        make_float4(r[0], r[1], r[2], r[3]);
  }
}

// ---------------- MFMA flash attention ------------------------------------
// one block per (b,h): 128 threads = 2 waves; wave handles 64 query rows.
// S = Q K^T (MFMA), mask+exp (no max: scores bounded), P@Vt (MFMA), /l.
__global__ __launch_bounds__(128) void attn_kernel(
    const u16* __restrict__ qkv, const int* __restrict__ txt_lengths,
    u16* __restrict__ o) {
  __shared__ u16 Qs[128][40];
  __shared__ u16 Ksh[128][40];
  __shared__ u16 Vt[32][136];   // V transposed: [d][j]
  __shared__ u16 Ps[128][136];  // P bf16
  __shared__ float lrow[128];
  int bh = blockIdx.x;
  int b = bh >> 3, h = bh & 7;
  int t = threadIdx.x;
  int len = txt_lengths[b] + 2;
  const int wave = t >> 6, lane = t & 63;
  const int l16 = lane & 15, lq = lane >> 4;
  const size_t base = ((size_t)b * 128) * 768 + h * 32;
  // ---- stage Q, K rows + V transposed ----
  #pragma unroll
  for (int p = 0; p < 4; ++p) {
    int idx = p * 128 + t;
    int row = idx >> 2, ch = idx & 3;
    size_t gofs = base + (size_t)row * 768 + ch * 8;
    uint4 q4 = *(const uint4*)(qkv + gofs);
    uint4 k4 = *(const uint4*)(qkv + gofs + 256);
    uint4 v4 = *(const uint4*)(qkv + gofs + 512);
    *(uint4*)&Qs[row][ch * 8] = q4;
    *(uint4*)&Ksh[row][ch * 8] = k4;
    const u16* vs = (const u16*)&v4;
    #pragma unroll
    for (int e = 0; e < 8; ++e) Vt[ch * 8 + e][row] = vs[e];
  }
  __syncthreads();
  const int rbase = wave * 64;
  const float scale = 0.17677669529663687f;
  // ---- phase 1: S tiles -> exp -> P(LDS) + row sums ----
  #pragma unroll
  for (int rt = 0; rt < 4; ++rt) {
    bf16x8 qf = *(const bf16x8*)&Qs[rbase + rt * 16 + l16][lq * 8];
    float psum[4] = {0.f, 0.f, 0.f, 0.f};
    #pragma unroll
    for (int ct = 0; ct < 8; ++ct) {
      bf16x8 kf = *(const bf16x8*)&Ksh[ct * 16 + l16][lq * 8];
      f32x4 acc = (f32x4)(0.f);
      acc = __builtin_amdgcn_mfma_f32_16x16x32_bf16(qf, kf, acc, 0, 0, 0);
      int col = ct * 16 + l16;
      #pragma unroll
      for (int r = 0; r < 4; ++r) {
        float p = (col < len) ? __expf(acc[r] * scale) : 0.f;
        psum[r] += p;
        Ps[rbase + rt * 16 + lq * 4 + r][col] = f2bf(p);
      }
    }
    #pragma unroll
    for (int r = 0; r < 4; ++r) {
      float s = psum[r];
      s += __shfl_xor(s, 1, 64);
      s += __shfl_xor(s, 2, 64);
      s += __shfl_xor(s, 4, 64);
      s += __shfl_xor(s, 8, 64);
      if (l16 == 0) lrow[rbase + rt * 16 + lq * 4 + r] = s;
    }
  }
  __syncthreads();
  // ---- phase 2: O = P @ Vt, normalize, store ----
  #pragma unroll
  for (int rt = 0; rt < 4; ++rt) {
    #pragma unroll
    for (int c2 = 0; c2 < 2; ++c2) {
      f32x4 acc = (f32x4)(0.f);
      #pragma unroll
      for (int kt = 0; kt < 4; ++kt) {
        bf16x8 pf = *(const bf16x8*)&Ps[rbase + rt * 16 + l16][kt * 32 + lq * 8];
        bf16x8 vf = *(const bf16x8*)&Vt[c2 * 16 + l16][kt * 32 + lq * 8];
        acc = __builtin_amdgcn_mfma_f32_16x16x32_bf16(pf, vf, acc, 0, 0, 0);
      }
      int col = c2 * 16 + l16;
      #pragma unroll
      for (int r = 0; r < 4; ++r) {
        int row = rbase + rt * 16 + lq * 4 + r;
        float inv = 1.f / lrow[row];
        o[(size_t)(b * 128 + row) * 256 + h * 32 + col] = f2bf(acc[r] * inv);
      }
    }
  }
}

// ---------------- GRU-D input imputation + concat ----------------
__global__ void impute_kernel(
    const float* __restrict__ x1, const float* __restrict__ m1,
    const float* __restrict__ d1, const float* __restrict__ dec_w,
    const float* __restrict__ dec_b, const float* __restrict__ x_m,
    float* __restrict__ xprep, float* __restrict__ dprep) {
  int idx = blockIdx.x * 256 + threadIdx.x;
  if (idx >= 256 * 24 * 16) return;
  int f = idx & 15;
  int t = (idx >> 4) % 24;
  int b = idx / (24 * 16);
  int src = (b * 36 + t) * 16 + f;
  float x = x1[src], m = m1[src], d = d1[src];
  float xd = expf(-fmaxf(d * dec_w[f] + dec_b[f], 0.f));
  float xv = m * x + (1.f - m) * xd * x + (1.f - m) * (1.f - xd) * x_m[f];
  int dst = b * 24 + t;
  xprep[dst * 32 + f] = xv;
  xprep[dst * 32 + 16 + f] = m;
  dprep[dst * 16 + f] = d;
}

// ------- GRU scan (R11 MFMA): 128 blocks x 2 batches, 256 threads ---------
__global__ __launch_bounds__(256) void gru_scan_mfma(
    const float* __restrict__ gx, const float* __restrict__ hdcyb,
    const u16* __restrict__ WhhT, const float* __restrict__ b_hh,
    const float* __restrict__ h0, float* __restrict__ ys) {
  __shared__ float hf[2][256];
  __shared__ u16 hbf[16][264];   // rows 2..15 zero
  __shared__ float gls[2][768];
  const int b0 = blockIdx.x * 2;
  const int tid = threadIdx.x;
  const int wave = tid >> 6, lane = tid & 63;
  const int l16 = lane & 15, lq = lane >> 4;
  #pragma unroll
  for (int r = 2; r < 16; ++r) hbf[r][tid] = 0;
  for (int i = tid; i < 512; i += 256) {
    int bb = i >> 8, col = i & 255;
    float v = h0[(size_t)(b0 + bb) * 256 + col] *
              hdcyb[(size_t)((b0 + bb) * 24) * 256 + col];
    hf[bb][col] = v;
    hbf[bb][col] = f2bf(v);
  }
  const float bh0 = b_hh[tid], bh1 = b_hh[256 + tid], bh2 = b_hh[512 + tid];
  __syncthreads();
  for (int t = 0; t < 24; ++t) {
    f32x4 acc[12];
    #pragma unroll
    for (int n = 0; n < 12; ++n) acc[n] = (f32x4)(0.f);
    #pragma unroll
    for (int kt = 0; kt < 8; ++kt) {
      bf16x8 af = *(const bf16x8*)&hbf[l16][kt * 32 + lq * 8];
      #pragma unroll
      for (int n = 0; n < 12; ++n) {
        int col0 = wave * 192 + n * 16;
        bf16x8 bf = *(const bf16x8*)(WhhT + (size_t)(col0 + l16) * 256 +
                                     kt * 32 + lq * 8);
        acc[n] =
            __builtin_amdgcn_mfma_f32_16x16x32_bf16(af, bf, acc[n], 0, 0, 0);
      }
    }
    if (lq == 0) {
      #pragma unroll
      for (int n = 0; n < 12; ++n) {
        int col = wave * 192 + n * 16 + l16;
        gls[0][col] = acc[n][0];
        gls[1][col] = acc[n][1];
      }
    }
    __syncthreads();
    #pragma unroll
    for (int bb = 0; bb < 2; ++bb) {
      const float* gxr = gx + (size_t)((b0 + bb) * 24 + t) * 768;
      int col = tid;
      float r = 1.f / (1.f + __expf(-(gxr[col] + gls[bb][col] + bh0)));
      float z =
          1.f / (1.f + __expf(-(gxr[256 + col] + gls[bb][256 + col] + bh1)));
      float n = tanhf(gxr[512 + col] + r * (gls[bb][512 + col] + bh2));
      float h1d = hf[bb][col];
      float hn = (1.f - z) * n + z * h1d;
      ys[(size_t)(t * 256 + b0 + bb) * 256 + col] = hn;
      float nxt = (t < 23)
                      ? hdcyb[(size_t)((b0 + bb) * 24 + t + 1) * 256 + col]
                      : 1.f;
      float hd = hn * nxt;
      hf[bb][col] = hd;
      hbf[bb][col] = f2bf(hd);
    }
    __syncthreads();
  }
}

// ------- c_t = LN(concat(...)) + pred + masked-MSE (merged) ---------------
__global__ __launch_bounds__(256) void ct_pred_kernel(
    const float* __restrict__ ys, const u16* __restrict__ hddbf,
    const int* __restrict__ input_lengths, const float* __restrict__ age,
    const float* __restrict__ gen, const float* __restrict__ g,
    const float* __restrict__ bb, float* __restrict__ c_t,
    const float* __restrict__ ct_w, const float* __restrict__ x1,
    const float* __restrict__ f_ind, float* __restrict__ accum) {
  __shared__ float buf[514];
  __shared__ float ctl[514];
  __shared__ float red[8];
  __shared__ float sq[192];
  int b = blockIdx.x, tid = threadIdx.x;
  int il = input_lengths[b] - 1;
  buf[tid] = ys[(size_t)(il * 256 + b) * 256 + tid];
  buf[256 + tid] = bf2f(hddbf[(size_t)(b * 128) * 256 + tid]);
  if (tid < 2) buf[512 + tid] = (tid == 0) ? age[b] : gen[b];
  __syncthreads();
  float p = buf[tid] + buf[256 + tid] + (tid < 2 ? buf[512 + tid] : 0.f);
  float mean = blockReduceSum(p, red) / 514.f;
  float d0 = buf[tid] - mean;
  float d1 = buf[256 + tid] - mean;
  float dq = (tid < 2) ? (buf[512 + tid] - mean) : 0.f;
  float var = blockReduceSum(d0 * d0 + d1 * d1 + dq * dq, red) / 514.f;
  float rs = rsqrtf(var + 1e-5f);
  float c0 = d0 * rs * g[tid] + bb[tid];
  float c1 = d1 * rs * g[256 + tid] + bb[256 + tid];
  ctl[tid] = c0;
  ctl[256 + tid] = c1;
  c_t[(size_t)b * 514 + tid] = c0;
  c_t[(size_t)b * 514 + 256 + tid] = c1;
  if (tid < 2) {
    float c2 = dq * rs * g[512 + tid] + bb[512 + tid];
    ctl[512 + tid] = c2;
    c_t[(size_t)b * 514 + 512 + tid] = c2;
  }
  __syncthreads();
  if (tid < 192) {
    int t = tid >> 4, f = tid & 15;
    float acc = 0.f;
    for (int c = 0; c < 514; ++c)
      acc += ctl[c] * ct_w[(size_t)(t * 514 + c) * 16 + f];
    float diff = acc - x1[(size_t)(b * 36 + 24 + t) * 16 + f];
    sq[tid] = diff * diff;
  }
  __syncthreads();
  if (tid < 12) {
    float s = 0.f;
    #pragma unroll
    for (int f = 0; f < 16; ++f) s += sq[tid * 16 + f];
    float w = f_ind[b * 12 + tid];
    atomicAdd(&accum[0], (s * (1.f / 16.f)) * w);
    atomicAdd(&accum[1], w);
  }
}

// ---------------- z1 = c_t @ fc_W1 + fc_b1 ----------------
__global__ __launch_bounds__(64) void fc1_kernel(
    const float* __restrict__ c_t, const float* __restrict__ fc_W1,
    const float* __restrict__ fc_b1, float* __restrict__ z1) {
  int t = blockIdx.x, b = blockIdx.y, dd = threadIdx.x;
  __shared__ float ct[514];
  for (int i = dd; i < 514; i += 64) ct[i] = c_t[(size_t)b * 514 + i];
  __syncthreads();
  float acc = fc_b1[t * 64 + dd];
  for (int c = 0; c < 514; ++c)
    acc += ct[c] * fc_W1[(size_t)(t * 514 + c) * 64 + dd];
  z1[(size_t)(t * 256 + b) * 64 + dd] = acc;
}

// ---------------- batchnorm stats over B per (t, dd) ----------------
__global__ __launch_bounds__(256) void bn_stats_kernel(
    const float* __restrict__ z1, float* __restrict__ mu,
    float* __restrict__ rstd) {
  __shared__ float red[8];
  int t = blockIdx.x >> 6;
  int dd = blockIdx.x & 63;
  int b = threadIdx.x;
  float v = z1[(size_t)(t * 256 + b) * 64 + dd];
  float mean = blockReduceSum(v, red) * (1.f / 256.f);
  float d = v - mean;
  float var = blockReduceSum(d * d, red) * (1.f / 256.f);
  if (b == 0) {
    mu[t * 64 + dd] = mean;
    rstd[t * 64 + dd] = rsqrtf(var + 1e-5f);
  }
}

// ---------------- out = relu(bn(z1)) @ fc_W2 + fc_b2 ----------------
__global__ __launch_bounds__(64) void out_kernel(
    const float* __restrict__ z1, const float* __restrict__ mu,
    const float* __restrict__ rstd, const float* __restrict__ bn_g,
    const float* __restrict__ bn_b, const float* __restrict__ fc_W2,
    const float* __restrict__ fc_b2, float* __restrict__ out) {
  int t = blockIdx.x, b = blockIdx.y, dd = threadIdx.x;
  float v = z1[(size_t)(t * 256 + b) * 64 + dd];
  float zn = (v - mu[t * 64 + dd]) * rstd[t * 64 + dd] * bn_g[t * 64 + dd] +
             bn_b[t * 64 + dd];
  float val = fmaxf(zn, 0.f) * fc_W2[t * 64 + dd];
  #pragma unroll
  for (int off = 32; off > 0; off >>= 1) val += __shfl_down(val, off, 64);
  if (dd == 0) out[t * 256 + b] = val + fc_b2[t];
}

__global__ void loss_final_kernel(const float* __restrict__ accum,
                                  float* __restrict__ out) {
  out[0] = accum[0] / accum[1];
}

// =======================================================================
extern "C" void kernel_launch(void* const* d_in, const int* in_sizes, int n_in,
                              void* d_out, int out_size, void* d_ws,
                              size_t ws_size, hipStream_t stream) {
  const float* x1 = (const float*)d_in[0];
  const float* h0 = (const float*)d_in[1];
  const float* m1 = (const float*)d_in[2];
  const float* d1 = (const float*)d_in[3];
  const float* x_m = (const float*)d_in[4];
  const float* age = (const float*)d_in[5];
  const float* gen = (const float*)d_in[6];
  const int* input_lengths = (const int*)d_in[7];
  const int* txts = (const int*)d_in[8];
  const int* txt_lengths = (const int*)d_in[9];
  const float* f_ind = (const float*)d_in[10];
  const float* emb = (const float*)d_in[11];
  const float* Win = (const float*)d_in[12];
  const float* bin_ = (const float*)d_in[13];
  const float* ln_in_g = (const float*)d_in[14];
  const float* ln_in_b = (const float*)d_in[15];
  const float* Wq = (const float*)d_in[16];
  const float* bq = (const float*)d_in[17];
  const float* Wk = (const float*)d_in[18];
  const float* bk = (const float*)d_in[19];
  const float* Wv = (const float*)d_in[20];
  const float* bv = (const float*)d_in[21];
  const float* Wo = (const float*)d_in[22];
  const float* bo = (const float*)d_in[23];
  const float* ln1_g = (const float*)d_in[24];
  const float* ln1_b = (const float*)d_in[25];
  const float* Wf1 = (const float*)d_in[26];
  const float* bf1 = (const float*)d_in[27];
  const float* Wf2 = (const float*)d_in[28];
  const float* bf2 = (const float*)d_in[29];
  const float* ln2_g = (const float*)d_in[30];
  const float* ln2_b = (const float*)d_in[31];
  const float* dec_w = (const float*)d_in[32];
  const float* dec_b = (const float*)d_in[33];
  const float* hd_W = (const float*)d_in[34];
  const float* hd_b = (const float*)d_in[35];
  const float* W_ih = (const float*)d_in[36];
  const float* b_ih = (const float*)d_in[37];
  const float* W_hh = (const float*)d_in[38];
  const float* b_hh = (const float*)d_in[39];
  const float* ln_c_g = (const float*)d_in[40];
  const float* ln_c_b = (const float*)d_in[41];
  const float* ct_w = (const float*)d_in[42];
  const float* fc_W1 = (const float*)d_in[43];
  const float* fc_b1 = (const float*)d_in[44];
  const float* bn_g = (const float*)d_in[45];
  const float* bn_b = (const float*)d_in[46];
  const float* fc_W2 = (const float*)d_in[47];
  const float* fc_b2 = (const float*)d_in[48];
  float* out = (float*)d_out;

  // ---- workspace layout (bytes) ----
  char* base = (char*)d_ws;
  u16* hdd_bf = (u16*)(base + 0);             // 16.8 MB (residual stream)
  u16* qkvb = (u16*)(base + 16777216);        // 50.3 MB
  u16* ob = (u16*)(base + 67108864);          // 16.8 MB (also tx_bf)
  u16* WinT = (u16*)(base + 83886080);        // 65536 el
  u16* WqkvT = WinT + 65536;                  // 4 x 196608 el
  u16* WoT = WqkvT + 786432;                  // 4 x 65536 el
  u16* Wf1T = WoT + 262144;                   // 4 x 131072 el
  u16* Wf2T = Wf1T + 524288;                  // 4 x 131072 el
  float* bqkv = (float*)(base + 88211456);    // 3072 f32
  float* pe = (float*)(base + 88223744);      // 128 KB
  u16* WhhT = (u16*)(base + 88354816);        // 384 KB bf16 [768][256]
  // GRU/head overlay over qkvb/ob (dead post-transformer); hdd_bf stays live
  char* gru = base + 16777216;
  float* xprep = (float*)gru;                 // 786432 B
  float* dprep = (float*)(gru + 786432);      // 393216 B
  float* gx = (float*)(gru + 1179648);        // 18874368 B
  float* hdcyb = (float*)(gru + 20054016);    // 6291456 B
  float* ys = (float*)(gru + 26345472);       // 6291456 B
  float* c_t = (float*)(gru + 32636928);      // 526336 B
  float* z1 = (float*)(gru + 33163264);       // 786432 B
  float* muv = (float*)(gru + 33949696);
  float* rstdv = (float*)(gru + 33952768);
  float* accum = (float*)(gru + 33955840);

  hipMemsetAsync(accum, 0, 2 * sizeof(float), stream);

  // ---- weight conversion ----
  transpose_bf16<<<dim3(8, 8, 1), 256, 0, stream>>>(Win, WinT, 256, 256, 65536);
  transpose_qkvo<<<dim3(8, 8, 16), 256, 0, stream>>>(Wq, Wk, Wv, Wo, WqkvT,
                                                     WoT);
  transpose_bf16<<<dim3(16, 8, 4), 256, 0, stream>>>(Wf1, Wf1T, 256, 512,
                                                     131072);
  transpose_bf16<<<dim3(8, 16, 4), 256, 0, stream>>>(Wf2, Wf2T, 512, 256,
                                                     131072);
  transpose_bf16<<<dim3(24, 8, 1), 256, 0, stream>>>(W_hh, WhhT, 256, 768,
                                                     196608);
  bias_concat_kernel<<<4, 768, 0, stream>>>(bq, bk, bv, bqkv);

  // ---- text transformer ----
  pe_kernel<<<128, 256, 0, stream>>>(pe);
  gather_kernel<<<8192, 256, 0, stream>>>(txts, emb, ob);  // tx in ob
  gemm_ln<<<512, 256, 0, stream>>>(ob, WinT, bin_, ln_in_g, ln_in_b, pe,
                                   hdd_bf, 32768, 256, 1);
  for (int l = 0; l < 4; ++l) {
    gemm_bf16<<<dim3(6, 256), 256, 0, stream>>>(hdd_bf, WqkvT + l * 196608,
                                                bqkv + l * 768, qkvb, 32768,
                                                768, 256, 0);
    attn_kernel<<<2048, 128, 0, stream>>>(qkvb, txt_lengths, ob);
    gemm_ln<<<512, 256, 0, stream>>>(ob, WoT + l * 65536, bo + l * 256,
                                     ln1_g + l * 256, ln1_b + l * 256, pe,
                                     hdd_bf, 32768, 256, 0);
    ffn_ln<<<512, 512, 0, stream>>>(hdd_bf, Wf1T + l * 131072, bf1 + l * 512,
                                    Wf2T + l * 131072, bf2 + l * 256,
                                    ln2_g + l * 256, ln2_b + l * 256, hdd_bf,
                                    32768);
  }

  // ---- GRU-D branch ----
  impute_kernel<<<384, 256, 0, stream>>>(x1, m1, d1, dec_w, dec_b, x_m, xprep,
                                         dprep);
  gemm_f32<<<dim3(12, 96), 256, 0, stream>>>(xprep, W_ih, b_ih, gx, 6144, 768,
                                             32, 0);
  gemm_f32<<<dim3(4, 96), 256, 0, stream>>>(dprep, hd_W, hd_b, hdcyb, 6144,
                                            256, 16, 2);
  gru_scan_mfma<<<128, 256, 0, stream>>>(gx, hdcyb, WhhT, b_hh, h0, ys);

  // ---- head ----
  ct_pred_kernel<<<256, 256, 0, stream>>>(ys, hdd_bf, input_lengths, age, gen,
                                          ln_c_g, ln_c_b, c_t, ct_w, x1, f_ind,
                                          accum);
  fc1_kernel<<<dim3(12, 256), 64, 0, stream>>>(c_t, fc_W1, fc_b1, z1);
  bn_stats_kernel<<<768, 256, 0, stream>>>(z1, muv, rstdv);
  out_kernel<<<dim3(12, 256), 64, 0, stream>>>(z1, muv, rstdv, bn_g, bn_b,
                                               fc_W2, fc_b2, out);
  loss_final_kernel<<<1, 1, 0, stream>>>(accum, out + 3072);
}

// Round 15
// 1144.097 us; speedup vs baseline: 1.5783x; 1.0011x over previous
//
#include <hip/hip_runtime.h>
#include <math.h>

typedef unsigned short u16;
typedef unsigned int u32;
typedef short bf16x8 __attribute__((ext_vector_type(8)));
typedef float f32x4 __attribute__((ext_vector_type(4)));

__device__ __forceinline__ u16 f2bf(float f) {
  u32 u = __float_as_uint(f);
  u32 r = (u + 0x7fffu + ((u >> 16) & 1u)) >> 16;
  return (u16)r;
}
__device__ __forceinline__ float bf2f(u16 h) {
  return __uint_as_float(((u32)h) << 16);
}
// async global->LDS, 16B per lane; LDS dest = wave-uniform base + lane*16
__device__ __forceinline__ void gload_lds16(const u16* g, u16* l) {
  __builtin_amdgcn_global_load_lds(
      (const __attribute__((address_space(1))) void*)g,
      (__attribute__((address_space(3))) void*)l, 16, 0, 0);
}
__device__ __forceinline__ float blockReduceSum(float v, float* red) {
  #pragma unroll
  for (int off = 32; off > 0; off >>= 1) v += __shfl_down(v, off, 64);
  const int lane = threadIdx.x & 63;
  const int wid = threadIdx.x >> 6;
  __syncthreads();
  if (lane == 0) red[wid] = v;
  __syncthreads();
  const int nw = (blockDim.x + 63) >> 6;
  float s = red[0];
  for (int i = 1; i < nw; ++i) s += red[i];
  return s;
}

// ---------------- positional encoding ----------------
__global__ void pe_kernel(float* __restrict__ pe) {
  int l = blockIdx.x;
  int i = threadIdx.x;
  double e = exp2(-(double)(2 * (i / 2)) / 256.0 * 13.287712379549449);
  double ang = (double)l * e;
  pe[l * 256 + i] = (float)((i & 1) ? cos(ang) : sin(ang));
}

// ---------------- embedding gather -> bf16 (wave per row) ----------------
__global__ __launch_bounds__(256) void gather_kernel(
    const int* __restrict__ txts, const float* __restrict__ emb,
    u16* __restrict__ tx) {
  int row = blockIdx.x * 4 + (threadIdx.x >> 6);
  int lane = threadIdx.x & 63;
  int tok = txts[row];
  float4 e = *(const float4*)(emb + (size_t)tok * 256 + lane * 4);
  u16 o[4] = {f2bf(e.x), f2bf(e.y), f2bf(e.z), f2bf(e.w)};
  *(uint2*)(tx + (size_t)row * 256 + lane * 4) = *(const uint2*)o;
}

// ------- weight transpose fp32[K][N] -> bf16[N][K], custom group stride ----
__global__ __launch_bounds__(256) void transpose_bf16(
    const float* __restrict__ W, u16* __restrict__ Wt, int K, int N,
    int dstStride) {
  __shared__ float tile[32][33];
  int g = blockIdx.z;
  const float* Wg = W + (size_t)g * K * N;
  u16* Wtg = Wt + (size_t)g * dstStride;
  int n0 = blockIdx.x * 32, k0 = blockIdx.y * 32;
  int tx = threadIdx.x & 31, ty = threadIdx.x >> 5;
  #pragma unroll
  for (int i = 0; i < 32; i += 8)
    tile[ty + i][tx] = Wg[(size_t)(k0 + ty + i) * N + n0 + tx];
  __syncthreads();
  #pragma unroll
  for (int i = 0; i < 32; i += 8)
    Wtg[(size_t)(n0 + ty + i) * K + k0 + tx] = f2bf(tile[tx][ty + i]);
}

// ------- merged transpose for Wq/Wk/Wv/Wo (all [4][256][256]) -------------
__global__ __launch_bounds__(256) void transpose_qkvo(
    const float* __restrict__ Wq, const float* __restrict__ Wk,
    const float* __restrict__ Wv, const float* __restrict__ Wo,
    u16* __restrict__ WqkvT, u16* __restrict__ WoT) {
  __shared__ float tile[32][33];
  int z = blockIdx.z, l = z >> 2, which = z & 3;
  const float* src = (which == 0) ? Wq : (which == 1) ? Wk
                     : (which == 2) ? Wv : Wo;
  src += (size_t)l * 65536;
  u16* dst = (which < 3) ? (WqkvT + (size_t)l * 196608 + which * 65536)
                         : (WoT + (size_t)l * 65536);
  int n0 = blockIdx.x * 32, k0 = blockIdx.y * 32;
  int tx = threadIdx.x & 31, ty = threadIdx.x >> 5;
  #pragma unroll
  for (int i = 0; i < 32; i += 8)
    tile[ty + i][tx] = src[(size_t)(k0 + ty + i) * 256 + n0 + tx];
  __syncthreads();
  #pragma unroll
  for (int i = 0; i < 32; i += 8)
    dst[(size_t)(n0 + ty + i) * 256 + k0 + tx] = f2bf(tile[tx][ty + i]);
}

// ---------------- concat qkv bias ----------------
__global__ void bias_concat_kernel(const float* __restrict__ bq,
                                   const float* __restrict__ bk,
                                   const float* __restrict__ bv,
                                   float* __restrict__ bqkv) {
  int l = blockIdx.x, i = threadIdx.x;
  float v;
  if (i < 256) v = bq[l * 256 + i];
  else if (i < 512) v = bk[l * 256 + i - 256];
  else v = bv[l * 256 + i - 512];
  bqkv[l * 768 + i] = v;
}

// ---------------- bf16 MFMA GEMM, 128x128 tile (m97 shape) ----------------
// grid (N/128, M/128), block 256 (4 waves: 2x2). act: 0 none, 1 relu.
__global__ __launch_bounds__(256) void gemm_bf16(
    const u16* __restrict__ A, const u16* __restrict__ Bt,
    const float* __restrict__ bias, u16* __restrict__ Cb, int M, int N, int K,
    int act) {
  __shared__ u16 As[128][32];
  __shared__ u16 Bs[128][32];
  const int tid = threadIdx.x;
  const int wave = tid >> 6, lane = tid & 63;
  const int wr = wave >> 1, wc = wave & 1;
  const int rowblk = blockIdx.y * 128, colblk = blockIdx.x * 128;
  const int l16 = lane & 15, lq = lane >> 4;
  const int lr = lane >> 2, lc = lane & 3;
  const int r0 = wave * 32;
  f32x4 acc[4][4];
  #pragma unroll
  for (int i = 0; i < 4; ++i)
    #pragma unroll
    for (int j = 0; j < 4; ++j) acc[i][j] = (f32x4)(0.f);

  for (int kt = 0; kt < K; kt += 32) {
    __syncthreads();
    gload_lds16(A + (size_t)(rowblk + r0 + lr) * K + kt + lc * 8, &As[r0][0]);
    gload_lds16(A + (size_t)(rowblk + r0 + 16 + lr) * K + kt + lc * 8,
                &As[r0 + 16][0]);
    gload_lds16(Bt + (size_t)(colblk + r0 + lr) * K + kt + lc * 8, &Bs[r0][0]);
    gload_lds16(Bt + (size_t)(colblk + r0 + 16 + lr) * K + kt + lc * 8,
                &Bs[r0 + 16][0]);
    __syncthreads();
    bf16x8 af[4], bfr[4];
    #pragma unroll
    for (int t = 0; t < 4; ++t) {
      af[t] = *(const bf16x8*)&As[wr * 64 + t * 16 + l16][lq * 8];
      bfr[t] = *(const bf16x8*)&Bs[wc * 64 + t * 16 + l16][lq * 8];
    }
    #pragma unroll
    for (int i = 0; i < 4; ++i)
      #pragma unroll
      for (int j = 0; j < 4; ++j)
        acc[i][j] = __builtin_amdgcn_mfma_f32_16x16x32_bf16(af[i], bfr[j],
                                                            acc[i][j], 0, 0, 0);
  }
  const int rbase = rowblk + wr * 64, cbase = colblk + wc * 64;
  #pragma unroll
  for (int j = 0; j < 4; ++j) {
    int col = cbase + j * 16 + l16;
    float bv = bias[col];
    #pragma unroll
    for (int i = 0; i < 4; ++i) {
      int row0 = rbase + i * 16 + lq * 4;
      #pragma unroll
      for (int r = 0; r < 4; ++r) {
        float vv = acc[i][j][r] + bv;
        if (act == 1) vv = fmaxf(vv, 0.f);
        Cb[(size_t)(row0 + r) * N + col] = f2bf(vv);
      }
    }
  }
}

// ------- fused GEMM (N=256) + bf16 residual/PE + LayerNorm -----------------
// 64-row blocks, 256 threads (4 col-waves). grid = M/64.
__global__ __launch_bounds__(256) void gemm_ln(
    const u16* __restrict__ A, const u16* __restrict__ Bt,
    const float* __restrict__ bias, const float* __restrict__ g,
    const float* __restrict__ bvec, const float* __restrict__ pe,
    u16* __restrict__ hddbf, int M, int K, int mode) {
  __shared__ u16 As[64][32];
  __shared__ u16 Bs[256][32];
  __shared__ float redS[4][64];
  __shared__ float redQ[4][64];
  __shared__ float rowstat[64][2];
  const int tid = threadIdx.x;
  const int wave = tid >> 6, lane = tid & 63;
  const int wc = wave;
  const int rowblk = blockIdx.x * 64;
  const int l16 = lane & 15, lq = lane >> 4;
  const int lr = lane >> 2, lc = lane & 3;
  f32x4 acc[4][4];
  #pragma unroll
  for (int i = 0; i < 4; ++i)
    #pragma unroll
    for (int j = 0; j < 4; ++j) acc[i][j] = (f32x4)(0.f);

  for (int kt = 0; kt < K; kt += 32) {
    __syncthreads();
    gload_lds16(A + (size_t)(rowblk + wave * 16 + lr) * K + kt + lc * 8,
                &As[wave * 16][0]);
    #pragma unroll
    for (int p = 0; p < 4; ++p)
      gload_lds16(Bt + (size_t)(wave * 64 + p * 16 + lr) * K + kt + lc * 8,
                  &Bs[wave * 64 + p * 16][0]);
    __syncthreads();
    bf16x8 af[4], bfr[4];
    #pragma unroll
    for (int t = 0; t < 4; ++t) {
      af[t] = *(const bf16x8*)&As[t * 16 + l16][lq * 8];
      bfr[t] = *(const bf16x8*)&Bs[wc * 64 + t * 16 + l16][lq * 8];
    }
    #pragma unroll
    for (int i = 0; i < 4; ++i)
      #pragma unroll
      for (int j = 0; j < 4; ++j)
        acc[i][j] = __builtin_amdgcn_mfma_f32_16x16x32_bf16(af[i], bfr[j],
                                                            acc[i][j], 0, 0, 0);
  }
  const int cbase = wc * 64;
  #pragma unroll
  for (int j = 0; j < 4; ++j) {
    int col = cbase + j * 16 + l16;
    float bv = bias[col];
    #pragma unroll
    for (int i = 0; i < 4; ++i) {
      int row0 = rowblk + i * 16 + lq * 4;
      #pragma unroll
      for (int r = 0; r < 4; ++r) {
        float v = acc[i][j][r] + bv;
        if (mode == 0) v += bf2f(hddbf[(size_t)(row0 + r) * 256 + col]);
        acc[i][j][r] = v;
      }
    }
  }
  #pragma unroll
  for (int i = 0; i < 4; ++i) {
    #pragma unroll
    for (int r = 0; r < 4; ++r) {
      float s = 0.f, q = 0.f;
      #pragma unroll
      for (int j = 0; j < 4; ++j) {
        float v = acc[i][j][r];
        s += v;
        q += v * v;
      }
      #pragma unroll
      for (int m = 1; m < 16; m <<= 1) {
        s += __shfl_xor(s, m, 64);
        q += __shfl_xor(q, m, 64);
      }
      if (l16 == 0) {
        int lrr = i * 16 + lq * 4 + r;
        redS[wc][lrr] = s;
        redQ[wc][lrr] = q;
      }
    }
  }
  __syncthreads();
  if (tid < 64) {
    float s = redS[0][tid] + redS[1][tid] + redS[2][tid] + redS[3][tid];
    float q = redQ[0][tid] + redQ[1][tid] + redQ[2][tid] + redQ[3][tid];
    float mean = s * (1.f / 256.f);
    float var = q * (1.f / 256.f) - mean * mean;
    rowstat[tid][0] = mean;
    rowstat[tid][1] = rsqrtf(var + 1e-5f);
  }
  __syncthreads();
  float gg[4], bb2[4];
  #pragma unroll
  for (int j = 0; j < 4; ++j) {
    int col = cbase + j * 16 + l16;
    gg[j] = g[col];
    bb2[j] = bvec[col];
  }
  #pragma unroll
  for (int i = 0; i < 4; ++i) {
    #pragma unroll
    for (int r = 0; r < 4; ++r) {
      int lrr = i * 16 + lq * 4 + r;
      int row = rowblk + lrr;
      float mean = rowstat[lrr][0], rstd = rowstat[lrr][1];
      #pragma unroll
      for (int j = 0; j < 4; ++j) {
        int col = cbase + j * 16 + l16;
        float o = (acc[i][j][r] - mean) * rstd * gg[j] + bb2[j];
        if (mode == 1) o += pe[(size_t)(row & 127) * 256 + col];
        hddbf[(size_t)row * 256 + col] = f2bf(o);
      }
    }
  }
}

// ------- fused FFN: relu(A@W1+b1)@W2+b2 + residual + LN --------------------
// A read directly from L2-hot global (no As staging) -> LDS ~71 KB, 2 blk/CU
__global__ __launch_bounds__(512) void ffn_ln(
    const u16* __restrict__ A, const u16* __restrict__ W1t,
    const float* __restrict__ b1, const u16* __restrict__ W2t,
    const float* __restrict__ b2, const float* __restrict__ g,
    const float* __restrict__ bvec, u16* __restrict__ hddbf, int M) {
  __shared__ u16 Fs[64][536];  // stride 536 u16 = 1072B: ~2-4 way conflicts
  __shared__ float redS[4][64];
  __shared__ float redQ[4][64];
  __shared__ float rowstat[64][2];
  const int tid = threadIdx.x;
  const int wave = tid >> 6, lane = tid & 63;
  const int l16 = lane & 15, lq = lane >> 4;
  const int rowblk = blockIdx.x * 64;
  // ---- stage 1: ff1 (64 x 512, K=256); wave -> cols [wave*64, +64) ----
  {
    f32x4 acc1[4][4];
    #pragma unroll
    for (int i = 0; i < 4; ++i)
      #pragma unroll
      for (int j = 0; j < 4; ++j) acc1[i][j] = (f32x4)(0.f);
    #pragma unroll
    for (int kt = 0; kt < 8; ++kt) {
      bf16x8 af[4], bfr[4];
      #pragma unroll
      for (int t = 0; t < 4; ++t) {
        af[t] = *(const bf16x8*)(A + (size_t)(rowblk + t * 16 + l16) * 256 +
                                 kt * 32 + lq * 8);
        bfr[t] = *(const bf16x8*)(W1t +
                                  (size_t)(wave * 64 + t * 16 + l16) * 256 +
                                  kt * 32 + lq * 8);
      }
      #pragma unroll
      for (int i = 0; i < 4; ++i)
        #pragma unroll
        for (int j = 0; j < 4; ++j)
          acc1[i][j] = __builtin_amdgcn_mfma_f32_16x16x32_bf16(
              af[i], bfr[j], acc1[i][j], 0, 0, 0);
    }
    #pragma unroll
    for (int j = 0; j < 4; ++j) {
      int col = wave * 64 + j * 16 + l16;
      float bias1 = b1[col];
      #pragma unroll
      for (int i = 0; i < 4; ++i) {
        int row0 = i * 16 + lq * 4;
        #pragma unroll
        for (int r = 0; r < 4; ++r)
          Fs[row0 + r][col] = f2bf(fmaxf(acc1[i][j][r] + bias1, 0.f));
      }
    }
  }
  __syncthreads();
  // ---- stage 2: ff2 (64 x 256, K=512); wave grid 2 rows x 4 cols ----
  const int wr = wave >> 2, wc = wave & 3;
  f32x4 acc2[2][4];
  #pragma unroll
  for (int i = 0; i < 2; ++i)
    #pragma unroll
    for (int j = 0; j < 4; ++j) acc2[i][j] = (f32x4)(0.f);
  #pragma unroll
  for (int kt = 0; kt < 16; ++kt) {
    bf16x8 af[2], bfr[4];
    #pragma unroll
    for (int i = 0; i < 2; ++i)
      af[i] = *(const bf16x8*)&Fs[wr * 32 + i * 16 + l16][kt * 32 + lq * 8];
    #pragma unroll
    for (int j = 0; j < 4; ++j)
      bfr[j] = *(const bf16x8*)(W2t + (size_t)(wc * 64 + j * 16 + l16) * 512 +
                                kt * 32 + lq * 8);
    #pragma unroll
    for (int i = 0; i < 2; ++i)
      #pragma unroll
      for (int j = 0; j < 4; ++j)
        acc2[i][j] = __builtin_amdgcn_mfma_f32_16x16x32_bf16(af[i], bfr[j],
                                                             acc2[i][j], 0, 0,
                                                             0);
  }
  #pragma unroll
  for (int j = 0; j < 4; ++j) {
    int col = wc * 64 + j * 16 + l16;
    float bias2 = b2[col];
    #pragma unroll
    for (int i = 0; i < 2; ++i) {
      int row0 = rowblk + wr * 32 + i * 16 + lq * 4;
      #pragma unroll
      for (int r = 0; r < 4; ++r)
        acc2[i][j][r] += bias2 + bf2f(hddbf[(size_t)(row0 + r) * 256 + col]);
    }
  }
  #pragma unroll
  for (int i = 0; i < 2; ++i) {
    #pragma unroll
    for (int r = 0; r < 4; ++r) {
      float s = 0.f, q = 0.f;
      #pragma unroll
      for (int j = 0; j < 4; ++j) {
        float v = acc2[i][j][r];
        s += v;
        q += v * v;
      }
      #pragma unroll
      for (int m = 1; m < 16; m <<= 1) {
        s += __shfl_xor(s, m, 64);
        q += __shfl_xor(q, m, 64);
      }
      if (l16 == 0) {
        int lrr = wr * 32 + i * 16 + lq * 4 + r;
        redS[wc][lrr] = s;
        redQ[wc][lrr] = q;
      }
    }
  }
  __syncthreads();
  if (tid < 64) {
    float s = redS[0][tid] + redS[1][tid] + redS[2][tid] + redS[3][tid];
    float q = redQ[0][tid] + redQ[1][tid] + redQ[2][tid] + redQ[3][tid];
    float mean = s * (1.f / 256.f);
    float var = q * (1.f / 256.f) - mean * mean;
    rowstat[tid][0] = mean;
    rowstat[tid][1] = rsqrtf(var + 1e-5f);
  }
  __syncthreads();
  #pragma unroll
  for (int j = 0; j < 4; ++j) {
    int col = wc * 64 + j * 16 + l16;
    float gg = g[col], bb2v = bvec[col];
    #pragma unroll
    for (int i = 0; i < 2; ++i) {
      #pragma unroll
      for (int r = 0; r < 4; ++r) {
        int lrr = wr * 32 + i * 16 + lq * 4 + r;
        int row = rowblk + lrr;
        float o = (acc2[i][j][r] - rowstat[lrr][0]) * rowstat[lrr][1] * gg +
                  bb2v;
        hddbf[(size_t)row * 256 + col] = f2bf(o);
      }
    }
  }
}

// ---------------- generic fp32 GEMM (small GRU matmuls) ----------------
__global__ __launch_bounds__(256) void gemm_f32(
    const float* __restrict__ A, const float* __restrict__ B,
    const float* __restrict__ bias, float* __restrict__ C,
    int M, int N, int K, int act) {
  __shared__ float As[16][68];
  __shared__ float Bs[16][64];
  const int id = threadIdx.x;
  const int tx = id & 15;
  const int ty = id >> 4;
  const int colblk = blockIdx.x * 64;
  const int rowblk = blockIdx.y * 64;
  const int lin = id * 4;
  const int ar = lin >> 4;
  const int ac = lin & 15;
  const int bc = lin >> 6;
  const int bcol = lin & 63;
  float acc[4][4] = {};
  for (int kt = 0; kt < K; kt += 16) {
    float4 a4 = *(const float4*)(A + (size_t)(rowblk + ar) * K + kt + ac);
    float4 b4 = *(const float4*)(B + (size_t)(kt + bc) * N + colblk + bcol);
    As[ac + 0][ar] = a4.x; As[ac + 1][ar] = a4.y;
    As[ac + 2][ar] = a4.z; As[ac + 3][ar] = a4.w;
    *(float4*)&Bs[bc][bcol] = b4;
    __syncthreads();
    #pragma unroll
    for (int kk = 0; kk < 16; ++kk) {
      float4 av = *(const float4*)&As[kk][ty * 4];
      float4 bv = *(const float4*)&Bs[kk][tx * 4];
      float a[4] = {av.x, av.y, av.z, av.w};
      float b[4] = {bv.x, bv.y, bv.z, bv.w};
      #pragma unroll
      for (int i = 0; i < 4; ++i)
        #pragma unroll
        for (int j = 0; j < 4; ++j) acc[i][j] += a[i] * b[j];
    }
    __syncthreads();
  }
  const int col = colblk + tx * 4;
  float4 bi = *(const float4*)(bias + col);
  #pragma unroll
  for (int i = 0; i < 4; ++i) {
    float r[4] = {acc[i][0] + bi.x, acc[i][1] + bi.y,
                  acc[i][2] + bi.z, acc[i][3] + bi.w};
    if (act == 2) {
      #pragma unroll
      for (int j = 0; j < 4; ++j) r[j] = expf(-fmaxf(r[j], 0.f));
    }
    *(float4*)(C + (size_t)(rowblk + ty * 4 + i) * N + col) =
        make_float4(r[0], r[1], r[2], r[3]);
  }
}

// ---------------- MFMA flash attention ------------------------------------
__global__ __launch_bounds__(128) void attn_kernel(
    const u16* __restrict__ qkv, const int* __restrict__ txt_lengths,
    u16* __restrict__ o) {
  __shared__ u16 Qs[128][40];
  __shared__ u16 Ksh[128][40];
  __shared__ u16 Vt[32][136];   // V transposed: [d][j]
  __shared__ u16 Ps[128][136];  // P bf16
  __shared__ float lrow[128];
  int bh = blockIdx.x;
  int b = bh >> 3, h = bh & 7;
  int t = threadIdx.x;
  int len = txt_lengths[b] + 2;
  const int wave = t >> 6, lane = t & 63;
  const int l16 = lane & 15, lq = lane >> 4;
  const size_t base = ((size_t)b * 128) * 768 + h * 32;
  #pragma unroll
  for (int p = 0; p < 4; ++p) {
    int idx = p * 128 + t;
    int row = idx >> 2, ch = idx & 3;
    size_t gofs = base + (size_t)row * 768 + ch * 8;
    uint4 q4 = *(const uint4*)(qkv + gofs);
    uint4 k4 = *(const uint4*)(qkv + gofs + 256);
    uint4 v4 = *(const uint4*)(qkv + gofs + 512);
    *(uint4*)&Qs[row][ch * 8] = q4;
    *(uint4*)&Ksh[row][ch * 8] = k4;
    const u16* vs = (const u16*)&v4;
    #pragma unroll
    for (int e = 0; e < 8; ++e) Vt[ch * 8 + e][row] = vs[e];
  }
  __syncthreads();
  const int rbase = wave * 64;
  const float scale = 0.17677669529663687f;
  #pragma unroll
  for (int rt = 0; rt < 4; ++rt) {
    bf16x8 qf = *(const bf16x8*)&Qs[rbase + rt * 16 + l16][lq * 8];
    float psum[4] = {0.f, 0.f, 0.f, 0.f};
    #pragma unroll
    for (int ct = 0; ct < 8; ++ct) {
      bf16x8 kf = *(const bf16x8*)&Ksh[ct * 16 + l16][lq * 8];
      f32x4 acc = (f32x4)(0.f);
      acc = __builtin_amdgcn_mfma_f32_16x16x32_bf16(qf, kf, acc, 0, 0, 0);
      int col = ct * 16 + l16;
      #pragma unroll
      for (int r = 0; r < 4; ++r) {
        float p = (col < len) ? __expf(acc[r] * scale) : 0.f;
        psum[r] += p;
        Ps[rbase + rt * 16 + lq * 4 + r][col] = f2bf(p);
      }
    }
    #pragma unroll
    for (int r = 0; r < 4; ++r) {
      float s = psum[r];
      s += __shfl_xor(s, 1, 64);
      s += __shfl_xor(s, 2, 64);
      s += __shfl_xor(s, 4, 64);
      s += __shfl_xor(s, 8, 64);
      if (l16 == 0) lrow[rbase + rt * 16 + lq * 4 + r] = s;
    }
  }
  __syncthreads();
  #pragma unroll
  for (int rt = 0; rt < 4; ++rt) {
    #pragma unroll
    for (int c2 = 0; c2 < 2; ++c2) {
      f32x4 acc = (f32x4)(0.f);
      #pragma unroll
      for (int kt = 0; kt < 4; ++kt) {
        bf16x8 pf = *(const bf16x8*)&Ps[rbase + rt * 16 + l16][kt * 32 + lq * 8];
        bf16x8 vf = *(const bf16x8*)&Vt[c2 * 16 + l16][kt * 32 + lq * 8];
        acc = __builtin_amdgcn_mfma_f32_16x16x32_bf16(pf, vf, acc, 0, 0, 0);
      }
      int col = c2 * 16 + l16;
      #pragma unroll
      for (int r = 0; r < 4; ++r) {
        int row = rbase + rt * 16 + lq * 4 + r;
        float inv = 1.f / lrow[row];
        o[(size_t)(b * 128 + row) * 256 + h * 32 + col] = f2bf(acc[r] * inv);
      }
    }
  }
}

// ---------------- GRU-D input imputation + concat ----------------
__global__ void impute_kernel(
    const float* __restrict__ x1, const float* __restrict__ m1,
    const float* __restrict__ d1, const float* __restrict__ dec_w,
    const float* __restrict__ dec_b, const float* __restrict__ x_m,
    float* __restrict__ xprep, float* __restrict__ dprep) {
  int idx = blockIdx.x * 256 + threadIdx.x;
  if (idx >= 256 * 24 * 16) return;
  int f = idx & 15;
  int t = (idx >> 4) % 24;
  int b = idx / (24 * 16);
  int src = (b * 36 + t) * 16 + f;
  float x = x1[src], m = m1[src], d = d1[src];
  float xd = expf(-fmaxf(d * dec_w[f] + dec_b[f], 0.f));
  float xv = m * x + (1.f - m) * xd * x + (1.f - m) * (1.f - xd) * x_m[f];
  int dst = b * 24 + t;
  xprep[dst * 32 + f] = xv;
  xprep[dst * 32 + 16 + f] = m;
  dprep[dst * 16 + f] = d;
}

// ------- GRU scan MFMA: 128 blocks x 2 batches; zero-frag for l16>=2 ------
__global__ __launch_bounds__(256) void gru_scan_mfma(
    const float* __restrict__ gx, const float* __restrict__ hdcyb,
    const u16* __restrict__ WhhT, const float* __restrict__ b_hh,
    const float* __restrict__ h0, float* __restrict__ ys) {
  __shared__ float hf[2][256];
  __shared__ u16 hbf[2][264];
  __shared__ float gls[2][768];
  const int b0 = blockIdx.x * 2;
  const int tid = threadIdx.x;
  const int wave = tid >> 6, lane = tid & 63;
  const int l16 = lane & 15, lq = lane >> 4;
  for (int i = tid; i < 512; i += 256) {
    int bb = i >> 8, col = i & 255;
    float v = h0[(size_t)(b0 + bb) * 256 + col] *
              hdcyb[(size_t)((b0 + bb) * 24) * 256 + col];
    hf[bb][col] = v;
    hbf[bb][col] = f2bf(v);
  }
  const float bh0 = b_hh[tid], bh1 = b_hh[256 + tid], bh2 = b_hh[512 + tid];
  __syncthreads();
  for (int t = 0; t < 24; ++t) {
    f32x4 acc[12];
    #pragma unroll
    for (int n = 0; n < 12; ++n) acc[n] = (f32x4)(0.f);
    #pragma unroll
    for (int kt = 0; kt < 8; ++kt) {
      bf16x8 af = (bf16x8)(short)0;
      if (l16 < 2) af = *(const bf16x8*)&hbf[l16][kt * 32 + lq * 8];
      #pragma unroll
      for (int n = 0; n < 12; ++n) {
        int col0 = wave * 192 + n * 16;
        bf16x8 bf = *(const bf16x8*)(WhhT + (size_t)(col0 + l16) * 256 +
                                     kt * 32 + lq * 8);
        acc[n] =
            __builtin_amdgcn_mfma_f32_16x16x32_bf16(af, bf, acc[n], 0, 0, 0);
      }
    }
    if (lq == 0) {
      #pragma unroll
      for (int n = 0; n < 12; ++n) {
        int col = wave * 192 + n * 16 + l16;
        gls[0][col] = acc[n][0];
        gls[1][col] = acc[n][1];
      }
    }
    __syncthreads();
    #pragma unroll
    for (int bb = 0; bb < 2; ++bb) {
      const float* gxr = gx + (size_t)((b0 + bb) * 24 + t) * 768;
      int col = tid;
      float r = 1.f / (1.f + __expf(-(gxr[col] + gls[bb][col] + bh0)));
      float z =
          1.f / (1.f + __expf(-(gxr[256 + col] + gls[bb][256 + col] + bh1)));
      float n = tanhf(gxr[512 + col] + r * (gls[bb][512 + col] + bh2));
      float h1d = hf[bb][col];
      float hn = (1.f - z) * n + z * h1d;
      ys[(size_t)(t * 256 + b0 + bb) * 256 + col] = hn;
      float nxt = (t < 23)
                      ? hdcyb[(size_t)((b0 + bb) * 24 + t + 1) * 256 + col]
                      : 1.f;
      float hd = hn * nxt;
      hf[bb][col] = hd;
      hbf[bb][col] = f2bf(hd);
    }
    __syncthreads();
  }
}

// ------- c_t = LN(concat(...)) + pred + masked-MSE (merged) ---------------
__global__ __launch_bounds__(256) void ct_pred_kernel(
    const float* __restrict__ ys, const u16* __restrict__ hddbf,
    const int* __restrict__ input_lengths, const float* __restrict__ age,
    const float* __restrict__ gen, const float* __restrict__ g,
    const float* __restrict__ bb, float* __restrict__ c_t,
    const float* __restrict__ ct_w, const float* __restrict__ x1,
    const float* __restrict__ f_ind, float* __restrict__ accum) {
  __shared__ float buf[514];
  __shared__ float ctl[514];
  __shared__ float red[8];
  __shared__ float sq[192];
  int b = blockIdx.x, tid = threadIdx.x;
  int il = input_lengths[b] - 1;
  buf[tid] = ys[(size_t)(il * 256 + b) * 256 + tid];
  buf[256 + tid] = bf2f(hddbf[(size_t)(b * 128) * 256 + tid]);
  if (tid < 2) buf[512 + tid] = (tid == 0) ? age[b] : gen[b];
  __syncthreads();
  float p = buf[tid] + buf[256 + tid] + (tid < 2 ? buf[512 + tid] : 0.f);
  float mean = blockReduceSum(p, red) / 514.f;
  float d0 = buf[tid] - mean;
  float d1 = buf[256 + tid] - mean;
  float dq = (tid < 2) ? (buf[512 + tid] - mean) : 0.f;
  float var = blockReduceSum(d0 * d0 + d1 * d1 + dq * dq, red) / 514.f;
  float rs = rsqrtf(var + 1e-5f);
  float c0 = d0 * rs * g[tid] + bb[tid];
  float c1 = d1 * rs * g[256 + tid] + bb[256 + tid];
  ctl[tid] = c0;
  ctl[256 + tid] = c1;
  c_t[(size_t)b * 514 + tid] = c0;
  c_t[(size_t)b * 514 + 256 + tid] = c1;
  if (tid < 2) {
    float c2 = dq * rs * g[512 + tid] + bb[512 + tid];
    ctl[512 + tid] = c2;
    c_t[(size_t)b * 514 + 512 + tid] = c2;
  }
  __syncthreads();
  if (tid < 192) {
    int t = tid >> 4, f = tid & 15;
    float acc = 0.f;
    for (int c = 0; c < 514; ++c)
      acc += ctl[c] * ct_w[(size_t)(t * 514 + c) * 16 + f];
    float diff = acc - x1[(size_t)(b * 36 + 24 + t) * 16 + f];
    sq[tid] = diff * diff;
  }
  __syncthreads();
  if (tid < 12) {
    float s = 0.f;
    #pragma unroll
    for (int f = 0; f < 16; ++f) s += sq[tid * 16 + f];
    float w = f_ind[b * 12 + tid];
    atomicAdd(&accum[0], (s * (1.f / 16.f)) * w);
    atomicAdd(&accum[1], w);
  }
}

// ---------------- z1 = c_t @ fc_W1 + fc_b1 ----------------
__global__ __launch_bounds__(64) void fc1_kernel(
    const float* __restrict__ c_t, const float* __restrict__ fc_W1,
    const float* __restrict__ fc_b1, float* __restrict__ z1) {
  int t = blockIdx.x, b = blockIdx.y, dd = threadIdx.x;
  __shared__ float ct[514];
  for (int i = dd; i < 514; i += 64) ct[i] = c_t[(size_t)b * 514 + i];
  __syncthreads();
  float acc = fc_b1[t * 64 + dd];
  for (int c = 0; c < 514; ++c)
    acc += ct[c] * fc_W1[(size_t)(t * 514 + c) * 64 + dd];
  z1[(size_t)(t * 256 + b) * 64 + dd] = acc;
}

// ---------------- batchnorm stats over B per (t, dd) ----------------
__global__ __launch_bounds__(256) void bn_stats_kernel(
    const float* __restrict__ z1, float* __restrict__ mu,
    float* __restrict__ rstd) {
  __shared__ float red[8];
  int t = blockIdx.x >> 6;
  int dd = blockIdx.x & 63;
  int b = threadIdx.x;
  float v = z1[(size_t)(t * 256 + b) * 64 + dd];
  float mean = blockReduceSum(v, red) * (1.f / 256.f);
  float d = v - mean;
  float var = blockReduceSum(d * d, red) * (1.f / 256.f);
  if (b == 0) {
    mu[t * 64 + dd] = mean;
    rstd[t * 64 + dd] = rsqrtf(var + 1e-5f);
  }
}

// ---------------- out = relu(bn(z1)) @ fc_W2 + fc_b2 ----------------
__global__ __launch_bounds__(64) void out_kernel(
    const float* __restrict__ z1, const float* __restrict__ mu,
    const float* __restrict__ rstd, const float* __restrict__ bn_g,
    const float* __restrict__ bn_b, const float* __restrict__ fc_W2,
    const float* __restrict__ fc_b2, float* __restrict__ out) {
  int t = blockIdx.x, b = blockIdx.y, dd = threadIdx.x;
  float v = z1[(size_t)(t * 256 + b) * 64 + dd];
  float zn = (v - mu[t * 64 + dd]) * rstd[t * 64 + dd] * bn_g[t * 64 + dd] +
             bn_b[t * 64 + dd];
  float val = fmaxf(zn, 0.f) * fc_W2[t * 64 + dd];
  #pragma unroll
  for (int off = 32; off > 0; off >>= 1) val += __shfl_down(val, off, 64);
  if (dd == 0) out[t * 256 + b] = val + fc_b2[t];
}

__global__ void loss_final_kernel(const float* __restrict__ accum,
                                  float* __restrict__ out) {
  out[0] = accum[0] / accum[1];
}

// =======================================================================
extern "C" void kernel_launch(void* const* d_in, const int* in_sizes, int n_in,
                              void* d_out, int out_size, void* d_ws,
                              size_t ws_size, hipStream_t stream) {
  const float* x1 = (const float*)d_in[0];
  const float* h0 = (const float*)d_in[1];
  const float* m1 = (const float*)d_in[2];
  const float* d1 = (const float*)d_in[3];
  const float* x_m = (const float*)d_in[4];
  const float* age = (const float*)d_in[5];
  const float* gen = (const float*)d_in[6];
  const int* input_lengths = (const int*)d_in[7];
  const int* txts = (const int*)d_in[8];
  const int* txt_lengths = (const int*)d_in[9];
  const float* f_ind = (const float*)d_in[10];
  const float* emb = (const float*)d_in[11];
  const float* Win = (const float*)d_in[12];
  const float* bin_ = (const float*)d_in[13];
  const float* ln_in_g = (const float*)d_in[14];
  const float* ln_in_b = (const float*)d_in[15];
  const float* Wq = (const float*)d_in[16];
  const float* bq = (const float*)d_in[17];
  const float* Wk = (const float*)d_in[18];
  const float* bk = (const float*)d_in[19];
  const float* Wv = (const float*)d_in[20];
  const float* bv = (const float*)d_in[21];
  const float* Wo = (const float*)d_in[22];
  const float* bo = (const float*)d_in[23];
  const float* ln1_g = (const float*)d_in[24];
  const float* ln1_b = (const float*)d_in[25];
  const float* Wf1 = (const float*)d_in[26];
  const float* bf1 = (const float*)d_in[27];
  const float* Wf2 = (const float*)d_in[28];
  const float* bf2 = (const float*)d_in[29];
  const float* ln2_g = (const float*)d_in[30];
  const float* ln2_b = (const float*)d_in[31];
  const float* dec_w = (const float*)d_in[32];
  const float* dec_b = (const float*)d_in[33];
  const float* hd_W = (const float*)d_in[34];
  const float* hd_b = (const float*)d_in[35];
  const float* W_ih = (const float*)d_in[36];
  const float* b_ih = (const float*)d_in[37];
  const float* W_hh = (const float*)d_in[38];
  const float* b_hh = (const float*)d_in[39];
  const float* ln_c_g = (const float*)d_in[40];
  const float* ln_c_b = (const float*)d_in[41];
  const float* ct_w = (const float*)d_in[42];
  const float* fc_W1 = (const float*)d_in[43];
  const float* fc_b1 = (const float*)d_in[44];
  const float* bn_g = (const float*)d_in[45];
  const float* bn_b = (const float*)d_in[46];
  const float* fc_W2 = (const float*)d_in[47];
  const float* fc_b2 = (const float*)d_in[48];
  float* out = (float*)d_out;

  // ---- workspace layout (bytes) ----
  char* base = (char*)d_ws;
  u16* hdd_bf = (u16*)(base + 0);             // 16.8 MB (residual stream)
  u16* qkvb = (u16*)(base + 16777216);        // 50.3 MB
  u16* ob = (u16*)(base + 67108864);          // 16.8 MB (also tx_bf)
  u16* WinT = (u16*)(base + 83886080);        // 65536 el
  u16* WqkvT = WinT + 65536;                  // 4 x 196608 el
  u16* WoT = WqkvT + 786432;                  // 4 x 65536 el
  u16* Wf1T = WoT + 262144;                   // 4 x 131072 el
  u16* Wf2T = Wf1T + 524288;                  // 4 x 131072 el
  float* bqkv = (float*)(base + 88211456);    // 3072 f32
  float* pe = (float*)(base + 88223744);      // 128 KB
  u16* WhhT = (u16*)(base + 88354816);        // 384 KB bf16 [768][256]
  // GRU/head overlay over qkvb/ob (dead post-transformer); hdd_bf stays live
  char* gru = base + 16777216;
  float* xprep = (float*)gru;                 // 786432 B
  float* dprep = (float*)(gru + 786432);      // 393216 B
  float* gx = (float*)(gru + 1179648);        // 18874368 B
  float* hdcyb = (float*)(gru + 20054016);    // 6291456 B
  float* ys = (float*)(gru + 26345472);       // 6291456 B
  float* c_t = (float*)(gru + 32636928);      // 526336 B
  float* z1 = (float*)(gru + 33163264);       // 786432 B
  float* muv = (float*)(gru + 33949696);
  float* rstdv = (float*)(gru + 33952768);
  float* accum = (float*)(gru + 33955840);

  hipMemsetAsync(accum, 0, 2 * sizeof(float), stream);

  // ---- weight conversion ----
  transpose_bf16<<<dim3(8, 8, 1), 256, 0, stream>>>(Win, WinT, 256, 256, 65536);
  transpose_qkvo<<<dim3(8, 8, 16), 256, 0, stream>>>(Wq, Wk, Wv, Wo, WqkvT,
                                                     WoT);
  transpose_bf16<<<dim3(16, 8, 4), 256, 0, stream>>>(Wf1, Wf1T, 256, 512,
                                                     131072);
  transpose_bf16<<<dim3(8, 16, 4), 256, 0, stream>>>(Wf2, Wf2T, 512, 256,
                                                     131072);
  transpose_bf16<<<dim3(24, 8, 1), 256, 0, stream>>>(W_hh, WhhT, 256, 768,
                                                     196608);
  bias_concat_kernel<<<4, 768, 0, stream>>>(bq, bk, bv, bqkv);

  // ---- text transformer ----
  pe_kernel<<<128, 256, 0, stream>>>(pe);
  gather_kernel<<<8192, 256, 0, stream>>>(txts, emb, ob);  // tx in ob
  gemm_ln<<<512, 256, 0, stream>>>(ob, WinT, bin_, ln_in_g, ln_in_b, pe,
                                   hdd_bf, 32768, 256, 1);
  for (int l = 0; l < 4; ++l) {
    gemm_bf16<<<dim3(6, 256), 256, 0, stream>>>(hdd_bf, WqkvT + l * 196608,
                                                bqkv + l * 768, qkvb, 32768,
                                                768, 256, 0);
    attn_kernel<<<2048, 128, 0, stream>>>(qkvb, txt_lengths, ob);
    gemm_ln<<<512, 256, 0, stream>>>(ob, WoT + l * 65536, bo + l * 256,
                                     ln1_g + l * 256, ln1_b + l * 256, pe,
                                     hdd_bf, 32768, 256, 0);
    ffn_ln<<<512, 512, 0, stream>>>(hdd_bf, Wf1T + l * 131072, bf1 + l * 512,
                                    Wf2T + l * 131072, bf2 + l * 256,
                                    ln2_g + l * 256, ln2_b + l * 256, hdd_bf,
                                    32768);
  }

  // ---- GRU-D branch ----
  impute_kernel<<<384, 256, 0, stream>>>(x1, m1, d1, dec_w, dec_b, x_m, xprep,
                                         dprep);
  gemm_f32<<<dim3(12, 96), 256, 0, stream>>>(xprep, W_ih, b_ih, gx, 6144, 768,
                                             32, 0);
  gemm_f32<<<dim3(4, 96), 256, 0, stream>>>(dprep, hd_W, hd_b, hdcyb, 6144,
                                            256, 16, 2);
  gru_scan_mfma<<<128, 256, 0, stream>>>(gx, hdcyb, WhhT, b_hh, h0, ys);

  // ---- head ----
  ct_pred_kernel<<<256, 256, 0, stream>>>(ys, hdd_bf, input_lengths, age, gen,
                                          ln_c_g, ln_c_b, c_t, ct_w, x1, f_ind,
                                          accum);
  fc1_kernel<<<dim3(12, 256), 64, 0, stream>>>(c_t, fc_W1, fc_b1, z1);
  bn_stats_kernel<<<768, 256, 0, stream>>>(z1, muv, rstdv);
  out_kernel<<<dim3(12, 256), 64, 0, stream>>>(z1, muv, rstdv, bn_g, bn_b,
                                               fc_W2, fc_b2, out);
  loss_final_kernel<<<1, 1, 0, stream>>>(accum, out + 3072);
}

// Round 16
// 1020.152 us; speedup vs baseline: 1.7700x; 1.1215x over previous
//
#include <hip/hip_runtime.h>
#include <math.h>

typedef unsigned short u16;
typedef unsigned int u32;
typedef short bf16x8 __attribute__((ext_vector_type(8)));
typedef float f32x4 __attribute__((ext_vector_type(4)));

__device__ __forceinline__ u16 f2bf(float f) {
  u32 u = __float_as_uint(f);
  u32 r = (u + 0x7fffu + ((u >> 16) & 1u)) >> 16;
  return (u16)r;
}
__device__ __forceinline__ float bf2f(u16 h) {
  return __uint_as_float(((u32)h) << 16);
}
// async global->LDS, 16B per lane; LDS dest = wave-uniform base + lane*16
__device__ __forceinline__ void gload_lds16(const u16* g, u16* l) {
  __builtin_amdgcn_global_load_lds(
      (const __attribute__((address_space(1))) void*)g,
      (__attribute__((address_space(3))) void*)l, 16, 0, 0);
}
__device__ __forceinline__ float blockReduceSum(float v, float* red) {
  #pragma unroll
  for (int off = 32; off > 0; off >>= 1) v += __shfl_down(v, off, 64);
  const int lane = threadIdx.x & 63;
  const int wid = threadIdx.x >> 6;
  __syncthreads();
  if (lane == 0) red[wid] = v;
  __syncthreads();
  const int nw = (blockDim.x + 63) >> 6;
  float s = red[0];
  for (int i = 1; i < nw; ++i) s += red[i];
  return s;
}

// ---------------- positional encoding ----------------
__global__ void pe_kernel(float* __restrict__ pe) {
  int l = blockIdx.x;
  int i = threadIdx.x;
  double e = exp2(-(double)(2 * (i / 2)) / 256.0 * 13.287712379549449);
  double ang = (double)l * e;
  pe[l * 256 + i] = (float)((i & 1) ? cos(ang) : sin(ang));
}

// ---------------- embedding gather -> bf16 (wave per row) ----------------
__global__ __launch_bounds__(256) void gather_kernel(
    const int* __restrict__ txts, const float* __restrict__ emb,
    u16* __restrict__ tx) {
  int row = blockIdx.x * 4 + (threadIdx.x >> 6);
  int lane = threadIdx.x & 63;
  int tok = txts[row];
  float4 e = *(const float4*)(emb + (size_t)tok * 256 + lane * 4);
  u16 o[4] = {f2bf(e.x), f2bf(e.y), f2bf(e.z), f2bf(e.w)};
  *(uint2*)(tx + (size_t)row * 256 + lane * 4) = *(const uint2*)o;
}

// ------- weight transpose fp32[K][N] -> bf16[N][K], custom group stride ----
__global__ __launch_bounds__(256) void transpose_bf16(
    const float* __restrict__ W, u16* __restrict__ Wt, int K, int N,
    int dstStride) {
  __shared__ float tile[32][33];
  int g = blockIdx.z;
  const float* Wg = W + (size_t)g * K * N;
  u16* Wtg = Wt + (size_t)g * dstStride;
  int n0 = blockIdx.x * 32, k0 = blockIdx.y * 32;
  int tx = threadIdx.x & 31, ty = threadIdx.x >> 5;
  #pragma unroll
  for (int i = 0; i < 32; i += 8)
    tile[ty + i][tx] = Wg[(size_t)(k0 + ty + i) * N + n0 + tx];
  __syncthreads();
  #pragma unroll
  for (int i = 0; i < 32; i += 8)
    Wtg[(size_t)(n0 + ty + i) * K + k0 + tx] = f2bf(tile[tx][ty + i]);
}

// ------- merged transpose for Wq/Wk/Wv/Wo (all [4][256][256]) -------------
__global__ __launch_bounds__(256) void transpose_qkvo(
    const float* __restrict__ Wq, const float* __restrict__ Wk,
    const float* __restrict__ Wv, const float* __restrict__ Wo,
    u16* __restrict__ WqkvT, u16* __restrict__ WoT) {
  __shared__ float tile[32][33];
  int z = blockIdx.z, l = z >> 2, which = z & 3;
  const float* src = (which == 0) ? Wq : (which == 1) ? Wk
                     : (which == 2) ? Wv : Wo;
  src += (size_t)l * 65536;
  u16* dst = (which < 3) ? (WqkvT + (size_t)l * 196608 + which * 65536)
                         : (WoT + (size_t)l * 65536);
  int n0 = blockIdx.x * 32, k0 = blockIdx.y * 32;
  int tx = threadIdx.x & 31, ty = threadIdx.x >> 5;
  #pragma unroll
  for (int i = 0; i < 32; i += 8)
    tile[ty + i][tx] = src[(size_t)(k0 + ty + i) * 256 + n0 + tx];
  __syncthreads();
  #pragma unroll
  for (int i = 0; i < 32; i += 8)
    dst[(size_t)(n0 + ty + i) * 256 + k0 + tx] = f2bf(tile[tx][ty + i]);
}

// ---------------- concat qkv bias ----------------
__global__ void bias_concat_kernel(const float* __restrict__ bq,
                                   const float* __restrict__ bk,
                                   const float* __restrict__ bv,
                                   float* __restrict__ bqkv) {
  int l = blockIdx.x, i = threadIdx.x;
  float v;
  if (i < 256) v = bq[l * 256 + i];
  else if (i < 512) v = bk[l * 256 + i - 256];
  else v = bv[l * 256 + i - 512];
  bqkv[l * 768 + i] = v;
}

// ---------------- bf16 MFMA GEMM, 128x128 tile (m97 shape) ----------------
// grid (N/128, M/128), block 256 (4 waves: 2x2). act: 0 none, 1 relu.
__global__ __launch_bounds__(256) void gemm_bf16(
    const u16* __restrict__ A, const u16* __restrict__ Bt,
    const float* __restrict__ bias, u16* __restrict__ Cb, int M, int N, int K,
    int act) {
  __shared__ u16 As[128][32];
  __shared__ u16 Bs[128][32];
  const int tid = threadIdx.x;
  const int wave = tid >> 6, lane = tid & 63;
  const int wr = wave >> 1, wc = wave & 1;
  const int rowblk = blockIdx.y * 128, colblk = blockIdx.x * 128;
  const int l16 = lane & 15, lq = lane >> 4;
  const int lr = lane >> 2, lc = lane & 3;
  const int r0 = wave * 32;
  f32x4 acc[4][4];
  #pragma unroll
  for (int i = 0; i < 4; ++i)
    #pragma unroll
    for (int j = 0; j < 4; ++j) acc[i][j] = (f32x4)(0.f);

  for (int kt = 0; kt < K; kt += 32) {
    __syncthreads();
    gload_lds16(A + (size_t)(rowblk + r0 + lr) * K + kt + lc * 8, &As[r0][0]);
    gload_lds16(A + (size_t)(rowblk + r0 + 16 + lr) * K + kt + lc * 8,
                &As[r0 + 16][0]);
    gload_lds16(Bt + (size_t)(colblk + r0 + lr) * K + kt + lc * 8, &Bs[r0][0]);
    gload_lds16(Bt + (size_t)(colblk + r0 + 16 + lr) * K + kt + lc * 8,
                &Bs[r0 + 16][0]);
    __syncthreads();
    bf16x8 af[4], bfr[4];
    #pragma unroll
    for (int t = 0; t < 4; ++t) {
      af[t] = *(const bf16x8*)&As[wr * 64 + t * 16 + l16][lq * 8];
      bfr[t] = *(const bf16x8*)&Bs[wc * 64 + t * 16 + l16][lq * 8];
    }
    #pragma unroll
    for (int i = 0; i < 4; ++i)
      #pragma unroll
      for (int j = 0; j < 4; ++j)
        acc[i][j] = __builtin_amdgcn_mfma_f32_16x16x32_bf16(af[i], bfr[j],
                                                            acc[i][j], 0, 0, 0);
  }
  const int rbase = rowblk + wr * 64, cbase = colblk + wc * 64;
  #pragma unroll
  for (int j = 0; j < 4; ++j) {
    int col = cbase + j * 16 + l16;
    float bv = bias[col];
    #pragma unroll
    for (int i = 0; i < 4; ++i) {
      int row0 = rbase + i * 16 + lq * 4;
      #pragma unroll
      for (int r = 0; r < 4; ++r) {
        float vv = acc[i][j][r] + bv;
        if (act == 1) vv = fmaxf(vv, 0.f);
        Cb[(size_t)(row0 + r) * N + col] = f2bf(vv);
      }
    }
  }
}

// ------- fused GEMM (N=256) + bf16 residual/PE + LayerNorm -----------------
// 64-row blocks, 256 threads (4 col-waves). grid = M/64.
__global__ __launch_bounds__(256) void gemm_ln(
    const u16* __restrict__ A, const u16* __restrict__ Bt,
    const float* __restrict__ bias, const float* __restrict__ g,
    const float* __restrict__ bvec, const float* __restrict__ pe,
    u16* __restrict__ hddbf, int M, int K, int mode) {
  __shared__ u16 As[64][32];
  __shared__ u16 Bs[256][32];
  __shared__ float redS[4][64];
  __shared__ float redQ[4][64];
  __shared__ float rowstat[64][2];
  const int tid = threadIdx.x;
  const int wave = tid >> 6, lane = tid & 63;
  const int wc = wave;
  const int rowblk = blockIdx.x * 64;
  const int l16 = lane & 15, lq = lane >> 4;
  const int lr = lane >> 2, lc = lane & 3;
  f32x4 acc[4][4];
  #pragma unroll
  for (int i = 0; i < 4; ++i)
    #pragma unroll
    for (int j = 0; j < 4; ++j) acc[i][j] = (f32x4)(0.f);

  for (int kt = 0; kt < K; kt += 32) {
    __syncthreads();
    gload_lds16(A + (size_t)(rowblk + wave * 16 + lr) * K + kt + lc * 8,
                &As[wave * 16][0]);
    #pragma unroll
    for (int p = 0; p < 4; ++p)
      gload_lds16(Bt + (size_t)(wave * 64 + p * 16 + lr) * K + kt + lc * 8,
                  &Bs[wave * 64 + p * 16][0]);
    __syncthreads();
    bf16x8 af[4], bfr[4];
    #pragma unroll
    for (int t = 0; t < 4; ++t) {
      af[t] = *(const bf16x8*)&As[t * 16 + l16][lq * 8];
      bfr[t] = *(const bf16x8*)&Bs[wc * 64 + t * 16 + l16][lq * 8];
    }
    #pragma unroll
    for (int i = 0; i < 4; ++i)
      #pragma unroll
      for (int j = 0; j < 4; ++j)
        acc[i][j] = __builtin_amdgcn_mfma_f32_16x16x32_bf16(af[i], bfr[j],
                                                            acc[i][j], 0, 0, 0);
  }
  const int cbase = wc * 64;
  #pragma unroll
  for (int j = 0; j < 4; ++j) {
    int col = cbase + j * 16 + l16;
    float bv = bias[col];
    #pragma unroll
    for (int i = 0; i < 4; ++i) {
      int row0 = rowblk + i * 16 + lq * 4;
      #pragma unroll
      for (int r = 0; r < 4; ++r) {
        float v = acc[i][j][r] + bv;
        if (mode == 0) v += bf2f(hddbf[(size_t)(row0 + r) * 256 + col]);
        acc[i][j][r] = v;
      }
    }
  }
  #pragma unroll
  for (int i = 0; i < 4; ++i) {
    #pragma unroll
    for (int r = 0; r < 4; ++r) {
      float s = 0.f, q = 0.f;
      #pragma unroll
      for (int j = 0; j < 4; ++j) {
        float v = acc[i][j][r];
        s += v;
        q += v * v;
      }
      #pragma unroll
      for (int m = 1; m < 16; m <<= 1) {
        s += __shfl_xor(s, m, 64);
        q += __shfl_xor(q, m, 64);
      }
      if (l16 == 0) {
        int lrr = i * 16 + lq * 4 + r;
        redS[wc][lrr] = s;
        redQ[wc][lrr] = q;
      }
    }
  }
  __syncthreads();
  if (tid < 64) {
    float s = redS[0][tid] + redS[1][tid] + redS[2][tid] + redS[3][tid];
    float q = redQ[0][tid] + redQ[1][tid] + redQ[2][tid] + redQ[3][tid];
    float mean = s * (1.f / 256.f);
    float var = q * (1.f / 256.f) - mean * mean;
    rowstat[tid][0] = mean;
    rowstat[tid][1] = rsqrtf(var + 1e-5f);
  }
  __syncthreads();
  float gg[4], bb2[4];
  #pragma unroll
  for (int j = 0; j < 4; ++j) {
    int col = cbase + j * 16 + l16;
    gg[j] = g[col];
    bb2[j] = bvec[col];
  }
  #pragma unroll
  for (int i = 0; i < 4; ++i) {
    #pragma unroll
    for (int r = 0; r < 4; ++r) {
      int lrr = i * 16 + lq * 4 + r;
      int row = rowblk + lrr;
      float mean = rowstat[lrr][0], rstd = rowstat[lrr][1];
      #pragma unroll
      for (int j = 0; j < 4; ++j) {
        int col = cbase + j * 16 + l16;
        float o = (acc[i][j][r] - mean) * rstd * gg[j] + bb2[j];
        if (mode == 1) o += pe[(size_t)(row & 127) * 256 + col];
        hddbf[(size_t)row * 256 + col] = f2bf(o);
      }
    }
  }
}

// ------- fused FFN: relu(A@W1+b1)@W2+b2 + residual + LN --------------------
// A read directly from L2-hot global (no As staging) -> LDS ~71 KB, 2 blk/CU
__global__ __launch_bounds__(512) void ffn_ln(
    const u16* __restrict__ A, const u16* __restrict__ W1t,
    const float* __restrict__ b1, const u16* __restrict__ W2t,
    const float* __restrict__ b2, const float* __restrict__ g,
    const float* __restrict__ bvec, u16* __restrict__ hddbf, int M) {
  __shared__ u16 Fs[64][536];  // stride 536 u16 = 1072B: ~2-4 way conflicts
  __shared__ float redS[4][64];
  __shared__ float redQ[4][64];
  __shared__ float rowstat[64][2];
  const int tid = threadIdx.x;
  const int wave = tid >> 6, lane = tid & 63;
  const int l16 = lane & 15, lq = lane >> 4;
  const int rowblk = blockIdx.x * 64;
  {
    f32x4 acc1[4][4];
    #pragma unroll
    for (int i = 0; i < 4; ++i)
      #pragma unroll
      for (int j = 0; j < 4; ++j) acc1[i][j] = (f32x4)(0.f);
    #pragma unroll
    for (int kt = 0; kt < 8; ++kt) {
      bf16x8 af[4], bfr[4];
      #pragma unroll
      for (int t = 0; t < 4; ++t) {
        af[t] = *(const bf16x8*)(A + (size_t)(rowblk + t * 16 + l16) * 256 +
                                 kt * 32 + lq * 8);
        bfr[t] = *(const bf16x8*)(W1t +
                                  (size_t)(wave * 64 + t * 16 + l16) * 256 +
                                  kt * 32 + lq * 8);
      }
      #pragma unroll
      for (int i = 0; i < 4; ++i)
        #pragma unroll
        for (int j = 0; j < 4; ++j)
          acc1[i][j] = __builtin_amdgcn_mfma_f32_16x16x32_bf16(
              af[i], bfr[j], acc1[i][j], 0, 0, 0);
    }
    #pragma unroll
    for (int j = 0; j < 4; ++j) {
      int col = wave * 64 + j * 16 + l16;
      float bias1 = b1[col];
      #pragma unroll
      for (int i = 0; i < 4; ++i) {
        int row0 = i * 16 + lq * 4;
        #pragma unroll
        for (int r = 0; r < 4; ++r)
          Fs[row0 + r][col] = f2bf(fmaxf(acc1[i][j][r] + bias1, 0.f));
      }
    }
  }
  __syncthreads();
  const int wr = wave >> 2, wc = wave & 3;
  f32x4 acc2[2][4];
  #pragma unroll
  for (int i = 0; i < 2; ++i)
    #pragma unroll
    for (int j = 0; j < 4; ++j) acc2[i][j] = (f32x4)(0.f);
  #pragma unroll
  for (int kt = 0; kt < 16; ++kt) {
    bf16x8 af[2], bfr[4];
    #pragma unroll
    for (int i = 0; i < 2; ++i)
      af[i] = *(const bf16x8*)&Fs[wr * 32 + i * 16 + l16][kt * 32 + lq * 8];
    #pragma unroll
    for (int j = 0; j < 4; ++j)
      bfr[j] = *(const bf16x8*)(W2t + (size_t)(wc * 64 + j * 16 + l16) * 512 +
                                kt * 32 + lq * 8);
    #pragma unroll
    for (int i = 0; i < 2; ++i)
      #pragma unroll
      for (int j = 0; j < 4; ++j)
        acc2[i][j] = __builtin_amdgcn_mfma_f32_16x16x32_bf16(af[i], bfr[j],
                                                             acc2[i][j], 0, 0,
                                                             0);
  }
  #pragma unroll
  for (int j = 0; j < 4; ++j) {
    int col = wc * 64 + j * 16 + l16;
    float bias2 = b2[col];
    #pragma unroll
    for (int i = 0; i < 2; ++i) {
      int row0 = rowblk + wr * 32 + i * 16 + lq * 4;
      #pragma unroll
      for (int r = 0; r < 4; ++r)
        acc2[i][j][r] += bias2 + bf2f(hddbf[(size_t)(row0 + r) * 256 + col]);
    }
  }
  #pragma unroll
  for (int i = 0; i < 2; ++i) {
    #pragma unroll
    for (int r = 0; r < 4; ++r) {
      float s = 0.f, q = 0.f;
      #pragma unroll
      for (int j = 0; j < 4; ++j) {
        float v = acc2[i][j][r];
        s += v;
        q += v * v;
      }
      #pragma unroll
      for (int m = 1; m < 16; m <<= 1) {
        s += __shfl_xor(s, m, 64);
        q += __shfl_xor(q, m, 64);
      }
      if (l16 == 0) {
        int lrr = wr * 32 + i * 16 + lq * 4 + r;
        redS[wc][lrr] = s;
        redQ[wc][lrr] = q;
      }
    }
  }
  __syncthreads();
  if (tid < 64) {
    float s = redS[0][tid] + redS[1][tid] + redS[2][tid] + redS[3][tid];
    float q = redQ[0][tid] + redQ[1][tid] + redQ[2][tid] + redQ[3][tid];
    float mean = s * (1.f / 256.f);
    float var = q * (1.f / 256.f) - mean * mean;
    rowstat[tid][0] = mean;
    rowstat[tid][1] = rsqrtf(var + 1e-5f);
  }
  __syncthreads();
  #pragma unroll
  for (int j = 0; j < 4; ++j) {
    int col = wc * 64 + j * 16 + l16;
    float gg = g[col], bb2v = bvec[col];
    #pragma unroll
    for (int i = 0; i < 2; ++i) {
      #pragma unroll
      for (int r = 0; r < 4; ++r) {
        int lrr = wr * 32 + i * 16 + lq * 4 + r;
        int row = rowblk + lrr;
        float o = (acc2[i][j][r] - rowstat[lrr][0]) * rowstat[lrr][1] * gg +
                  bb2v;
        hddbf[(size_t)row * 256 + col] = f2bf(o);
      }
    }
  }
}

// ---------------- generic fp32 GEMM (small GRU matmuls) ----------------
__global__ __launch_bounds__(256) void gemm_f32(
    const float* __restrict__ A, const float* __restrict__ B,
    const float* __restrict__ bias, float* __restrict__ C,
    int M, int N, int K, int act) {
  __shared__ float As[16][68];
  __shared__ float Bs[16][64];
  const int id = threadIdx.x;
  const int tx = id & 15;
  const int ty = id >> 4;
  const int colblk = blockIdx.x * 64;
  const int rowblk = blockIdx.y * 64;
  const int lin = id * 4;
  const int ar = lin >> 4;
  const int ac = lin & 15;
  const int bc = lin >> 6;
  const int bcol = lin & 63;
  float acc[4][4] = {};
  for (int kt = 0; kt < K; kt += 16) {
    float4 a4 = *(const float4*)(A + (size_t)(rowblk + ar) * K + kt + ac);
    float4 b4 = *(const float4*)(B + (size_t)(kt + bc) * N + colblk + bcol);
    As[ac + 0][ar] = a4.x; As[ac + 1][ar] = a4.y;
    As[ac + 2][ar] = a4.z; As[ac + 3][ar] = a4.w;
    *(float4*)&Bs[bc][bcol] = b4;
    __syncthreads();
    #pragma unroll
    for (int kk = 0; kk < 16; ++kk) {
      float4 av = *(const float4*)&As[kk][ty * 4];
      float4 bv = *(const float4*)&Bs[kk][tx * 4];
      float a[4] = {av.x, av.y, av.z, av.w};
      float b[4] = {bv.x, bv.y, bv.z, bv.w};
      #pragma unroll
      for (int i = 0; i < 4; ++i)
        #pragma unroll
        for (int j = 0; j < 4; ++j) acc[i][j] += a[i] * b[j];
    }
    __syncthreads();
  }
  const int col = colblk + tx * 4;
  float4 bi = *(const float4*)(bias + col);
  #pragma unroll
  for (int i = 0; i < 4; ++i) {
    float r[4] = {acc[i][0] + bi.x, acc[i][1] + bi.y,
                  acc[i][2] + bi.z, acc[i][3] + bi.w};
    if (act == 2) {
      #pragma unroll
      for (int j = 0; j < 4; ++j) r[j] = expf(-fmaxf(r[j], 0.f));
    }
    *(float4*)(C + (size_t)(rowblk + ty * 4 + i) * N + col) =
        make_float4(r[0], r[1], r[2], r[3]);
  }
}

// ---------------- MFMA flash attention ------------------------------------
__global__ __launch_bounds__(128) void attn_kernel(
    const u16* __restrict__ qkv, const int* __restrict__ txt_lengths,
    u16* __restrict__ o) {
  __shared__ u16 Qs[128][40];
  __shared__ u16 Ksh[128][40];
  __shared__ u16 Vt[32][136];   // V transposed: [d][j]
  __shared__ u16 Ps[128][136];  // P bf16
  __shared__ float lrow[128];
  int bh = blockIdx.x;
  int b = bh >> 3, h = bh & 7;
  int t = threadIdx.x;
  int len = txt_lengths[b] + 2;
  const int wave = t >> 6, lane = t & 63;
  const int l16 = lane & 15, lq = lane >> 4;
  const size_t base = ((size_t)b * 128) * 768 + h * 32;
  #pragma unroll
  for (int p = 0; p < 4; ++p) {
    int idx = p * 128 + t;
    int row = idx >> 2, ch = idx & 3;
    size_t gofs = base + (size_t)row * 768 + ch * 8;
    uint4 q4 = *(const uint4*)(qkv + gofs);
    uint4 k4 = *(const uint4*)(qkv + gofs + 256);
    uint4 v4 = *(const uint4*)(qkv + gofs + 512);
    *(uint4*)&Qs[row][ch * 8] = q4;
    *(uint4*)&Ksh[row][ch * 8] = k4;
    const u16* vs = (const u16*)&v4;
    #pragma unroll
    for (int e = 0; e < 8; ++e) Vt[ch * 8 + e][row] = vs[e];
  }
  __syncthreads();
  const int rbase = wave * 64;
  const float scale = 0.17677669529663687f;
  #pragma unroll
  for (int rt = 0; rt < 4; ++rt) {
    bf16x8 qf = *(const bf16x8*)&Qs[rbase + rt * 16 + l16][lq * 8];
    float psum[4] = {0.f, 0.f, 0.f, 0.f};
    #pragma unroll
    for (int ct = 0; ct < 8; ++ct) {
      bf16x8 kf = *(const bf16x8*)&Ksh[ct * 16 + l16][lq * 8];
      f32x4 acc = (f32x4)(0.f);
      acc = __builtin_amdgcn_mfma_f32_16x16x32_bf16(qf, kf, acc, 0, 0, 0);
      int col = ct * 16 + l16;
      #pragma unroll
      for (int r = 0; r < 4; ++r) {
        float p = (col < len) ? __expf(acc[r] * scale) : 0.f;
        psum[r] += p;
        Ps[rbase + rt * 16 + lq * 4 + r][col] = f2bf(p);
      }
    }
    #pragma unroll
    for (int r = 0; r < 4; ++r) {
      float s = psum[r];
      s += __shfl_xor(s, 1, 64);
      s += __shfl_xor(s, 2, 64);
      s += __shfl_xor(s, 4, 64);
      s += __shfl_xor(s, 8, 64);
      if (l16 == 0) lrow[rbase + rt * 16 + lq * 4 + r] = s;
    }
  }
  __syncthreads();
  #pragma unroll
  for (int rt = 0; rt < 4; ++rt) {
    #pragma unroll
    for (int c2 = 0; c2 < 2; ++c2) {
      f32x4 acc = (f32x4)(0.f);
      #pragma unroll
      for (int kt = 0; kt < 4; ++kt) {
        bf16x8 pf = *(const bf16x8*)&Ps[rbase + rt * 16 + l16][kt * 32 + lq * 8];
        bf16x8 vf = *(const bf16x8*)&Vt[c2 * 16 + l16][kt * 32 + lq * 8];
        acc = __builtin_amdgcn_mfma_f32_16x16x32_bf16(pf, vf, acc, 0, 0, 0);
      }
      int col = c2 * 16 + l16;
      #pragma unroll
      for (int r = 0; r < 4; ++r) {
        int row = rbase + rt * 16 + lq * 4 + r;
        float inv = 1.f / lrow[row];
        o[(size_t)(b * 128 + row) * 256 + h * 32 + col] = f2bf(acc[r] * inv);
      }
    }
  }
}

// ---------------- GRU-D input imputation + concat ----------------
__global__ void impute_kernel(
    const float* __restrict__ x1, const float* __restrict__ m1,
    const float* __restrict__ d1, const float* __restrict__ dec_w,
    const float* __restrict__ dec_b, const float* __restrict__ x_m,
    float* __restrict__ xprep, float* __restrict__ dprep) {
  int idx = blockIdx.x * 256 + threadIdx.x;
  if (idx >= 256 * 24 * 16) return;
  int f = idx & 15;
  int t = (idx >> 4) % 24;
  int b = idx / (24 * 16);
  int src = (b * 36 + t) * 16 + f;
  float x = x1[src], m = m1[src], d = d1[src];
  float xd = expf(-fmaxf(d * dec_w[f] + dec_b[f], 0.f));
  float xv = m * x + (1.f - m) * xd * x + (1.f - m) * (1.f - xd) * x_m[f];
  int dst = b * 24 + t;
  xprep[dst * 32 + f] = xv;
  xprep[dst * 32 + 16 + f] = m;
  dprep[dst * 16 + f] = d;
}

// ------- GRU scan MFMA: 128 blocks x 2 batches; zero-frag for l16>=2 ------
__global__ __launch_bounds__(256) void gru_scan_mfma(
    const float* __restrict__ gx, const float* __restrict__ hdcyb,
    const u16* __restrict__ WhhT, const float* __restrict__ b_hh,
    const float* __restrict__ h0, float* __restrict__ ys) {
  __shared__ float hf[2][256];
  __shared__ u16 hbf[2][264];
  __shared__ float gls[2][768];
  const int b0 = blockIdx.x * 2;
  const int tid = threadIdx.x;
  const int wave = tid >> 6, lane = tid & 63;
  const int l16 = lane & 15, lq = lane >> 4;
  for (int i = tid; i < 512; i += 256) {
    int bb = i >> 8, col = i & 255;
    float v = h0[(size_t)(b0 + bb) * 256 + col] *
              hdcyb[(size_t)((b0 + bb) * 24) * 256 + col];
    hf[bb][col] = v;
    hbf[bb][col] = f2bf(v);
  }
  const float bh0 = b_hh[tid], bh1 = b_hh[256 + tid], bh2 = b_hh[512 + tid];
  __syncthreads();
  for (int t = 0; t < 24; ++t) {
    f32x4 acc[12];
    #pragma unroll
    for (int n = 0; n < 12; ++n) acc[n] = (f32x4)(0.f);
    #pragma unroll
    for (int kt = 0; kt < 8; ++kt) {
      bf16x8 af = (bf16x8)(short)0;
      if (l16 < 2) af = *(const bf16x8*)&hbf[l16][kt * 32 + lq * 8];
      #pragma unroll
      for (int n = 0; n < 12; ++n) {
        int col0 = wave * 192 + n * 16;
        bf16x8 bf = *(const bf16x8*)(WhhT + (size_t)(col0 + l16) * 256 +
                                     kt * 32 + lq * 8);
        acc[n] =
            __builtin_amdgcn_mfma_f32_16x16x32_bf16(af, bf, acc[n], 0, 0, 0);
      }
    }
    if (lq == 0) {
      #pragma unroll
      for (int n = 0; n < 12; ++n) {
        int col = wave * 192 + n * 16 + l16;
        gls[0][col] = acc[n][0];
        gls[1][col] = acc[n][1];
      }
    }
    __syncthreads();
    #pragma unroll
    for (int bb = 0; bb < 2; ++bb) {
      const float* gxr = gx + (size_t)((b0 + bb) * 24 + t) * 768;
      int col = tid;
      float r = 1.f / (1.f + __expf(-(gxr[col] + gls[bb][col] + bh0)));
      float z =
          1.f / (1.f + __expf(-(gxr[256 + col] + gls[bb][256 + col] + bh1)));
      float n = tanhf(gxr[512 + col] + r * (gls[bb][512 + col] + bh2));
      float h1d = hf[bb][col];
      float hn = (1.f - z) * n + z * h1d;
      ys[(size_t)(t * 256 + b0 + bb) * 256 + col] = hn;
      float nxt = (t < 23)
                      ? hdcyb[(size_t)((b0 + bb) * 24 + t + 1) * 256 + col]
                      : 1.f;
      float hd = hn * nxt;
      hf[bb][col] = hd;
      hbf[bb][col] = f2bf(hd);
    }
    __syncthreads();
  }
}

// ------- c_t = LN(concat(...)) + pred + masked-MSE (merged, unrolled) -----
__global__ __launch_bounds__(256) void ct_pred_kernel(
    const float* __restrict__ ys, const u16* __restrict__ hddbf,
    const int* __restrict__ input_lengths, const float* __restrict__ age,
    const float* __restrict__ gen, const float* __restrict__ g,
    const float* __restrict__ bb, float* __restrict__ c_t,
    const float* __restrict__ ct_w, const float* __restrict__ x1,
    const float* __restrict__ f_ind, float* __restrict__ accum) {
  __shared__ float buf[514];
  __shared__ float ctl[514];
  __shared__ float red[8];
  __shared__ float sq[192];
  int b = blockIdx.x, tid = threadIdx.x;
  int il = input_lengths[b] - 1;
  buf[tid] = ys[(size_t)(il * 256 + b) * 256 + tid];
  buf[256 + tid] = bf2f(hddbf[(size_t)(b * 128) * 256 + tid]);
  if (tid < 2) buf[512 + tid] = (tid == 0) ? age[b] : gen[b];
  __syncthreads();
  float p = buf[tid] + buf[256 + tid] + (tid < 2 ? buf[512 + tid] : 0.f);
  float mean = blockReduceSum(p, red) / 514.f;
  float d0 = buf[tid] - mean;
  float d1 = buf[256 + tid] - mean;
  float dq = (tid < 2) ? (buf[512 + tid] - mean) : 0.f;
  float var = blockReduceSum(d0 * d0 + d1 * d1 + dq * dq, red) / 514.f;
  float rs = rsqrtf(var + 1e-5f);
  float c0 = d0 * rs * g[tid] + bb[tid];
  float c1 = d1 * rs * g[256 + tid] + bb[256 + tid];
  ctl[tid] = c0;
  ctl[256 + tid] = c1;
  c_t[(size_t)b * 514 + tid] = c0;
  c_t[(size_t)b * 514 + 256 + tid] = c1;
  if (tid < 2) {
    float c2 = dq * rs * g[512 + tid] + bb[512 + tid];
    ctl[512 + tid] = c2;
    c_t[(size_t)b * 514 + 512 + tid] = c2;
  }
  __syncthreads();
  if (tid < 192) {
    int t = tid >> 4, f = tid & 15;
    const float* wb = ct_w + (size_t)t * 514 * 16 + f;
    // 8 independent accumulator chains -> 8 outstanding loads
    float a0 = 0.f, a1 = 0.f, a2 = 0.f, a3 = 0.f;
    float a4 = 0.f, a5 = 0.f, a6 = 0.f, a7 = 0.f;
    #pragma unroll 2
    for (int c = 0; c < 512; c += 8) {
      a0 += ctl[c + 0] * wb[(size_t)(c + 0) * 16];
      a1 += ctl[c + 1] * wb[(size_t)(c + 1) * 16];
      a2 += ctl[c + 2] * wb[(size_t)(c + 2) * 16];
      a3 += ctl[c + 3] * wb[(size_t)(c + 3) * 16];
      a4 += ctl[c + 4] * wb[(size_t)(c + 4) * 16];
      a5 += ctl[c + 5] * wb[(size_t)(c + 5) * 16];
      a6 += ctl[c + 6] * wb[(size_t)(c + 6) * 16];
      a7 += ctl[c + 7] * wb[(size_t)(c + 7) * 16];
    }
    a0 += ctl[512] * wb[(size_t)512 * 16];
    a1 += ctl[513] * wb[(size_t)513 * 16];
    float acc = ((a0 + a1) + (a2 + a3)) + ((a4 + a5) + (a6 + a7));
    float diff = acc - x1[(size_t)(b * 36 + 24 + t) * 16 + f];
    sq[tid] = diff * diff;
  }
  __syncthreads();
  if (tid < 12) {
    float s = 0.f;
    #pragma unroll
    for (int f = 0; f < 16; ++f) s += sq[tid * 16 + f];
    float w = f_ind[b * 12 + tid];
    atomicAdd(&accum[0], (s * (1.f / 16.f)) * w);
    atomicAdd(&accum[1], w);
  }
}

// ---------------- z1 = c_t @ fc_W1 + fc_b1 (unrolled chains) --------------
__global__ __launch_bounds__(64) void fc1_kernel(
    const float* __restrict__ c_t, const float* __restrict__ fc_W1,
    const float* __restrict__ fc_b1, float* __restrict__ z1) {
  int t = blockIdx.x, b = blockIdx.y, dd = threadIdx.x;
  __shared__ float ct[514];
  for (int i = dd; i < 514; i += 64) ct[i] = c_t[(size_t)b * 514 + i];
  __syncthreads();
  const float* wb = fc_W1 + (size_t)t * 514 * 64 + dd;
  float a0 = 0.f, a1 = 0.f, a2 = 0.f, a3 = 0.f;
  float a4 = 0.f, a5 = 0.f, a6 = 0.f, a7 = 0.f;
  #pragma unroll 2
  for (int c = 0; c < 512; c += 8) {
    a0 += ct[c + 0] * wb[(size_t)(c + 0) * 64];
    a1 += ct[c + 1] * wb[(size_t)(c + 1) * 64];
    a2 += ct[c + 2] * wb[(size_t)(c + 2) * 64];
    a3 += ct[c + 3] * wb[(size_t)(c + 3) * 64];
    a4 += ct[c + 4] * wb[(size_t)(c + 4) * 64];
    a5 += ct[c + 5] * wb[(size_t)(c + 5) * 64];
    a6 += ct[c + 6] * wb[(size_t)(c + 6) * 64];
    a7 += ct[c + 7] * wb[(size_t)(c + 7) * 64];
  }
  a0 += ct[512] * wb[(size_t)512 * 64];
  a1 += ct[513] * wb[(size_t)513 * 64];
  float acc = fc_b1[t * 64 + dd] +
              (((a0 + a1) + (a2 + a3)) + ((a4 + a5) + (a6 + a7)));
  z1[(size_t)(t * 256 + b) * 64 + dd] = acc;
}

// ---------------- batchnorm stats over B per (t, dd) ----------------
__global__ __launch_bounds__(256) void bn_stats_kernel(
    const float* __restrict__ z1, float* __restrict__ mu,
    float* __restrict__ rstd) {
  __shared__ float red[8];
  int t = blockIdx.x >> 6;
  int dd = blockIdx.x & 63;
  int b = threadIdx.x;
  float v = z1[(size_t)(t * 256 + b) * 64 + dd];
  float mean = blockReduceSum(v, red) * (1.f / 256.f);
  float d = v - mean;
  float var = blockReduceSum(d * d, red) * (1.f / 256.f);
  if (b == 0) {
    mu[t * 64 + dd] = mean;
    rstd[t * 64 + dd] = rsqrtf(var + 1e-5f);
  }
}

// ---------------- out = relu(bn(z1)) @ fc_W2 + fc_b2 ----------------
__global__ __launch_bounds__(64) void out_kernel(
    const float* __restrict__ z1, const float* __restrict__ mu,
    const float* __restrict__ rstd, const float* __restrict__ bn_g,
    const float* __restrict__ bn_b, const float* __restrict__ fc_W2,
    const float* __restrict__ fc_b2, float* __restrict__ out) {
  int t = blockIdx.x, b = blockIdx.y, dd = threadIdx.x;
  float v = z1[(size_t)(t * 256 + b) * 64 + dd];
  float zn = (v - mu[t * 64 + dd]) * rstd[t * 64 + dd] * bn_g[t * 64 + dd] +
             bn_b[t * 64 + dd];
  float val = fmaxf(zn, 0.f) * fc_W2[t * 64 + dd];
  #pragma unroll
  for (int off = 32; off > 0; off >>= 1) val += __shfl_down(val, off, 64);
  if (dd == 0) out[t * 256 + b] = val + fc_b2[t];
}

__global__ void loss_final_kernel(const float* __restrict__ accum,
                                  float* __restrict__ out) {
  out[0] = accum[0] / accum[1];
}

// =======================================================================
extern "C" void kernel_launch(void* const* d_in, const int* in_sizes, int n_in,
                              void* d_out, int out_size, void* d_ws,
                              size_t ws_size, hipStream_t stream) {
  const float* x1 = (const float*)d_in[0];
  const float* h0 = (const float*)d_in[1];
  const float* m1 = (const float*)d_in[2];
  const float* d1 = (const float*)d_in[3];
  const float* x_m = (const float*)d_in[4];
  const float* age = (const float*)d_in[5];
  const float* gen = (const float*)d_in[6];
  const int* input_lengths = (const int*)d_in[7];
  const int* txts = (const int*)d_in[8];
  const int* txt_lengths = (const int*)d_in[9];
  const float* f_ind = (const float*)d_in[10];
  const float* emb = (const float*)d_in[11];
  const float* Win = (const float*)d_in[12];
  const float* bin_ = (const float*)d_in[13];
  const float* ln_in_g = (const float*)d_in[14];
  const float* ln_in_b = (const float*)d_in[15];
  const float* Wq = (const float*)d_in[16];
  const float* bq = (const float*)d_in[17];
  const float* Wk = (const float*)d_in[18];
  const float* bk = (const float*)d_in[19];
  const float* Wv = (const float*)d_in[20];
  const float* bv = (const float*)d_in[21];
  const float* Wo = (const float*)d_in[22];
  const float* bo = (const float*)d_in[23];
  const float* ln1_g = (const float*)d_in[24];
  const float* ln1_b = (const float*)d_in[25];
  const float* Wf1 = (const float*)d_in[26];
  const float* bf1 = (const float*)d_in[27];
  const float* Wf2 = (const float*)d_in[28];
  const float* bf2 = (const float*)d_in[29];
  const float* ln2_g = (const float*)d_in[30];
  const float* ln2_b = (const float*)d_in[31];
  const float* dec_w = (const float*)d_in[32];
  const float* dec_b = (const float*)d_in[33];
  const float* hd_W = (const float*)d_in[34];
  const float* hd_b = (const float*)d_in[35];
  const float* W_ih = (const float*)d_in[36];
  const float* b_ih = (const float*)d_in[37];
  const float* W_hh = (const float*)d_in[38];
  const float* b_hh = (const float*)d_in[39];
  const float* ln_c_g = (const float*)d_in[40];
  const float* ln_c_b = (const float*)d_in[41];
  const float* ct_w = (const float*)d_in[42];
  const float* fc_W1 = (const float*)d_in[43];
  const float* fc_b1 = (const float*)d_in[44];
  const float* bn_g = (const float*)d_in[45];
  const float* bn_b = (const float*)d_in[46];
  const float* fc_W2 = (const float*)d_in[47];
  const float* fc_b2 = (const float*)d_in[48];
  float* out = (float*)d_out;

  // ---- workspace layout (bytes) ----
  char* base = (char*)d_ws;
  u16* hdd_bf = (u16*)(base + 0);             // 16.8 MB (residual stream)
  u16* qkvb = (u16*)(base + 16777216);        // 50.3 MB
  u16* ob = (u16*)(base + 67108864);          // 16.8 MB (also tx_bf)
  u16* WinT = (u16*)(base + 83886080);        // 65536 el
  u16* WqkvT = WinT + 65536;                  // 4 x 196608 el
  u16* WoT = WqkvT + 786432;                  // 4 x 65536 el
  u16* Wf1T = WoT + 262144;                   // 4 x 131072 el
  u16* Wf2T = Wf1T + 524288;                  // 4 x 131072 el
  float* bqkv = (float*)(base + 88211456);    // 3072 f32
  float* pe = (float*)(base + 88223744);      // 128 KB
  u16* WhhT = (u16*)(base + 88354816);        // 384 KB bf16 [768][256]
  // GRU/head overlay over qkvb/ob (dead post-transformer); hdd_bf stays live
  char* gru = base + 16777216;
  float* xprep = (float*)gru;                 // 786432 B
  float* dprep = (float*)(gru + 786432);      // 393216 B
  float* gx = (float*)(gru + 1179648);        // 18874368 B
  float* hdcyb = (float*)(gru + 20054016);    // 6291456 B
  float* ys = (float*)(gru + 26345472);       // 6291456 B
  float* c_t = (float*)(gru + 32636928);      // 526336 B
  float* z1 = (float*)(gru + 33163264);       // 786432 B
  float* muv = (float*)(gru + 33949696);
  float* rstdv = (float*)(gru + 33952768);
  float* accum = (float*)(gru + 33955840);

  hipMemsetAsync(accum, 0, 2 * sizeof(float), stream);

  // ---- weight conversion ----
  transpose_bf16<<<dim3(8, 8, 1), 256, 0, stream>>>(Win, WinT, 256, 256, 65536);
  transpose_qkvo<<<dim3(8, 8, 16), 256, 0, stream>>>(Wq, Wk, Wv, Wo, WqkvT,
                                                     WoT);
  transpose_bf16<<<dim3(16, 8, 4), 256, 0, stream>>>(Wf1, Wf1T, 256, 512,
                                                     131072);
  transpose_bf16<<<dim3(8, 16, 4), 256, 0, stream>>>(Wf2, Wf2T, 512, 256,
                                                     131072);
  transpose_bf16<<<dim3(24, 8, 1), 256, 0, stream>>>(W_hh, WhhT, 256, 768,
                                                     196608);
  bias_concat_kernel<<<4, 768, 0, stream>>>(bq, bk, bv, bqkv);

  // ---- text transformer ----
  pe_kernel<<<128, 256, 0, stream>>>(pe);
  gather_kernel<<<8192, 256, 0, stream>>>(txts, emb, ob);  // tx in ob
  gemm_ln<<<512, 256, 0, stream>>>(ob, WinT, bin_, ln_in_g, ln_in_b, pe,
                                   hdd_bf, 32768, 256, 1);
  for (int l = 0; l < 4; ++l) {
    gemm_bf16<<<dim3(6, 256), 256, 0, stream>>>(hdd_bf, WqkvT + l * 196608,
                                                bqkv + l * 768, qkvb, 32768,
                                                768, 256, 0);
    attn_kernel<<<2048, 128, 0, stream>>>(qkvb, txt_lengths, ob);
    gemm_ln<<<512, 256, 0, stream>>>(ob, WoT + l * 65536, bo + l * 256,
                                     ln1_g + l * 256, ln1_b + l * 256, pe,
                                     hdd_bf, 32768, 256, 0);
    ffn_ln<<<512, 512, 0, stream>>>(hdd_bf, Wf1T + l * 131072, bf1 + l * 512,
                                    Wf2T + l * 131072, bf2 + l * 256,
                                    ln2_g + l * 256, ln2_b + l * 256, hdd_bf,
                                    32768);
  }

  // ---- GRU-D branch ----
  impute_kernel<<<384, 256, 0, stream>>>(x1, m1, d1, dec_w, dec_b, x_m, xprep,
                                         dprep);
  gemm_f32<<<dim3(12, 96), 256, 0, stream>>>(xprep, W_ih, b_ih, gx, 6144, 768,
                                             32, 0);
  gemm_f32<<<dim3(4, 96), 256, 0, stream>>>(dprep, hd_W, hd_b, hdcyb, 6144,
                                            256, 16, 2);
  gru_scan_mfma<<<128, 256, 0, stream>>>(gx, hdcyb, WhhT, b_hh, h0, ys);

  // ---- head ----
  ct_pred_kernel<<<256, 256, 0, stream>>>(ys, hdd_bf, input_lengths, age, gen,
                                          ln_c_g, ln_c_b, c_t, ct_w, x1, f_ind,
                                          accum);
  fc1_kernel<<<dim3(12, 256), 64, 0, stream>>>(c_t, fc_W1, fc_b1, z1);
  bn_stats_kernel<<<768, 256, 0, stream>>>(z1, muv, rstdv);
  out_kernel<<<dim3(12, 256), 64, 0, stream>>>(z1, muv, rstdv, bn_g, bn_b,
                                               fc_W2, fc_b2, out);
  loss_final_kernel<<<1, 1, 0, stream>>>(accum, out + 3072);
}